// Round 1
// baseline (1793.030 us; speedup 1.0000x reference)
//
#include <hip/hip_runtime.h>
#include <hip/hip_bf16.h>

#define EPSF 1e-20f

typedef __hip_bfloat16 bf16;

__device__ __forceinline__ float b2f(bf16 v) { return __bfloat162float(v); }
__device__ __forceinline__ bf16 f2b(float v) { return __float2bfloat16(v); }
__device__ __forceinline__ float rcpf_(float v) { return __builtin_amdgcn_rcpf(v); }

// ---- problem dims (fixed by setup_inputs) ----
#define B_ 16
#define H1 352
#define W1 1216
#define H2 176
#define W2 608
#define H3 88
#define W3 304
#define H4 44
#define W4 152

// ---------------------------------------------------------------------------
// Weight prep (f32 inputs): w = softplus(10*p)/10, plus per-out-ch kernel sums.
// wb layout (floats): wt1@0(50) s1@64(2) | wt2@96(100) s2@224(2) |
// wt3@256(100) s3@384(2) | wt4@416(72) s4@512(2) | wt5@544(72) s5@640(2) |
// wt6@672(72) s6@768(2) | wt7@800(2) s7@804(1).
// ---------------------------------------------------------------------------
__global__ void prep_weights(const float* w1, const float* w2, const float* w3,
                             const float* w4, const float* w5, const float* w6,
                             const float* w7, float* wb) {
    const float* ptrs[7] = {w1, w2, w3, w4, w5, w6, w7};
    const int ns[7]   = {50, 100, 100, 72, 72, 72, 2};
    const int offs[7] = {0, 96, 256, 416, 544, 672, 800};
    for (int it = 0; it < 7; ++it)
        for (int i = threadIdx.x; i < ns[it]; i += blockDim.x) {
            float z = 10.f * ptrs[it][i];
            float sp = (z > 20.f) ? z : log1pf(expf(z));
            wb[offs[it] + i] = sp * 0.1f;
        }
    __syncthreads();
    if (threadIdx.x == 0) {
        const int souts[7] = {2, 2, 2, 2, 2, 2, 1};
        const int klen[7]  = {25, 50, 50, 36, 36, 36, 2};
        const int soff[7]  = {64, 224, 384, 512, 640, 768, 804};
        for (int it = 0; it < 7; ++it)
            for (int o = 0; o < souts[it]; ++o) {
                float s = 0.f;
                for (int i = 0; i < klen[it]; ++i) s += wb[offs[it] + o * klen[it] + i];
                wb[soff[it] + o] = s;
            }
    }
}

// ---------------------------------------------------------------------------
// Fused L1 encoder + pool, LDS-traffic-optimized rewrite:
//  - LDS stores (p = x*c, c) as float2 -> one ds_read_b64 per tap (was 2x b32
//    + per-tap mul).
//  - Stage1/2 compute horizontal output PAIRS (6 taps/row feed 2 outputs);
//    stage3 computes its 2x2 quad via a 6-row sliding window (72 reads vs 200).
//  - Stage buffers aliased: stage0 tile lives in the stage2 buffer (dead after
//    stage1) -> LDS 48.6 KB -> 3 blocks/CU (was 63 KB -> 2).
//  - Odd float2 row strides (45/41/37) de-phase row-wrap bank conflicts.
//  - rcp instead of div; 1/s precomputed; bf16x2 packed coalesced stores.
// ---------------------------------------------------------------------------
#define TDIM 32
#define S0STR 45
#define S1STR 41
#define S2STR 37

__global__ __launch_bounds__(256, 3) void fused_l1pool(
    const float* __restrict__ x0g, const float* __restrict__ c0g,
    const float* __restrict__ wb,
    const float* __restrict__ b1, const float* __restrict__ b2, const float* __restrict__ b3,
    bf16* __restrict__ Axg, bf16* __restrict__ Acg,
    bf16* __restrict__ P1x, bf16* __restrict__ P1c) {

    __shared__ float2 A1[2 * 40 * S1STR];   // stage1 out (p,c), per ci. 26240 B
    __shared__ float2 B0[2 * 36 * S2STR];   // stage0 (44xS0STR) then stage2 out. 21312 B
    __shared__ float sw[262];
    // sw: w1@0(50), w2@50(100), w3@150(100), 1/s1@250, 1/s2@252, 1/s3@254,
    //     b1@256, b2@258, b3@260
    const int tid = threadIdx.x;
    for (int i = tid; i < 262; i += 256) {
        float v;
        if (i < 50)        v = wb[i];
        else if (i < 150)  v = wb[96 + (i - 50)];
        else if (i < 250)  v = wb[256 + (i - 150)];
        else if (i < 252)  v = 1.0f / wb[64 + (i - 250)];
        else if (i < 254)  v = 1.0f / wb[224 + (i - 252)];
        else if (i < 256)  v = 1.0f / wb[384 + (i - 254)];
        else if (i < 258)  v = b1[i - 256];
        else if (i < 260)  v = b2[i - 258];
        else               v = b3[i - 260];
        sw[i] = v;
    }

    const int base_h = blockIdx.y * TDIM;
    const int base_w = blockIdx.x * TDIM;
    const int b = blockIdx.z;
    const float* xp = x0g + (long)b * (H1 * W1);
    const float* cp = c0g + (long)b * (H1 * W1);

    // stage 0: 44x44 (p,c) tile at origin (-6,-6), zero OOB. 256=5*44+36.
    {
        int r = tid / 44, c = tid - r * 44;
        while (r < 44) {
            int gh = base_h - 6 + r, gw = base_w - 6 + c;
            float xv = 0.f, cv = 0.f;
            if (gh >= 0 && gh < H1 && gw >= 0 && gw < W1) {
                long o = (long)gh * W1 + gw;
                xv = xp[o]; cv = cp[o];
            }
            B0[r * S0STR + c] = make_float2(xv * cv, cv);
            r += 5; c += 36; if (c >= 44) { c -= 44; ++r; }
        }
    }
    __syncthreads();

    // stage 1: conv1 (CIN=1), 40x40 outputs (origin -4) as 800 horiz pairs.
    // 256 = 12*20 + 16.
    {
        int r = tid / 20, pcx = tid - r * 20;
        while (r < 40) {
            const int c = 2 * pcx;
            float n0a=0,d0a=0,n1a=0,d1a=0,n0b=0,d0b=0,n1b=0,d1b=0;
            #pragma unroll
            for (int dh = 0; dh < 5; ++dh) {
                const float2* row = &B0[(r + dh) * S0STR + c];
                float2 tt[6];
                #pragma unroll
                for (int j = 0; j < 6; ++j) tt[j] = row[j];
                #pragma unroll
                for (int dw = 0; dw < 5; ++dw) {
                    float w0  = sw[dh * 5 + dw];
                    float w1v = sw[25 + dh * 5 + dw];
                    n0a = fmaf(w0,  tt[dw].x,   n0a); d0a = fmaf(w0,  tt[dw].y,   d0a);
                    n1a = fmaf(w1v, tt[dw].x,   n1a); d1a = fmaf(w1v, tt[dw].y,   d1a);
                    n0b = fmaf(w0,  tt[dw+1].x, n0b); d0b = fmaf(w0,  tt[dw+1].y, d0b);
                    n1b = fmaf(w1v, tt[dw+1].x, n1b); d1b = fmaf(w1v, tt[dw+1].y, d1b);
                }
            }
            const int gh = base_h - 4 + r;
            const int gwa = base_w - 4 + c;
            const bool rin = (gh >= 0 && gh < H1);
            float2 z = make_float2(0.f, 0.f);
            float2 pa0 = z, pa1 = z, pb0 = z, pb1 = z;
            if (rin && gwa >= 0 && gwa < W1) {
                float cA = d0a * sw[250];
                float xA = n0a * rcpf_(d0a + EPSF) + sw[256];
                pa0 = make_float2(xA * cA, cA);
                float cB = d1a * sw[251];
                float xB = n1a * rcpf_(d1a + EPSF) + sw[257];
                pa1 = make_float2(xB * cB, cB);
            }
            if (rin && gwa + 1 >= 0 && gwa + 1 < W1) {
                float cA = d0b * sw[250];
                float xA = n0b * rcpf_(d0b + EPSF) + sw[256];
                pb0 = make_float2(xA * cA, cA);
                float cB = d1b * sw[251];
                float xB = n1b * rcpf_(d1b + EPSF) + sw[257];
                pb1 = make_float2(xB * cB, cB);
            }
            A1[r * S1STR + c]                    = pa0;
            A1[r * S1STR + c + 1]                = pb0;
            A1[40 * S1STR + r * S1STR + c]       = pa1;
            A1[40 * S1STR + r * S1STR + c + 1]   = pb1;
            r += 12; pcx += 16; if (pcx >= 20) { pcx -= 20; ++r; }
        }
    }
    __syncthreads();

    // stage 2: conv2 (CIN=2), 36x36 outputs (origin -2) as 648 pairs.
    // Writes into B0 (stage0 data dead). 256 = 14*18 + 4.
    {
        int r = tid / 18, pcx = tid - r * 18;
        while (r < 36) {
            const int c = 2 * pcx;
            float n0a=0,d0a=0,n1a=0,d1a=0,n0b=0,d0b=0,n1b=0,d1b=0;
            #pragma unroll
            for (int ci = 0; ci < 2; ++ci) {
                #pragma unroll
                for (int dh = 0; dh < 5; ++dh) {
                    const float2* row = &A1[ci * (40 * S1STR) + (r + dh) * S1STR + c];
                    float2 tt[6];
                    #pragma unroll
                    for (int j = 0; j < 6; ++j) tt[j] = row[j];
                    #pragma unroll
                    for (int dw = 0; dw < 5; ++dw) {
                        float w0  = sw[50 + ci * 25 + dh * 5 + dw];
                        float w1v = sw[100 + ci * 25 + dh * 5 + dw];
                        n0a = fmaf(w0,  tt[dw].x,   n0a); d0a = fmaf(w0,  tt[dw].y,   d0a);
                        n1a = fmaf(w1v, tt[dw].x,   n1a); d1a = fmaf(w1v, tt[dw].y,   d1a);
                        n0b = fmaf(w0,  tt[dw+1].x, n0b); d0b = fmaf(w0,  tt[dw+1].y, d0b);
                        n1b = fmaf(w1v, tt[dw+1].x, n1b); d1b = fmaf(w1v, tt[dw+1].y, d1b);
                    }
                }
            }
            const int gh = base_h - 2 + r;
            const int gwa = base_w - 2 + c;
            const bool rin = (gh >= 0 && gh < H1);
            float2 z = make_float2(0.f, 0.f);
            float2 pa0 = z, pa1 = z, pb0 = z, pb1 = z;
            if (rin && gwa >= 0 && gwa < W1) {
                float cA = d0a * sw[252];
                float xA = n0a * rcpf_(d0a + EPSF) + sw[258];
                pa0 = make_float2(xA * cA, cA);
                float cB = d1a * sw[253];
                float xB = n1a * rcpf_(d1a + EPSF) + sw[259];
                pa1 = make_float2(xB * cB, cB);
            }
            if (rin && gwa + 1 >= 0 && gwa + 1 < W1) {
                float cA = d0b * sw[252];
                float xA = n0b * rcpf_(d0b + EPSF) + sw[258];
                pb0 = make_float2(xA * cA, cA);
                float cB = d1b * sw[253];
                float xB = n1b * rcpf_(d1b + EPSF) + sw[259];
                pb1 = make_float2(xB * cB, cB);
            }
            B0[r * S2STR + c]                    = pa0;
            B0[r * S2STR + c + 1]                = pb0;
            B0[36 * S2STR + r * S2STR + c]       = pa1;
            B0[36 * S2STR + r * S2STR + c + 1]   = pb1;
            r += 14; pcx += 4; if (pcx >= 18) { pcx -= 18; ++r; }
        }
    }
    __syncthreads();

    // stage 3: conv3 per 2x2 quad, 6-row sliding window (72 b64 reads/thread).
    // Writes full-res A (packed bf16x2) AND pooled P1.
    {
        const int pr = tid >> 4, pcq = tid & 15;
        const int r0 = 2 * pr, c0 = 2 * pcq;
        float acc[2][2][4];   // [qr][qc][n0,d0,n1,d1]
        #pragma unroll
        for (int a = 0; a < 2; ++a)
            #pragma unroll
            for (int q = 0; q < 2; ++q)
                #pragma unroll
                for (int k = 0; k < 4; ++k) acc[a][q][k] = 0.f;
        #pragma unroll
        for (int tr = 0; tr < 6; ++tr) {
            #pragma unroll
            for (int ci = 0; ci < 2; ++ci) {
                const float2* row = &B0[ci * (36 * S2STR) + (r0 + tr) * S2STR + c0];
                float2 tt[6];
                #pragma unroll
                for (int j = 0; j < 6; ++j) tt[j] = row[j];
                #pragma unroll
                for (int qr = 0; qr < 2; ++qr) {
                    const int dh = tr - qr;
                    if (dh < 0 || dh > 4) continue;   // compile-time after unroll
                    #pragma unroll
                    for (int dw = 0; dw < 5; ++dw) {
                        float w0  = sw[150 + ci * 25 + dh * 5 + dw];
                        float w1v = sw[200 + ci * 25 + dh * 5 + dw];
                        #pragma unroll
                        for (int qc = 0; qc < 2; ++qc) {
                            float2 pc2 = tt[dw + qc];
                            acc[qr][qc][0] = fmaf(w0,  pc2.x, acc[qr][qc][0]);
                            acc[qr][qc][1] = fmaf(w0,  pc2.y, acc[qr][qc][1]);
                            acc[qr][qc][2] = fmaf(w1v, pc2.x, acc[qr][qc][2]);
                            acc[qr][qc][3] = fmaf(w1v, pc2.y, acc[qr][qc][3]);
                        }
                    }
                }
            }
        }
        const int fh = base_h + r0, fw = base_w + c0;
        const int ph = (base_h >> 1) + pr, pw = (base_w >> 1) + pcq;
        #pragma unroll
        for (int ch = 0; ch < 2; ++ch) {
            float xq[4], cq[4];
            #pragma unroll
            for (int qr = 0; qr < 2; ++qr)
                #pragma unroll
                for (int qc = 0; qc < 2; ++qc) {
                    float n = acc[qr][qc][2 * ch], d = acc[qr][qc][2 * ch + 1];
                    xq[qr * 2 + qc] = n * rcpf_(d + EPSF) + sw[260 + ch];
                    cq[qr * 2 + qc] = d * sw[254 + ch];
                }
            long o0 = (long)(b * 2 + ch) * (H1 * W1) + (long)fh * W1 + fw;
            __hip_bfloat162 v0, v1;
            v0.x = f2b(xq[0]); v0.y = f2b(xq[1]);
            v1.x = f2b(xq[2]); v1.y = f2b(xq[3]);
            *reinterpret_cast<__hip_bfloat162*>(Axg + o0) = v0;
            *reinterpret_cast<__hip_bfloat162*>(Axg + o0 + W1) = v1;
            v0.x = f2b(cq[0]); v0.y = f2b(cq[1]);
            v1.x = f2b(cq[2]); v1.y = f2b(cq[3]);
            *reinterpret_cast<__hip_bfloat162*>(Acg + o0) = v0;
            *reinterpret_cast<__hip_bfloat162*>(Acg + o0 + W1) = v1;
            // pooled (first-max on conf, row-major)
            int sel = 0; float cm = cq[0];
            if (cq[1] > cm) { cm = cq[1]; sel = 1; }
            if (cq[2] > cm) { cm = cq[2]; sel = 2; }
            if (cq[3] > cm) { cm = cq[3]; sel = 3; }
            long o = (long)(b * 2 + ch) * (H2 * W2) + (long)ph * W2 + pw;
            P1c[o] = f2b(cm * 0.25f);
            P1x[o] = f2b(xq[sel]);
        }
    }
}

// ---------------------------------------------------------------------------
// 5x5 pad2 nconv, 2 in ch -> 2 out ch, bf16 I/O, fp32 accumulation.
// ---------------------------------------------------------------------------
__global__ void nconv5_c2(const bf16* __restrict__ xin, const bf16* __restrict__ cin,
                          const float* __restrict__ wt, const float* __restrict__ sb,
                          const float* __restrict__ bias,
                          bf16* __restrict__ xout, bf16* __restrict__ cout,
                          int H, int W) {
    __shared__ float sw[104];
    for (int i = threadIdx.x; i < 100; i += blockDim.x) sw[i] = wt[i];
    if (threadIdx.x < 2) {
        sw[100 + threadIdx.x] = sb[threadIdx.x];
        sw[102 + threadIdx.x] = bias[threadIdx.x];
    }
    __syncthreads();
    int idx = blockIdx.x * blockDim.x + threadIdx.x;
    int total = B_ * H * W;
    if (idx >= total) return;
    int w = idx % W; int t = idx / W; int h = t % H; int b = t / H;
    float nom0 = 0, den0 = 0, nom1 = 0, den1 = 0;
    #pragma unroll
    for (int ci = 0; ci < 2; ++ci) {
        const bf16* xp = xin + (long)(b * 2 + ci) * H * W;
        const bf16* cp = cin + (long)(b * 2 + ci) * H * W;
        #pragma unroll
        for (int dh = 0; dh < 5; ++dh) {
            int ih = h + dh - 2;
            if (ih < 0 || ih >= H) continue;
            #pragma unroll
            for (int dw = 0; dw < 5; ++dw) {
                int iw = w + dw - 2;
                if (iw < 0 || iw >= W) continue;
                float c = b2f(cp[ih * W + iw]);
                float x = b2f(xp[ih * W + iw]);
                float p = x * c;
                float w0 = sw[ci * 25 + dh * 5 + dw];
                float w1 = sw[50 + ci * 25 + dh * 5 + dw];
                nom0 = fmaf(w0, p, nom0); den0 = fmaf(w0, c, den0);
                nom1 = fmaf(w1, p, nom1); den1 = fmaf(w1, c, den1);
            }
        }
    }
    long o0 = (long)(b * 2) * H * W + h * W + w;
    long o1 = o0 + H * W;
    xout[o0] = f2b(nom0 / (den0 + EPSF) + sw[102]);
    xout[o1] = f2b(nom1 / (den1 + EPSF) + sw[103]);
    cout[o0] = f2b(den0 / sw[100]);
    cout[o1] = f2b(den1 / sw[101]);
}

// ---------------------------------------------------------------------------
// 2x2 max-pool on conf (first-max, row-major), gather x at argmax, conf/4.
// ---------------------------------------------------------------------------
__global__ void pool_ds2(const bf16* __restrict__ cin, const bf16* __restrict__ xin,
                         bf16* __restrict__ cout, bf16* __restrict__ xout,
                         int H, int W) {
    int Ho = H / 2, Wo = W / 2;
    int idx = blockIdx.x * blockDim.x + threadIdx.x;
    int total = B_ * 2 * Ho * Wo;
    if (idx >= total) return;
    int wo = idx % Wo; int t = idx / Wo; int ho = t % Ho; int bc = t / Ho;
    const bf16* cp = cin + (long)bc * H * W;
    const bf16* xp = xin + (long)bc * H * W;
    int base = (2 * ho) * W + 2 * wo;
    float c00 = b2f(cp[base]), c01 = b2f(cp[base + 1]);
    float c10 = b2f(cp[base + W]), c11 = b2f(cp[base + W + 1]);
    int sel = 0; float cm = c00;
    if (c01 > cm) { cm = c01; sel = 1; }
    if (c10 > cm) { cm = c10; sel = 2; }
    if (c11 > cm) { cm = c11; sel = 3; }
    bf16 xv = (sel == 0) ? xp[base] : (sel == 1) ? xp[base + 1]
            : (sel == 2) ? xp[base + W] : xp[base + W + 1];
    long o = (long)(bc * Ho + ho) * Wo + wo;
    cout[o] = f2b(cm * 0.25f);
    xout[o] = xv;
}

// ---------------------------------------------------------------------------
// Decoder nconv (mid-levels): 3x3 pad1 over concat(native [wch 0-1],
// up2(half) [wch 2-3]). bf16 I/O.
// ---------------------------------------------------------------------------
__global__ void nconv_cat(const bf16* __restrict__ nx, const bf16* __restrict__ nc,
                          const bf16* __restrict__ ux, const bf16* __restrict__ uc,
                          const float* __restrict__ wt, const float* __restrict__ sb,
                          const float* __restrict__ bias,
                          bf16* __restrict__ xout, bf16* __restrict__ cout,
                          int H, int W) {
    __shared__ float sw[76];
    for (int i = threadIdx.x; i < 72; i += blockDim.x) sw[i] = wt[i];
    if (threadIdx.x < 2) {
        sw[72 + threadIdx.x] = sb[threadIdx.x];
        sw[74 + threadIdx.x] = bias[threadIdx.x];
    }
    __syncthreads();
    int idx = blockIdx.x * blockDim.x + threadIdx.x;
    int total = B_ * H * W;
    if (idx >= total) return;
    int Hh = H / 2, Wh = W / 2;
    int w = idx % W; int t = idx / W; int h = t % H; int b = t / H;
    float nom0 = 0, den0 = 0, nom1 = 0, den1 = 0;
    #pragma unroll
    for (int dh = 0; dh < 3; ++dh) {
        int ih = h + dh - 1;
        if (ih < 0 || ih >= H) continue;
        #pragma unroll
        for (int dw = 0; dw < 3; ++dw) {
            int iw = w + dw - 1;
            if (iw < 0 || iw >= W) continue;
            int ih2 = ih >> 1, iw2 = iw >> 1;
            #pragma unroll
            for (int ci = 0; ci < 2; ++ci) {
                float c = b2f(nc[(long)(b * 2 + ci) * H * W + ih * W + iw]);
                float x = b2f(nx[(long)(b * 2 + ci) * H * W + ih * W + iw]);
                float p = x * c;
                float w0 = sw[ci * 9 + dh * 3 + dw];
                float w1 = sw[36 + ci * 9 + dh * 3 + dw];
                nom0 = fmaf(w0, p, nom0); den0 = fmaf(w0, c, den0);
                nom1 = fmaf(w1, p, nom1); den1 = fmaf(w1, c, den1);
                float c2 = b2f(uc[(long)(b * 2 + ci) * Hh * Wh + ih2 * Wh + iw2]);
                float x2 = b2f(ux[(long)(b * 2 + ci) * Hh * Wh + ih2 * Wh + iw2]);
                float p2 = x2 * c2;
                float v0 = sw[(2 + ci) * 9 + dh * 3 + dw];
                float v1 = sw[36 + (2 + ci) * 9 + dh * 3 + dw];
                nom0 = fmaf(v0, p2, nom0); den0 = fmaf(v0, c2, den0);
                nom1 = fmaf(v1, p2, nom1); den1 = fmaf(v1, c2, den1);
            }
        }
    }
    long o0 = (long)(b * 2) * H * W + h * W + w;
    long o1 = o0 + H * W;
    xout[o0] = f2b(nom0 / (den0 + EPSF) + sw[74]);
    xout[o1] = f2b(nom1 / (den1 + EPSF) + sw[75]);
    cout[o0] = f2b(den0 / sw[72]);
    cout[o1] = f2b(den1 / sw[73]);
}

// ---------------------------------------------------------------------------
// Final tiled kernel: cat(up2(x23) [wch 0-1], x1 [wch 2-3]) -> w6 3x3 nconv
// -> fused w7 1x1 nconv -> f32 d_out. 32x32 tile; A halo 1, E half-res tile
// 18x18. LDS ≈ 24 KB.
// ---------------------------------------------------------------------------
__global__ __launch_bounds__(256) void final_tiled(
    const bf16* __restrict__ Axg, const bf16* __restrict__ Acg,
    const bf16* __restrict__ Exg, const bf16* __restrict__ Ecg,
    const float* __restrict__ wb,
    const float* __restrict__ b6g, const float* __restrict__ b7g,
    float* __restrict__ oX, float* __restrict__ oC) {

    __shared__ float aX[2][34][34], aC[2][34][34];
    __shared__ float eX[2][18][18], eC[2][18][18];
    __shared__ float sw[80];
    // sw: w6@0(72) s6@72(2) b6@74(2) w7@76(2) s7@78 b7@79
    int tid = threadIdx.x;
    for (int i = tid; i < 80; i += 256) {
        float v;
        if (i < 72)       v = wb[672 + i];
        else if (i < 74)  v = wb[768 + (i - 72)];
        else if (i < 76)  v = b6g[i - 74];
        else if (i < 78)  v = wb[800 + (i - 76)];
        else if (i == 78) v = wb[804];
        else              v = b7g[0];
        sw[i] = v;
    }

    const int bh = blockIdx.y * 32, bw = blockIdx.x * 32, b = blockIdx.z;
    const int eh0 = (bh - 1) >> 1, ew0 = (bw - 1) >> 1;   // arithmetic shift: floor

    // A tile 34x34 (origin -1), zero OOB
    for (int i = tid; i < 34 * 34; i += 256) {
        int r = i / 34, c = i % 34;
        int gh = bh - 1 + r, gw = bw - 1 + c;
        bool in = (gh >= 0 && gh < H1 && gw >= 0 && gw < W1);
        #pragma unroll
        for (int ch = 0; ch < 2; ++ch) {
            long o = (long)(b * 2 + ch) * (H1 * W1) + gh * W1 + gw;
            aX[ch][r][c] = in ? b2f(Axg[o]) : 0.f;
            aC[ch][r][c] = in ? b2f(Acg[o]) : 0.f;
        }
    }
    // E tile 18x18 (origin eh0, ew0), zero OOB
    for (int i = tid; i < 18 * 18; i += 256) {
        int r = i / 18, c = i % 18;
        int gh = eh0 + r, gw = ew0 + c;
        bool in = (gh >= 0 && gh < H2 && gw >= 0 && gw < W2);
        #pragma unroll
        for (int ch = 0; ch < 2; ++ch) {
            long o = (long)(b * 2 + ch) * (H2 * W2) + gh * W2 + gw;
            eX[ch][r][c] = in ? b2f(Exg[o]) : 0.f;
            eC[ch][r][c] = in ? b2f(Ecg[o]) : 0.f;
        }
    }
    __syncthreads();

    for (int i = tid; i < 32 * 32; i += 256) {
        int r = i >> 5, c = i & 31;
        int gh = bh + r, gw = bw + c;
        float n0 = 0, d0 = 0, n1 = 0, d1 = 0;
        #pragma unroll
        for (int dh = 0; dh < 3; ++dh) {
            int ih = gh - 1 + dh;
            if (ih < 0 || ih >= H1) continue;
            int lr = r + dh, le = (ih >> 1) - eh0;
            #pragma unroll
            for (int dw = 0; dw < 3; ++dw) {
                int iw = gw - 1 + dw;
                if (iw < 0 || iw >= W1) continue;
                int lc = c + dw, lw = (iw >> 1) - ew0;
                #pragma unroll
                for (int ci = 0; ci < 2; ++ci) {
                    float cE = eC[ci][le][lw];
                    float pE = eX[ci][le][lw] * cE;
                    float u0 = sw[ci * 9 + dh * 3 + dw];
                    float u1 = sw[36 + ci * 9 + dh * 3 + dw];
                    n0 = fmaf(u0, pE, n0); d0 = fmaf(u0, cE, d0);
                    n1 = fmaf(u1, pE, n1); d1 = fmaf(u1, cE, d1);
                    float cN = aC[ci][lr][lc];
                    float pN = aX[ci][lr][lc] * cN;
                    float v0 = sw[(2 + ci) * 9 + dh * 3 + dw];
                    float v1 = sw[36 + (2 + ci) * 9 + dh * 3 + dw];
                    n0 = fmaf(v0, pN, n0); d0 = fmaf(v0, cN, d0);
                    n1 = fmaf(v1, pN, n1); d1 = fmaf(v1, cN, d1);
                }
            }
        }
        float x0v = n0 / (d0 + EPSF) + sw[74];
        float x1v = n1 / (d1 + EPSF) + sw[75];
        float c0v = d0 / sw[72];
        float c1v = d1 / sw[73];
        float w70 = sw[76], w71 = sw[77];
        float den7 = fmaf(w70, c0v, w71 * c1v);
        float nom7 = fmaf(w70, x0v * c0v, w71 * (x1v * c1v));
        long o = (long)b * (H1 * W1) + gh * W1 + gw;
        oX[o] = nom7 / (den7 + EPSF) + sw[79];
        oC[o] = den7 / sw[78];
    }
}

extern "C" void kernel_launch(void* const* d_in, const int* in_sizes, int n_in,
                              void* d_out, int out_size, void* d_ws, size_t ws_size,
                              hipStream_t stream) {
    const float* x0 = (const float*)d_in[0];
    const float* c0 = (const float*)d_in[1];
    const float* w1 = (const float*)d_in[2];
    const float* b1 = (const float*)d_in[3];
    const float* w2 = (const float*)d_in[4];
    const float* b2 = (const float*)d_in[5];
    const float* w3 = (const float*)d_in[6];
    const float* b3 = (const float*)d_in[7];
    const float* w4 = (const float*)d_in[8];
    const float* b4 = (const float*)d_in[9];
    const float* w5 = (const float*)d_in[10];
    const float* b5 = (const float*)d_in[11];
    const float* w6 = (const float*)d_in[12];
    const float* b6 = (const float*)d_in[13];
    const float* w7 = (const float*)d_in[14];
    const float* b7 = (const float*)d_in[15];

    const int N1 = B_ * H1 * W1;            // 6,848,512
    const int N2 = N1 / 4, N3 = N1 / 16, N4 = N1 / 64;

    // ws: [wb 4KB][Ax 2N1][Ac 2N1][Ex 2N2][Ec 2N2] ≈ 69 MB (under proven 96 MB)
    float* wb = (float*)d_ws;
    bf16* Ax = (bf16*)((char*)d_ws + 4096);
    bf16* Ac = Ax + 2 * (long)N1;
    bf16* Ex = Ac + 2 * (long)N1;
    bf16* Ec = Ex + 2 * (long)N2;

    // d_out (2N1 f32) as bf16 scratch (uses first 27.4 of 54.8 MB):
    bf16* R = (bf16*)d_out;
    bf16* P1x = R;                  // x1_ds  [0, 2N2)
    bf16* P1c = R + 2 * (long)N2;   // c1_ds  [2N2, 4N2)
    bf16* T2x = R + 4 * (long)N2;   // L2 temp [4N2, 6N2)
    bf16* T2c = R + 6 * (long)N2;   //         [6N2, 8N2)
    bf16* Dx = P1x;                 // x2,c2 reuse P1 (dead after L2 conv#1)
    bf16* Dc = P1c;
    bf16* C0 = R + 4 * (long)N2;    // carve region (T2 dead after L2 conv#2)
    bf16* P2x = C0;                  bf16* P2c = C0 + 2 * (long)N3;
    bf16* Gx  = C0 + 4 * (long)N3;   bf16* Gc  = C0 + 6 * (long)N3;
    bf16* P3x = C0 + 8 * (long)N3;   bf16* P3c = P3x + 2 * (long)N4;
    bf16* Ix  = P3x + 4 * (long)N4;  bf16* Ic  = Ix + 2 * (long)N4;
    bf16* Fx  = P3x + 8 * (long)N4;  bf16* Fc  = Fx + 2 * (long)N3;
    // Fc ends at C0 + 14*N3 <= end of the 2N1-bf16 region. OK.

    float* oX = (float*)d_out;
    float* oC = oX + (long)N1;

    prep_weights<<<1, 256, 0, stream>>>(w1, w2, w3, w4, w5, w6, w7, wb);

    // Fused L1 encoder + pool: x0,c0 -> A (ws) + P1 (d_out)
    dim3 gridF(W1 / TDIM, H1 / TDIM, B_);   // 38 x 11 x 16
    fused_l1pool<<<gridF, 256, 0, stream>>>(x0, c0, wb, b1, b2, b3, Ax, Ac, P1x, P1c);

    const int g2 = (B_ * H2 * W2 + 255) / 256;
    const int g3 = (B_ * H3 * W3 + 255) / 256;
    const int g4 = (B_ * H4 * W4 + 255) / 256;

    // L2
    nconv5_c2<<<g2, 256, 0, stream>>>(P1x, P1c, wb + 96, wb + 224, b2, T2x, T2c, H2, W2);
    nconv5_c2<<<g2, 256, 0, stream>>>(T2x, T2c, wb + 256, wb + 384, b3, Dx, Dc, H2, W2);  // D = x2,c2

    // L3
    pool_ds2<<<(B_ * 2 * H3 * W3 + 255) / 256, 256, 0, stream>>>(Dc, Dx, P2c, P2x, H2, W2);
    nconv5_c2<<<g3, 256, 0, stream>>>(P2x, P2c, wb + 96, wb + 224, b2, Gx, Gc, H3, W3);   // G = x3,c3

    // L4
    pool_ds2<<<(B_ * 2 * H4 * W4 + 255) / 256, 256, 0, stream>>>(Gc, Gx, P3c, P3x, H3, W3);
    nconv5_c2<<<g4, 256, 0, stream>>>(P3x, P3c, wb + 96, wb + 224, b2, Ix, Ic, H4, W4);   // I = x4,c4

    // Decoder
    nconv_cat<<<g3, 256, 0, stream>>>(Gx, Gc, Ix, Ic, wb + 416, wb + 512, b4, Fx, Fc, H3, W3);  // F = x34
    nconv_cat<<<g2, 256, 0, stream>>>(Dx, Dc, Fx, Fc, wb + 544, wb + 640, b5, Ex, Ec, H2, W2);  // E = x23 (ws)

    // Final: tiled w6+w7 -> f32 d_out (reads only ws; rewrites all of d_out)
    dim3 gridL(W1 / 32, H1 / 32, B_);       // 38 x 11 x 16
    final_tiled<<<gridL, 256, 0, stream>>>(Ax, Ac, Ex, Ec, wb, b6, b7, oX, oC);
}

// Round 2
// 859.677 us; speedup vs baseline: 2.0857x; 2.0857x over previous
//
#include <hip/hip_runtime.h>
#include <hip/hip_bf16.h>

#define EPSF 1e-20f

typedef __hip_bfloat16 bf16;

__device__ __forceinline__ float b2f(bf16 v) { return __bfloat162float(v); }
__device__ __forceinline__ bf16 f2b(float v) { return __float2bfloat16(v); }
__device__ __forceinline__ float rcpf_(float v) { return __builtin_amdgcn_rcpf(v); }

// ---- problem dims (fixed by setup_inputs) ----
#define B_ 16
#define H1 352
#define W1 1216
#define H2 176
#define W2 608
#define H3 88
#define W3 304
#define H4 44
#define W4 152

// ---------------------------------------------------------------------------
// Weight prep (f32 inputs): w = softplus(10*p)/10, plus per-out-ch kernel sums.
// wb layout (floats): wt1@0(50) s1@64(2) | wt2@96(100) s2@224(2) |
// wt3@256(100) s3@384(2) | wt4@416(72) s4@512(2) | wt5@544(72) s5@640(2) |
// wt6@672(72) s6@768(2) | wt7@800(2) s7@804(1).
// ---------------------------------------------------------------------------
__global__ void prep_weights(const float* w1, const float* w2, const float* w3,
                             const float* w4, const float* w5, const float* w6,
                             const float* w7, float* wb) {
    const float* ptrs[7] = {w1, w2, w3, w4, w5, w6, w7};
    const int ns[7]   = {50, 100, 100, 72, 72, 72, 2};
    const int offs[7] = {0, 96, 256, 416, 544, 672, 800};
    for (int it = 0; it < 7; ++it)
        for (int i = threadIdx.x; i < ns[it]; i += blockDim.x) {
            float z = 10.f * ptrs[it][i];
            float sp = (z > 20.f) ? z : log1pf(expf(z));
            wb[offs[it] + i] = sp * 0.1f;
        }
    __syncthreads();
    if (threadIdx.x == 0) {
        const int souts[7] = {2, 2, 2, 2, 2, 2, 1};
        const int klen[7]  = {25, 50, 50, 36, 36, 36, 2};
        const int soff[7]  = {64, 224, 384, 512, 640, 768, 804};
        for (int it = 0; it < 7; ++it)
            for (int o = 0; o < souts[it]; ++o) {
                float s = 0.f;
                for (int i = 0; i < klen[it]; ++i) s += wb[offs[it] + o * klen[it] + i];
                wb[soff[it] + o] = s;
            }
    }
}

// ---------------------------------------------------------------------------
// Fused L1 encoder + pool. Round-0 proven structure (plain strided loops,
// NO local vector arrays -> no scratch), upgraded:
//  - stage-1 input LDS holds (p=x*c, c) float2  -> 1x ds_read_b64 per tap
//  - stage-2/3 input LDS holds (p0,c0,p1,c1) float4 -> 1x ds_read_b128 per tap
//  - stage-0 tile unioned with stage-2 buffer: LDS 48.6 KB -> 3 blocks/CU
//  - rcp + precomputed 1/s (validated R1); packed bf16x2 full-res stores
// ---------------------------------------------------------------------------
#define TDIM 32

__global__ __launch_bounds__(256) void fused_l1pool(
    const float* __restrict__ x0g, const float* __restrict__ c0g,
    const float* __restrict__ wb,
    const float* __restrict__ b1, const float* __restrict__ b2, const float* __restrict__ b3,
    bf16* __restrict__ Axg, bf16* __restrict__ Acg,
    bf16* __restrict__ P1x, bf16* __restrict__ P1c) {

    __shared__ float4 A1[40 * 41];   // stage1 out (p0,c0,p1,c1). 26240 B
    __shared__ float4 U4[36 * 37];   // stage0 tile (as float2) / stage2 out. 21312 B
    __shared__ float sw[262];
    // sw: w1@0(50), w2@50(100), w3@150(100), 1/s1@250, 1/s2@252, 1/s3@254,
    //     b1@256, b2@258, b3@260
    float2* U2 = (float2*)U4;        // stage0 view: 44 rows x stride 45 (1979 <= 2664)

    const int tid = threadIdx.x;
    for (int i = tid; i < 262; i += 256) {
        float v;
        if (i < 50)        v = wb[i];
        else if (i < 150)  v = wb[96 + (i - 50)];
        else if (i < 250)  v = wb[256 + (i - 150)];
        else if (i < 252)  v = 1.0f / wb[64 + (i - 250)];
        else if (i < 254)  v = 1.0f / wb[224 + (i - 252)];
        else if (i < 256)  v = 1.0f / wb[384 + (i - 254)];
        else if (i < 258)  v = b1[i - 256];
        else if (i < 260)  v = b2[i - 258];
        else               v = b3[i - 260];
        sw[i] = v;
    }

    const int base_h = blockIdx.y * TDIM;
    const int base_w = blockIdx.x * TDIM;
    const int b = blockIdx.z;
    const float* xp = x0g + (long)b * (H1 * W1);
    const float* cp = c0g + (long)b * (H1 * W1);

    __syncthreads();

    // stage 0: 44x44 (p,c) tile at origin (-6,-6), zero OOB.
    for (int i = tid; i < 44 * 44; i += 256) {
        int r = i / 44, c = i % 44;
        int gh = base_h - 6 + r, gw = base_w - 6 + c;
        float xv = 0.f, cv = 0.f;
        if (gh >= 0 && gh < H1 && gw >= 0 && gw < W1) {
            long o = (long)gh * W1 + gw;
            xv = xp[o]; cv = cp[o];
        }
        U2[r * 45 + c] = make_float2(xv * cv, cv);
    }
    __syncthreads();

    // stage 1: conv1 (CIN=1), 40x40 outputs (origin -4). 25x ds_read_b64 each.
    for (int i = tid; i < 40 * 40; i += 256) {
        int r = i / 40, cx = i % 40;
        int gh = base_h - 4 + r, gw = base_w - 4 + cx;
        float4 out = make_float4(0.f, 0.f, 0.f, 0.f);
        if (gh >= 0 && gh < H1 && gw >= 0 && gw < W1) {
            float n0 = 0, d0 = 0, n1 = 0, d1 = 0;
            #pragma unroll
            for (int dh = 0; dh < 5; ++dh)
                #pragma unroll
                for (int dw = 0; dw < 5; ++dw) {
                    float2 v = U2[(r + dh) * 45 + (cx + dw)];
                    float w0  = sw[dh * 5 + dw];
                    float w1v = sw[25 + dh * 5 + dw];
                    n0 = fmaf(w0,  v.x, n0); d0 = fmaf(w0,  v.y, d0);
                    n1 = fmaf(w1v, v.x, n1); d1 = fmaf(w1v, v.y, d1);
                }
            float c0v = d0 * sw[250];
            float x0v = n0 * rcpf_(d0 + EPSF) + sw[256];
            float c1v = d1 * sw[251];
            float x1v = n1 * rcpf_(d1 + EPSF) + sw[257];
            out = make_float4(x0v * c0v, c0v, x1v * c1v, c1v);
        }
        A1[r * 41 + cx] = out;
    }
    __syncthreads();   // A1 ready; stage0 data now dead -> U4 reusable

    // stage 2: conv2 (CIN=2), 36x36 outputs (origin -2). 25x ds_read_b128 each.
    for (int i = tid; i < 36 * 36; i += 256) {
        int r = i / 36, cx = i % 36;
        int gh = base_h - 2 + r, gw = base_w - 2 + cx;
        float4 out = make_float4(0.f, 0.f, 0.f, 0.f);
        if (gh >= 0 && gh < H1 && gw >= 0 && gw < W1) {
            float n0 = 0, d0 = 0, n1 = 0, d1 = 0;
            #pragma unroll
            for (int dh = 0; dh < 5; ++dh)
                #pragma unroll
                for (int dw = 0; dw < 5; ++dw) {
                    float4 v = A1[(r + dh) * 41 + (cx + dw)];
                    int k = dh * 5 + dw;
                    float wa0 = sw[50 + k],  wb0 = sw[75 + k];
                    float wa1 = sw[100 + k], wb1 = sw[125 + k];
                    n0 = fmaf(wa0, v.x, n0); d0 = fmaf(wa0, v.y, d0);
                    n0 = fmaf(wb0, v.z, n0); d0 = fmaf(wb0, v.w, d0);
                    n1 = fmaf(wa1, v.x, n1); d1 = fmaf(wa1, v.y, d1);
                    n1 = fmaf(wb1, v.z, n1); d1 = fmaf(wb1, v.w, d1);
                }
            float c0v = d0 * sw[252];
            float x0v = n0 * rcpf_(d0 + EPSF) + sw[258];
            float c1v = d1 * sw[253];
            float x1v = n1 * rcpf_(d1 + EPSF) + sw[259];
            out = make_float4(x0v * c0v, c0v, x1v * c1v, c1v);
        }
        U4[r * 37 + cx] = out;
    }
    __syncthreads();

    // stage 3: conv3 per 2x2 quad. 25x ds_read_b128 per quad element.
    {
        int pr = tid >> 4, pc = tid & 15;
        float xv[2][4], cv[2][4];
        #pragma unroll
        for (int q = 0; q < 4; ++q) {
            int r = 2 * pr + (q >> 1), cx = 2 * pc + (q & 1);
            float n0 = 0, d0 = 0, n1 = 0, d1 = 0;
            #pragma unroll
            for (int dh = 0; dh < 5; ++dh)
                #pragma unroll
                for (int dw = 0; dw < 5; ++dw) {
                    float4 v = U4[(r + dh) * 37 + (cx + dw)];
                    int k = dh * 5 + dw;
                    float wa0 = sw[150 + k], wb0 = sw[175 + k];
                    float wa1 = sw[200 + k], wb1 = sw[225 + k];
                    n0 = fmaf(wa0, v.x, n0); d0 = fmaf(wa0, v.y, d0);
                    n0 = fmaf(wb0, v.z, n0); d0 = fmaf(wb0, v.w, d0);
                    n1 = fmaf(wa1, v.x, n1); d1 = fmaf(wa1, v.y, d1);
                    n1 = fmaf(wb1, v.z, n1); d1 = fmaf(wb1, v.w, d1);
                }
            xv[0][q] = n0 * rcpf_(d0 + EPSF) + sw[260];
            xv[1][q] = n1 * rcpf_(d1 + EPSF) + sw[261];
            cv[0][q] = d0 * sw[254];
            cv[1][q] = d1 * sw[255];
        }
        int fh = base_h + 2 * pr, fw = base_w + 2 * pc;
        int ph = (base_h >> 1) + pr, pw = (base_w >> 1) + pc;
        #pragma unroll
        for (int ch = 0; ch < 2; ++ch) {
            long o0 = (long)(b * 2 + ch) * (H1 * W1) + (long)fh * W1 + fw;
            __hip_bfloat162 v0, v1;
            v0.x = f2b(xv[ch][0]); v0.y = f2b(xv[ch][1]);
            v1.x = f2b(xv[ch][2]); v1.y = f2b(xv[ch][3]);
            *reinterpret_cast<__hip_bfloat162*>(Axg + o0) = v0;
            *reinterpret_cast<__hip_bfloat162*>(Axg + o0 + W1) = v1;
            v0.x = f2b(cv[ch][0]); v0.y = f2b(cv[ch][1]);
            v1.x = f2b(cv[ch][2]); v1.y = f2b(cv[ch][3]);
            *reinterpret_cast<__hip_bfloat162*>(Acg + o0) = v0;
            *reinterpret_cast<__hip_bfloat162*>(Acg + o0 + W1) = v1;
            // pooled (first-max on conf, row-major)
            int sel = 0; float cm = cv[ch][0];
            if (cv[ch][1] > cm) { cm = cv[ch][1]; sel = 1; }
            if (cv[ch][2] > cm) { cm = cv[ch][2]; sel = 2; }
            if (cv[ch][3] > cm) { cm = cv[ch][3]; sel = 3; }
            long o = (long)(b * 2 + ch) * (H2 * W2) + (long)ph * W2 + pw;
            P1c[o] = f2b(cm * 0.25f);
            P1x[o] = f2b(xv[ch][sel]);
        }
    }
}

// ---------------------------------------------------------------------------
// 5x5 pad2 nconv, 2 in ch -> 2 out ch, bf16 I/O, fp32 accumulation.
// ---------------------------------------------------------------------------
__global__ void nconv5_c2(const bf16* __restrict__ xin, const bf16* __restrict__ cin,
                          const float* __restrict__ wt, const float* __restrict__ sb,
                          const float* __restrict__ bias,
                          bf16* __restrict__ xout, bf16* __restrict__ cout,
                          int H, int W) {
    __shared__ float sw[104];
    for (int i = threadIdx.x; i < 100; i += blockDim.x) sw[i] = wt[i];
    if (threadIdx.x < 2) {
        sw[100 + threadIdx.x] = sb[threadIdx.x];
        sw[102 + threadIdx.x] = bias[threadIdx.x];
    }
    __syncthreads();
    int idx = blockIdx.x * blockDim.x + threadIdx.x;
    int total = B_ * H * W;
    if (idx >= total) return;
    int w = idx % W; int t = idx / W; int h = t % H; int b = t / H;
    float nom0 = 0, den0 = 0, nom1 = 0, den1 = 0;
    #pragma unroll
    for (int ci = 0; ci < 2; ++ci) {
        const bf16* xp = xin + (long)(b * 2 + ci) * H * W;
        const bf16* cp = cin + (long)(b * 2 + ci) * H * W;
        #pragma unroll
        for (int dh = 0; dh < 5; ++dh) {
            int ih = h + dh - 2;
            if (ih < 0 || ih >= H) continue;
            #pragma unroll
            for (int dw = 0; dw < 5; ++dw) {
                int iw = w + dw - 2;
                if (iw < 0 || iw >= W) continue;
                float c = b2f(cp[ih * W + iw]);
                float x = b2f(xp[ih * W + iw]);
                float p = x * c;
                float w0 = sw[ci * 25 + dh * 5 + dw];
                float w1 = sw[50 + ci * 25 + dh * 5 + dw];
                nom0 = fmaf(w0, p, nom0); den0 = fmaf(w0, c, den0);
                nom1 = fmaf(w1, p, nom1); den1 = fmaf(w1, c, den1);
            }
        }
    }
    long o0 = (long)(b * 2) * H * W + h * W + w;
    long o1 = o0 + H * W;
    xout[o0] = f2b(nom0 / (den0 + EPSF) + sw[102]);
    xout[o1] = f2b(nom1 / (den1 + EPSF) + sw[103]);
    cout[o0] = f2b(den0 / sw[100]);
    cout[o1] = f2b(den1 / sw[101]);
}

// ---------------------------------------------------------------------------
// 2x2 max-pool on conf (first-max, row-major), gather x at argmax, conf/4.
// ---------------------------------------------------------------------------
__global__ void pool_ds2(const bf16* __restrict__ cin, const bf16* __restrict__ xin,
                         bf16* __restrict__ cout, bf16* __restrict__ xout,
                         int H, int W) {
    int Ho = H / 2, Wo = W / 2;
    int idx = blockIdx.x * blockDim.x + threadIdx.x;
    int total = B_ * 2 * Ho * Wo;
    if (idx >= total) return;
    int wo = idx % Wo; int t = idx / Wo; int ho = t % Ho; int bc = t / Ho;
    const bf16* cp = cin + (long)bc * H * W;
    const bf16* xp = xin + (long)bc * H * W;
    int base = (2 * ho) * W + 2 * wo;
    float c00 = b2f(cp[base]), c01 = b2f(cp[base + 1]);
    float c10 = b2f(cp[base + W]), c11 = b2f(cp[base + W + 1]);
    int sel = 0; float cm = c00;
    if (c01 > cm) { cm = c01; sel = 1; }
    if (c10 > cm) { cm = c10; sel = 2; }
    if (c11 > cm) { cm = c11; sel = 3; }
    bf16 xv = (sel == 0) ? xp[base] : (sel == 1) ? xp[base + 1]
            : (sel == 2) ? xp[base + W] : xp[base + W + 1];
    long o = (long)(bc * Ho + ho) * Wo + wo;
    cout[o] = f2b(cm * 0.25f);
    xout[o] = xv;
}

// ---------------------------------------------------------------------------
// Decoder nconv (mid-levels): 3x3 pad1 over concat(native [wch 0-1],
// up2(half) [wch 2-3]). bf16 I/O.
// ---------------------------------------------------------------------------
__global__ void nconv_cat(const bf16* __restrict__ nx, const bf16* __restrict__ nc,
                          const bf16* __restrict__ ux, const bf16* __restrict__ uc,
                          const float* __restrict__ wt, const float* __restrict__ sb,
                          const float* __restrict__ bias,
                          bf16* __restrict__ xout, bf16* __restrict__ cout,
                          int H, int W) {
    __shared__ float sw[76];
    for (int i = threadIdx.x; i < 72; i += blockDim.x) sw[i] = wt[i];
    if (threadIdx.x < 2) {
        sw[72 + threadIdx.x] = sb[threadIdx.x];
        sw[74 + threadIdx.x] = bias[threadIdx.x];
    }
    __syncthreads();
    int idx = blockIdx.x * blockDim.x + threadIdx.x;
    int total = B_ * H * W;
    if (idx >= total) return;
    int Hh = H / 2, Wh = W / 2;
    int w = idx % W; int t = idx / W; int h = t % H; int b = t / H;
    float nom0 = 0, den0 = 0, nom1 = 0, den1 = 0;
    #pragma unroll
    for (int dh = 0; dh < 3; ++dh) {
        int ih = h + dh - 1;
        if (ih < 0 || ih >= H) continue;
        #pragma unroll
        for (int dw = 0; dw < 3; ++dw) {
            int iw = w + dw - 1;
            if (iw < 0 || iw >= W) continue;
            int ih2 = ih >> 1, iw2 = iw >> 1;
            #pragma unroll
            for (int ci = 0; ci < 2; ++ci) {
                float c = b2f(nc[(long)(b * 2 + ci) * H * W + ih * W + iw]);
                float x = b2f(nx[(long)(b * 2 + ci) * H * W + ih * W + iw]);
                float p = x * c;
                float w0 = sw[ci * 9 + dh * 3 + dw];
                float w1 = sw[36 + ci * 9 + dh * 3 + dw];
                nom0 = fmaf(w0, p, nom0); den0 = fmaf(w0, c, den0);
                nom1 = fmaf(w1, p, nom1); den1 = fmaf(w1, c, den1);
                float c2 = b2f(uc[(long)(b * 2 + ci) * Hh * Wh + ih2 * Wh + iw2]);
                float x2 = b2f(ux[(long)(b * 2 + ci) * Hh * Wh + ih2 * Wh + iw2]);
                float p2 = x2 * c2;
                float v0 = sw[(2 + ci) * 9 + dh * 3 + dw];
                float v1 = sw[36 + (2 + ci) * 9 + dh * 3 + dw];
                nom0 = fmaf(v0, p2, nom0); den0 = fmaf(v0, c2, den0);
                nom1 = fmaf(v1, p2, nom1); den1 = fmaf(v1, c2, den1);
            }
        }
    }
    long o0 = (long)(b * 2) * H * W + h * W + w;
    long o1 = o0 + H * W;
    xout[o0] = f2b(nom0 / (den0 + EPSF) + sw[74]);
    xout[o1] = f2b(nom1 / (den1 + EPSF) + sw[75]);
    cout[o0] = f2b(den0 / sw[72]);
    cout[o1] = f2b(den1 / sw[73]);
}

// ---------------------------------------------------------------------------
// Final tiled kernel: cat(up2(x23) [wch 0-1], x1 [wch 2-3]) -> w6 3x3 nconv
// -> fused w7 1x1 nconv -> f32 d_out. 32x32 tile; A halo 1, E half-res tile
// 18x18. LDS ≈ 24 KB.
// ---------------------------------------------------------------------------
__global__ __launch_bounds__(256) void final_tiled(
    const bf16* __restrict__ Axg, const bf16* __restrict__ Acg,
    const bf16* __restrict__ Exg, const bf16* __restrict__ Ecg,
    const float* __restrict__ wb,
    const float* __restrict__ b6g, const float* __restrict__ b7g,
    float* __restrict__ oX, float* __restrict__ oC) {

    __shared__ float aX[2][34][34], aC[2][34][34];
    __shared__ float eX[2][18][18], eC[2][18][18];
    __shared__ float sw[80];
    // sw: w6@0(72) s6@72(2) b6@74(2) w7@76(2) s7@78 b7@79
    int tid = threadIdx.x;
    for (int i = tid; i < 80; i += 256) {
        float v;
        if (i < 72)       v = wb[672 + i];
        else if (i < 74)  v = wb[768 + (i - 72)];
        else if (i < 76)  v = b6g[i - 74];
        else if (i < 78)  v = wb[800 + (i - 76)];
        else if (i == 78) v = wb[804];
        else              v = b7g[0];
        sw[i] = v;
    }

    const int bh = blockIdx.y * 32, bw = blockIdx.x * 32, b = blockIdx.z;
    const int eh0 = (bh - 1) >> 1, ew0 = (bw - 1) >> 1;   // arithmetic shift: floor

    // A tile 34x34 (origin -1), zero OOB
    for (int i = tid; i < 34 * 34; i += 256) {
        int r = i / 34, c = i % 34;
        int gh = bh - 1 + r, gw = bw - 1 + c;
        bool in = (gh >= 0 && gh < H1 && gw >= 0 && gw < W1);
        #pragma unroll
        for (int ch = 0; ch < 2; ++ch) {
            long o = (long)(b * 2 + ch) * (H1 * W1) + gh * W1 + gw;
            aX[ch][r][c] = in ? b2f(Axg[o]) : 0.f;
            aC[ch][r][c] = in ? b2f(Acg[o]) : 0.f;
        }
    }
    // E tile 18x18 (origin eh0, ew0), zero OOB
    for (int i = tid; i < 18 * 18; i += 256) {
        int r = i / 18, c = i % 18;
        int gh = eh0 + r, gw = ew0 + c;
        bool in = (gh >= 0 && gh < H2 && gw >= 0 && gw < W2);
        #pragma unroll
        for (int ch = 0; ch < 2; ++ch) {
            long o = (long)(b * 2 + ch) * (H2 * W2) + gh * W2 + gw;
            eX[ch][r][c] = in ? b2f(Exg[o]) : 0.f;
            eC[ch][r][c] = in ? b2f(Ecg[o]) : 0.f;
        }
    }
    __syncthreads();

    for (int i = tid; i < 32 * 32; i += 256) {
        int r = i >> 5, c = i & 31;
        int gh = bh + r, gw = bw + c;
        float n0 = 0, d0 = 0, n1 = 0, d1 = 0;
        #pragma unroll
        for (int dh = 0; dh < 3; ++dh) {
            int ih = gh - 1 + dh;
            if (ih < 0 || ih >= H1) continue;
            int lr = r + dh, le = (ih >> 1) - eh0;
            #pragma unroll
            for (int dw = 0; dw < 3; ++dw) {
                int iw = gw - 1 + dw;
                if (iw < 0 || iw >= W1) continue;
                int lc = c + dw, lw = (iw >> 1) - ew0;
                #pragma unroll
                for (int ci = 0; ci < 2; ++ci) {
                    float cE = eC[ci][le][lw];
                    float pE = eX[ci][le][lw] * cE;
                    float u0 = sw[ci * 9 + dh * 3 + dw];
                    float u1 = sw[36 + ci * 9 + dh * 3 + dw];
                    n0 = fmaf(u0, pE, n0); d0 = fmaf(u0, cE, d0);
                    n1 = fmaf(u1, pE, n1); d1 = fmaf(u1, cE, d1);
                    float cN = aC[ci][lr][lc];
                    float pN = aX[ci][lr][lc] * cN;
                    float v0 = sw[(2 + ci) * 9 + dh * 3 + dw];
                    float v1 = sw[36 + (2 + ci) * 9 + dh * 3 + dw];
                    n0 = fmaf(v0, pN, n0); d0 = fmaf(v0, cN, d0);
                    n1 = fmaf(v1, pN, n1); d1 = fmaf(v1, cN, d1);
                }
            }
        }
        float x0v = n0 / (d0 + EPSF) + sw[74];
        float x1v = n1 / (d1 + EPSF) + sw[75];
        float c0v = d0 / sw[72];
        float c1v = d1 / sw[73];
        float w70 = sw[76], w71 = sw[77];
        float den7 = fmaf(w70, c0v, w71 * c1v);
        float nom7 = fmaf(w70, x0v * c0v, w71 * (x1v * c1v));
        long o = (long)b * (H1 * W1) + gh * W1 + gw;
        oX[o] = nom7 / (den7 + EPSF) + sw[79];
        oC[o] = den7 / sw[78];
    }
}

extern "C" void kernel_launch(void* const* d_in, const int* in_sizes, int n_in,
                              void* d_out, int out_size, void* d_ws, size_t ws_size,
                              hipStream_t stream) {
    const float* x0 = (const float*)d_in[0];
    const float* c0 = (const float*)d_in[1];
    const float* w1 = (const float*)d_in[2];
    const float* b1 = (const float*)d_in[3];
    const float* w2 = (const float*)d_in[4];
    const float* b2 = (const float*)d_in[5];
    const float* w3 = (const float*)d_in[6];
    const float* b3 = (const float*)d_in[7];
    const float* w4 = (const float*)d_in[8];
    const float* b4 = (const float*)d_in[9];
    const float* w5 = (const float*)d_in[10];
    const float* b5 = (const float*)d_in[11];
    const float* w6 = (const float*)d_in[12];
    const float* b6 = (const float*)d_in[13];
    const float* w7 = (const float*)d_in[14];
    const float* b7 = (const float*)d_in[15];

    const int N1 = B_ * H1 * W1;            // 6,848,512
    const int N2 = N1 / 4, N3 = N1 / 16, N4 = N1 / 64;

    // ws: [wb 4KB][Ax 2N1][Ac 2N1][Ex 2N2][Ec 2N2] ≈ 69 MB (under proven 96 MB)
    float* wb = (float*)d_ws;
    bf16* Ax = (bf16*)((char*)d_ws + 4096);
    bf16* Ac = Ax + 2 * (long)N1;
    bf16* Ex = Ac + 2 * (long)N1;
    bf16* Ec = Ex + 2 * (long)N2;

    // d_out (2N1 f32) as bf16 scratch (uses first 27.4 of 54.8 MB):
    bf16* R = (bf16*)d_out;
    bf16* P1x = R;                  // x1_ds  [0, 2N2)
    bf16* P1c = R + 2 * (long)N2;   // c1_ds  [2N2, 4N2)
    bf16* T2x = R + 4 * (long)N2;   // L2 temp [4N2, 6N2)
    bf16* T2c = R + 6 * (long)N2;   //         [6N2, 8N2)
    bf16* Dx = P1x;                 // x2,c2 reuse P1 (dead after L2 conv#1)
    bf16* Dc = P1c;
    bf16* C0 = R + 4 * (long)N2;    // carve region (T2 dead after L2 conv#2)
    bf16* P2x = C0;                  bf16* P2c = C0 + 2 * (long)N3;
    bf16* Gx  = C0 + 4 * (long)N3;   bf16* Gc  = C0 + 6 * (long)N3;
    bf16* P3x = C0 + 8 * (long)N3;   bf16* P3c = P3x + 2 * (long)N4;
    bf16* Ix  = P3x + 4 * (long)N4;  bf16* Ic  = Ix + 2 * (long)N4;
    bf16* Fx  = P3x + 8 * (long)N4;  bf16* Fc  = Fx + 2 * (long)N3;
    // Fc ends at C0 + 14*N3 <= end of the 2N1-bf16 region. OK.

    float* oX = (float*)d_out;
    float* oC = oX + (long)N1;

    prep_weights<<<1, 256, 0, stream>>>(w1, w2, w3, w4, w5, w6, w7, wb);

    // Fused L1 encoder + pool: x0,c0 -> A (ws) + P1 (d_out)
    dim3 gridF(W1 / TDIM, H1 / TDIM, B_);   // 38 x 11 x 16
    fused_l1pool<<<gridF, 256, 0, stream>>>(x0, c0, wb, b1, b2, b3, Ax, Ac, P1x, P1c);

    const int g2 = (B_ * H2 * W2 + 255) / 256;
    const int g3 = (B_ * H3 * W3 + 255) / 256;
    const int g4 = (B_ * H4 * W4 + 255) / 256;

    // L2
    nconv5_c2<<<g2, 256, 0, stream>>>(P1x, P1c, wb + 96, wb + 224, b2, T2x, T2c, H2, W2);
    nconv5_c2<<<g2, 256, 0, stream>>>(T2x, T2c, wb + 256, wb + 384, b3, Dx, Dc, H2, W2);  // D = x2,c2

    // L3
    pool_ds2<<<(B_ * 2 * H3 * W3 + 255) / 256, 256, 0, stream>>>(Dc, Dx, P2c, P2x, H2, W2);
    nconv5_c2<<<g3, 256, 0, stream>>>(P2x, P2c, wb + 96, wb + 224, b2, Gx, Gc, H3, W3);   // G = x3,c3

    // L4
    pool_ds2<<<(B_ * 2 * H4 * W4 + 255) / 256, 256, 0, stream>>>(Gc, Gx, P3c, P3x, H3, W3);
    nconv5_c2<<<g4, 256, 0, stream>>>(P3x, P3c, wb + 96, wb + 224, b2, Ix, Ic, H4, W4);   // I = x4,c4

    // Decoder
    nconv_cat<<<g3, 256, 0, stream>>>(Gx, Gc, Ix, Ic, wb + 416, wb + 512, b4, Fx, Fc, H3, W3);  // F = x34
    nconv_cat<<<g2, 256, 0, stream>>>(Dx, Dc, Fx, Fc, wb + 544, wb + 640, b5, Ex, Ec, H2, W2);  // E = x23 (ws)

    // Final: tiled w6+w7 -> f32 d_out (reads only ws; rewrites all of d_out)
    dim3 gridL(W1 / 32, H1 / 32, B_);       // 38 x 11 x 16
    final_tiled<<<gridL, 256, 0, stream>>>(Ax, Ac, Ex, Ec, wb, b6, b7, oX, oC);
}

// Round 3
// 684.418 us; speedup vs baseline: 2.6198x; 1.2561x over previous
//
#include <hip/hip_runtime.h>
#include <hip/hip_bf16.h>

#define EPSF 1e-20f

typedef __hip_bfloat16 bf16;

__device__ __forceinline__ float b2f(bf16 v) { return __bfloat162float(v); }
__device__ __forceinline__ bf16 f2b(float v) { return __float2bfloat16(v); }
__device__ __forceinline__ float rcpf_(float v) { return __builtin_amdgcn_rcpf(v); }

// ---- problem dims (fixed by setup_inputs) ----
#define B_ 16
#define H1 352
#define W1 1216
#define H2 176
#define W2 608
#define H3 88
#define W3 304
#define H4 44
#define W4 152

// ---------------------------------------------------------------------------
// Weight prep: w = softplus(10*p)/10, per-out-ch kernel sums, AND inverse sums.
// wb layout (floats): wt1@0(50) s1@64(2) | wt2@96(100) s2@224(2) |
// wt3@256(100) s3@384(2) | wt4@416(72) s4@512(2) | wt5@544(72) s5@640(2) |
// wt6@672(72) s6@768(2) | wt7@800(2) s7@804(1) | is1@808(2) is2@810(2) is3@812(2)
// ---------------------------------------------------------------------------
__global__ void prep_weights(const float* w1, const float* w2, const float* w3,
                             const float* w4, const float* w5, const float* w6,
                             const float* w7, float* wb) {
    const float* ptrs[7] = {w1, w2, w3, w4, w5, w6, w7};
    const int ns[7]   = {50, 100, 100, 72, 72, 72, 2};
    const int offs[7] = {0, 96, 256, 416, 544, 672, 800};
    for (int it = 0; it < 7; ++it)
        for (int i = threadIdx.x; i < ns[it]; i += blockDim.x) {
            float z = 10.f * ptrs[it][i];
            float sp = (z > 20.f) ? z : log1pf(expf(z));
            wb[offs[it] + i] = sp * 0.1f;
        }
    __syncthreads();
    if (threadIdx.x == 0) {
        const int souts[7] = {2, 2, 2, 2, 2, 2, 1};
        const int klen[7]  = {25, 50, 50, 36, 36, 36, 2};
        const int soff[7]  = {64, 224, 384, 512, 640, 768, 804};
        for (int it = 0; it < 7; ++it)
            for (int o = 0; o < souts[it]; ++o) {
                float s = 0.f;
                for (int i = 0; i < klen[it]; ++i) s += wb[offs[it] + o * klen[it] + i];
                wb[soff[it] + o] = s;
            }
        for (int o = 0; o < 2; ++o) {
            wb[808 + o] = 1.f / wb[64 + o];    // 1/s1
            wb[810 + o] = 1.f / wb[224 + o];   // 1/s2
            wb[812 + o] = 1.f / wb[384 + o];   // 1/s3
        }
    }
}

// ---------------------------------------------------------------------------
// Fused L1 encoder + pool, v3:
//  - weights/biases/inv-sums read from wb/b* kernel args with compile-time
//    indices -> uniform s_load into SGPRs (OFF the LDS pipe); no sw[] buffer.
//  - 2x2 quad register blocking in ALL stages: 6x6 window = 36 LDS reads per
//    4 outputs (was 25/output). Arrays only with fully-unrolled indices.
//  - LDS: A1 26240 + U4 21312 = 47552 B -> 3 blocks/CU.
// ---------------------------------------------------------------------------
#define TDIM 32

__global__ __launch_bounds__(256) void fused_l1pool(
    const float* __restrict__ x0g, const float* __restrict__ c0g,
    const float* __restrict__ wb,
    const float* __restrict__ b1, const float* __restrict__ b2, const float* __restrict__ b3,
    bf16* __restrict__ Axg, bf16* __restrict__ Acg,
    bf16* __restrict__ P1x, bf16* __restrict__ P1c) {

    __shared__ float4 A1[40 * 41];   // stage1 out (p0,c0,p1,c1)
    __shared__ float4 U4[36 * 37];   // stage0 tile (float2 view) then stage2 out
    float2* U2 = (float2*)U4;        // 44 rows x stride 45 = 1980 float2 <= 2664

    const int tid = threadIdx.x;
    const int base_h = blockIdx.y * TDIM;
    const int base_w = blockIdx.x * TDIM;
    const int b = blockIdx.z;
    const float* xp = x0g + (long)b * (H1 * W1);
    const float* cp = c0g + (long)b * (H1 * W1);

    // stage 0: 44x44 (p,c) tile at origin (-6,-6), zero OOB.
    for (int i = tid; i < 44 * 44; i += 256) {
        int r = i / 44, c = i % 44;
        int gh = base_h - 6 + r, gw = base_w - 6 + c;
        float xv = 0.f, cv = 0.f;
        if (gh >= 0 && gh < H1 && gw >= 0 && gw < W1) {
            long o = (long)gh * W1 + gw;
            xv = xp[o]; cv = cp[o];
        }
        U2[r * 45 + c] = make_float2(xv * cv, cv);
    }
    __syncthreads();

    // stage 1: conv1 (CIN=1), 40x40 outputs (origin -4), 20x20 quads.
    {
        const float is0 = wb[808], is1 = wb[809];
        const float bb0 = b1[0], bb1 = b1[1];
        for (int i = tid; i < 400; i += 256) {
            int qr = i / 20, qc = i % 20;
            int r0 = 2 * qr, c0 = 2 * qc;
            float acc[2][2][4];
            #pragma unroll
            for (int a = 0; a < 2; ++a)
                #pragma unroll
                for (int o = 0; o < 2; ++o)
                    #pragma unroll
                    for (int k = 0; k < 4; ++k) acc[a][o][k] = 0.f;
            #pragma unroll
            for (int tr = 0; tr < 6; ++tr) {
                float2 t[6];
                #pragma unroll
                for (int j = 0; j < 6; ++j) t[j] = U2[(r0 + tr) * 45 + c0 + j];
                #pragma unroll
                for (int orr = 0; orr < 2; ++orr) {
                    const int dh = tr - orr;
                    if (dh < 0 || dh > 4) continue;    // compile-time after unroll
                    #pragma unroll
                    for (int dw = 0; dw < 5; ++dw) {
                        float wA = wb[dh * 5 + dw];
                        float wB = wb[25 + dh * 5 + dw];
                        #pragma unroll
                        for (int oc = 0; oc < 2; ++oc) {
                            float2 v = t[dw + oc];
                            acc[orr][oc][0] = fmaf(wA, v.x, acc[orr][oc][0]);
                            acc[orr][oc][1] = fmaf(wA, v.y, acc[orr][oc][1]);
                            acc[orr][oc][2] = fmaf(wB, v.x, acc[orr][oc][2]);
                            acc[orr][oc][3] = fmaf(wB, v.y, acc[orr][oc][3]);
                        }
                    }
                }
            }
            #pragma unroll
            for (int orr = 0; orr < 2; ++orr)
                #pragma unroll
                for (int oc = 0; oc < 2; ++oc) {
                    int r = r0 + orr, cc = c0 + oc;
                    int gh = base_h - 4 + r, gw = base_w - 4 + cc;
                    float4 out = make_float4(0.f, 0.f, 0.f, 0.f);
                    if (gh >= 0 && gh < H1 && gw >= 0 && gw < W1) {
                        float n0 = acc[orr][oc][0], d0 = acc[orr][oc][1];
                        float n1 = acc[orr][oc][2], d1 = acc[orr][oc][3];
                        float c0v = d0 * is0, x0v = n0 * rcpf_(d0 + EPSF) + bb0;
                        float c1v = d1 * is1, x1v = n1 * rcpf_(d1 + EPSF) + bb1;
                        out = make_float4(x0v * c0v, c0v, x1v * c1v, c1v);
                    }
                    A1[r * 41 + cc] = out;
                }
        }
    }
    __syncthreads();   // A1 ready; stage0 data dead -> U4 reusable

    // stage 2: conv2 (CIN=2), 36x36 outputs (origin -2), 18x18 quads.
    {
        const float is0 = wb[810], is1 = wb[811];
        const float bb0 = b2[0], bb1 = b2[1];
        for (int i = tid; i < 324; i += 256) {
            int qr = i / 18, qc = i % 18;
            int r0 = 2 * qr, c0 = 2 * qc;
            float acc[2][2][4];
            #pragma unroll
            for (int a = 0; a < 2; ++a)
                #pragma unroll
                for (int o = 0; o < 2; ++o)
                    #pragma unroll
                    for (int k = 0; k < 4; ++k) acc[a][o][k] = 0.f;
            #pragma unroll
            for (int tr = 0; tr < 6; ++tr) {
                float4 t[6];
                #pragma unroll
                for (int j = 0; j < 6; ++j) t[j] = A1[(r0 + tr) * 41 + c0 + j];
                #pragma unroll
                for (int orr = 0; orr < 2; ++orr) {
                    const int dh = tr - orr;
                    if (dh < 0 || dh > 4) continue;
                    #pragma unroll
                    for (int dw = 0; dw < 5; ++dw) {
                        const int k = dh * 5 + dw;
                        float wa0 = wb[96 + k],  wc0 = wb[121 + k];
                        float wa1 = wb[146 + k], wc1 = wb[171 + k];
                        #pragma unroll
                        for (int oc = 0; oc < 2; ++oc) {
                            float4 v = t[dw + oc];
                            acc[orr][oc][0] = fmaf(wa0, v.x, fmaf(wc0, v.z, acc[orr][oc][0]));
                            acc[orr][oc][1] = fmaf(wa0, v.y, fmaf(wc0, v.w, acc[orr][oc][1]));
                            acc[orr][oc][2] = fmaf(wa1, v.x, fmaf(wc1, v.z, acc[orr][oc][2]));
                            acc[orr][oc][3] = fmaf(wa1, v.y, fmaf(wc1, v.w, acc[orr][oc][3]));
                        }
                    }
                }
            }
            #pragma unroll
            for (int orr = 0; orr < 2; ++orr)
                #pragma unroll
                for (int oc = 0; oc < 2; ++oc) {
                    int r = r0 + orr, cc = c0 + oc;
                    int gh = base_h - 2 + r, gw = base_w - 2 + cc;
                    float4 out = make_float4(0.f, 0.f, 0.f, 0.f);
                    if (gh >= 0 && gh < H1 && gw >= 0 && gw < W1) {
                        float n0 = acc[orr][oc][0], d0 = acc[orr][oc][1];
                        float n1 = acc[orr][oc][2], d1 = acc[orr][oc][3];
                        float c0v = d0 * is0, x0v = n0 * rcpf_(d0 + EPSF) + bb0;
                        float c1v = d1 * is1, x1v = n1 * rcpf_(d1 + EPSF) + bb1;
                        out = make_float4(x0v * c0v, c0v, x1v * c1v, c1v);
                    }
                    U4[r * 37 + cc] = out;
                }
        }
    }
    __syncthreads();

    // stage 3: conv3, one 2x2 quad per thread (16x16 quads), 6x6 window.
    {
        const float is0 = wb[812], is1 = wb[813];
        const float bb0 = b3[0], bb1 = b3[1];
        const int pr = tid >> 4, pc = tid & 15;
        const int r0 = 2 * pr, c0 = 2 * pc;
        float acc[2][2][4];
        #pragma unroll
        for (int a = 0; a < 2; ++a)
            #pragma unroll
            for (int o = 0; o < 2; ++o)
                #pragma unroll
                for (int k = 0; k < 4; ++k) acc[a][o][k] = 0.f;
        #pragma unroll
        for (int tr = 0; tr < 6; ++tr) {
            float4 t[6];
            #pragma unroll
            for (int j = 0; j < 6; ++j) t[j] = U4[(r0 + tr) * 37 + c0 + j];
            #pragma unroll
            for (int orr = 0; orr < 2; ++orr) {
                const int dh = tr - orr;
                if (dh < 0 || dh > 4) continue;
                #pragma unroll
                for (int dw = 0; dw < 5; ++dw) {
                    const int k = dh * 5 + dw;
                    float wa0 = wb[256 + k], wc0 = wb[281 + k];
                    float wa1 = wb[306 + k], wc1 = wb[331 + k];
                    #pragma unroll
                    for (int oc = 0; oc < 2; ++oc) {
                        float4 v = t[dw + oc];
                        acc[orr][oc][0] = fmaf(wa0, v.x, fmaf(wc0, v.z, acc[orr][oc][0]));
                        acc[orr][oc][1] = fmaf(wa0, v.y, fmaf(wc0, v.w, acc[orr][oc][1]));
                        acc[orr][oc][2] = fmaf(wa1, v.x, fmaf(wc1, v.z, acc[orr][oc][2]));
                        acc[orr][oc][3] = fmaf(wa1, v.y, fmaf(wc1, v.w, acc[orr][oc][3]));
                    }
                }
            }
        }
        float xv[2][4], cv[2][4];
        #pragma unroll
        for (int orr = 0; orr < 2; ++orr)
            #pragma unroll
            for (int oc = 0; oc < 2; ++oc) {
                int q = orr * 2 + oc;
                float n0 = acc[orr][oc][0], d0 = acc[orr][oc][1];
                float n1 = acc[orr][oc][2], d1 = acc[orr][oc][3];
                xv[0][q] = n0 * rcpf_(d0 + EPSF) + bb0;
                xv[1][q] = n1 * rcpf_(d1 + EPSF) + bb1;
                cv[0][q] = d0 * is0;
                cv[1][q] = d1 * is1;
            }
        int fh = base_h + r0, fw = base_w + c0;
        int ph = (base_h >> 1) + pr, pw = (base_w >> 1) + pc;
        #pragma unroll
        for (int ch = 0; ch < 2; ++ch) {
            long o0 = (long)(b * 2 + ch) * (H1 * W1) + (long)fh * W1 + fw;
            __hip_bfloat162 v0, v1;
            v0.x = f2b(xv[ch][0]); v0.y = f2b(xv[ch][1]);
            v1.x = f2b(xv[ch][2]); v1.y = f2b(xv[ch][3]);
            *reinterpret_cast<__hip_bfloat162*>(Axg + o0) = v0;
            *reinterpret_cast<__hip_bfloat162*>(Axg + o0 + W1) = v1;
            v0.x = f2b(cv[ch][0]); v0.y = f2b(cv[ch][1]);
            v1.x = f2b(cv[ch][2]); v1.y = f2b(cv[ch][3]);
            *reinterpret_cast<__hip_bfloat162*>(Acg + o0) = v0;
            *reinterpret_cast<__hip_bfloat162*>(Acg + o0 + W1) = v1;
            int sel = 0; float cm = cv[ch][0];
            if (cv[ch][1] > cm) { cm = cv[ch][1]; sel = 1; }
            if (cv[ch][2] > cm) { cm = cv[ch][2]; sel = 2; }
            if (cv[ch][3] > cm) { cm = cv[ch][3]; sel = 3; }
            long o = (long)(b * 2 + ch) * (H2 * W2) + (long)ph * W2 + pw;
            P1c[o] = f2b(cm * 0.25f);
            P1x[o] = f2b(xv[ch][sel]);
        }
    }
}

// ---------------------------------------------------------------------------
// Fused L2: P1 -> conv2(w2,b2) -> conv3(w3,b3) -> D (full) + 2x2 pool -> P2.
// Structural clone of fused_l1pool stages 0/2/3. Tile 32x32, halo 4.
// Per-output bounds guards (H2=176 -> 5.5 tiles vertically).
// ---------------------------------------------------------------------------
__global__ __launch_bounds__(256) void fused_l2(
    const bf16* __restrict__ P1x, const bf16* __restrict__ P1c,
    const float* __restrict__ wb,
    const float* __restrict__ b2, const float* __restrict__ b3,
    bf16* __restrict__ Dx, bf16* __restrict__ Dc,
    bf16* __restrict__ P2x, bf16* __restrict__ P2c) {

    __shared__ float4 T0[40 * 41];   // input tile (p0,c0,p1,c1)
    __shared__ float4 T1[36 * 37];   // conv2 out

    const int tid = threadIdx.x;
    const int base_h = blockIdx.y * 32;
    const int base_w = blockIdx.x * 32;
    const int b = blockIdx.z;
    const long pl = (long)H2 * W2;
    const bf16* xp0 = P1x + (long)(b * 2) * pl;
    const bf16* cp0 = P1c + (long)(b * 2) * pl;

    // stage 0: 40x40 tile at origin (-4,-4), both channels, zero OOB.
    for (int i = tid; i < 40 * 40; i += 256) {
        int r = i / 40, c = i % 40;
        int gh = base_h - 4 + r, gw = base_w - 4 + c;
        float4 v = make_float4(0.f, 0.f, 0.f, 0.f);
        if (gh >= 0 && gh < H2 && gw >= 0 && gw < W2) {
            long o = (long)gh * W2 + gw;
            float xa = b2f(xp0[o]),      ca = b2f(cp0[o]);
            float xb = b2f(xp0[o + pl]), cb = b2f(cp0[o + pl]);
            v = make_float4(xa * ca, ca, xb * cb, cb);
        }
        T0[r * 41 + c] = v;
    }
    __syncthreads();

    // stage 1: conv w2 -> 36x36 (origin -2), 18x18 quads.
    {
        const float is0 = wb[810], is1 = wb[811];
        const float bb0 = b2[0], bb1 = b2[1];
        for (int i = tid; i < 324; i += 256) {
            int qr = i / 18, qc = i % 18;
            int r0 = 2 * qr, c0 = 2 * qc;
            float acc[2][2][4];
            #pragma unroll
            for (int a = 0; a < 2; ++a)
                #pragma unroll
                for (int o = 0; o < 2; ++o)
                    #pragma unroll
                    for (int k = 0; k < 4; ++k) acc[a][o][k] = 0.f;
            #pragma unroll
            for (int tr = 0; tr < 6; ++tr) {
                float4 t[6];
                #pragma unroll
                for (int j = 0; j < 6; ++j) t[j] = T0[(r0 + tr) * 41 + c0 + j];
                #pragma unroll
                for (int orr = 0; orr < 2; ++orr) {
                    const int dh = tr - orr;
                    if (dh < 0 || dh > 4) continue;
                    #pragma unroll
                    for (int dw = 0; dw < 5; ++dw) {
                        const int k = dh * 5 + dw;
                        float wa0 = wb[96 + k],  wc0 = wb[121 + k];
                        float wa1 = wb[146 + k], wc1 = wb[171 + k];
                        #pragma unroll
                        for (int oc = 0; oc < 2; ++oc) {
                            float4 v = t[dw + oc];
                            acc[orr][oc][0] = fmaf(wa0, v.x, fmaf(wc0, v.z, acc[orr][oc][0]));
                            acc[orr][oc][1] = fmaf(wa0, v.y, fmaf(wc0, v.w, acc[orr][oc][1]));
                            acc[orr][oc][2] = fmaf(wa1, v.x, fmaf(wc1, v.z, acc[orr][oc][2]));
                            acc[orr][oc][3] = fmaf(wa1, v.y, fmaf(wc1, v.w, acc[orr][oc][3]));
                        }
                    }
                }
            }
            #pragma unroll
            for (int orr = 0; orr < 2; ++orr)
                #pragma unroll
                for (int oc = 0; oc < 2; ++oc) {
                    int r = r0 + orr, cc = c0 + oc;
                    int gh = base_h - 2 + r, gw = base_w - 2 + cc;
                    float4 out = make_float4(0.f, 0.f, 0.f, 0.f);
                    if (gh >= 0 && gh < H2 && gw >= 0 && gw < W2) {
                        float n0 = acc[orr][oc][0], d0 = acc[orr][oc][1];
                        float n1 = acc[orr][oc][2], d1 = acc[orr][oc][3];
                        float c0v = d0 * is0, x0v = n0 * rcpf_(d0 + EPSF) + bb0;
                        float c1v = d1 * is1, x1v = n1 * rcpf_(d1 + EPSF) + bb1;
                        out = make_float4(x0v * c0v, c0v, x1v * c1v, c1v);
                    }
                    T1[r * 37 + cc] = out;
                }
        }
    }
    __syncthreads();

    // stage 2: conv w3, one 2x2 quad per thread; write D + pooled P2 (guarded).
    {
        const float is0 = wb[812], is1 = wb[813];
        const float bb0 = b3[0], bb1 = b3[1];
        const int pr = tid >> 4, pc = tid & 15;
        const int r0 = 2 * pr, c0 = 2 * pc;
        float acc[2][2][4];
        #pragma unroll
        for (int a = 0; a < 2; ++a)
            #pragma unroll
            for (int o = 0; o < 2; ++o)
                #pragma unroll
                for (int k = 0; k < 4; ++k) acc[a][o][k] = 0.f;
        #pragma unroll
        for (int tr = 0; tr < 6; ++tr) {
            float4 t[6];
            #pragma unroll
            for (int j = 0; j < 6; ++j) t[j] = T1[(r0 + tr) * 37 + c0 + j];
            #pragma unroll
            for (int orr = 0; orr < 2; ++orr) {
                const int dh = tr - orr;
                if (dh < 0 || dh > 4) continue;
                #pragma unroll
                for (int dw = 0; dw < 5; ++dw) {
                    const int k = dh * 5 + dw;
                    float wa0 = wb[256 + k], wc0 = wb[281 + k];
                    float wa1 = wb[306 + k], wc1 = wb[331 + k];
                    #pragma unroll
                    for (int oc = 0; oc < 2; ++oc) {
                        float4 v = t[dw + oc];
                        acc[orr][oc][0] = fmaf(wa0, v.x, fmaf(wc0, v.z, acc[orr][oc][0]));
                        acc[orr][oc][1] = fmaf(wa0, v.y, fmaf(wc0, v.w, acc[orr][oc][1]));
                        acc[orr][oc][2] = fmaf(wa1, v.x, fmaf(wc1, v.z, acc[orr][oc][2]));
                        acc[orr][oc][3] = fmaf(wa1, v.y, fmaf(wc1, v.w, acc[orr][oc][3]));
                    }
                }
            }
        }
        int fh = base_h + r0, fw = base_w + c0;
        if (fh < H2) {     // fh even, H2 even -> fh+1 < H2 too; fw always in-bounds
            float xv[2][4], cv[2][4];
            #pragma unroll
            for (int orr = 0; orr < 2; ++orr)
                #pragma unroll
                for (int oc = 0; oc < 2; ++oc) {
                    int q = orr * 2 + oc;
                    float n0 = acc[orr][oc][0], d0 = acc[orr][oc][1];
                    float n1 = acc[orr][oc][2], d1 = acc[orr][oc][3];
                    xv[0][q] = n0 * rcpf_(d0 + EPSF) + bb0;
                    xv[1][q] = n1 * rcpf_(d1 + EPSF) + bb1;
                    cv[0][q] = d0 * is0;
                    cv[1][q] = d1 * is1;
                }
            int ph = (base_h >> 1) + pr, pw = (base_w >> 1) + pc;
            #pragma unroll
            for (int ch = 0; ch < 2; ++ch) {
                long o0 = (long)(b * 2 + ch) * pl + (long)fh * W2 + fw;
                __hip_bfloat162 v0, v1;
                v0.x = f2b(xv[ch][0]); v0.y = f2b(xv[ch][1]);
                v1.x = f2b(xv[ch][2]); v1.y = f2b(xv[ch][3]);
                *reinterpret_cast<__hip_bfloat162*>(Dx + o0) = v0;
                *reinterpret_cast<__hip_bfloat162*>(Dx + o0 + W2) = v1;
                v0.x = f2b(cv[ch][0]); v0.y = f2b(cv[ch][1]);
                v1.x = f2b(cv[ch][2]); v1.y = f2b(cv[ch][3]);
                *reinterpret_cast<__hip_bfloat162*>(Dc + o0) = v0;
                *reinterpret_cast<__hip_bfloat162*>(Dc + o0 + W2) = v1;
                int sel = 0; float cm = cv[ch][0];
                if (cv[ch][1] > cm) { cm = cv[ch][1]; sel = 1; }
                if (cv[ch][2] > cm) { cm = cv[ch][2]; sel = 2; }
                if (cv[ch][3] > cm) { cm = cv[ch][3]; sel = 3; }
                long o = (long)(b * 2 + ch) * (H3 * W3) + (long)ph * W3 + pw;
                P2c[o] = f2b(cm * 0.25f);
                P2x[o] = f2b(xv[ch][sel]);
            }
        }
    }
}

// ---------------------------------------------------------------------------
// 5x5 pad2 nconv, 2 in ch -> 2 out ch, bf16 I/O, fp32 accumulation. (L3/L4)
// ---------------------------------------------------------------------------
__global__ void nconv5_c2(const bf16* __restrict__ xin, const bf16* __restrict__ cin,
                          const float* __restrict__ wt, const float* __restrict__ sb,
                          const float* __restrict__ bias,
                          bf16* __restrict__ xout, bf16* __restrict__ cout,
                          int H, int W) {
    __shared__ float sw[104];
    for (int i = threadIdx.x; i < 100; i += blockDim.x) sw[i] = wt[i];
    if (threadIdx.x < 2) {
        sw[100 + threadIdx.x] = sb[threadIdx.x];
        sw[102 + threadIdx.x] = bias[threadIdx.x];
    }
    __syncthreads();
    int idx = blockIdx.x * blockDim.x + threadIdx.x;
    int total = B_ * H * W;
    if (idx >= total) return;
    int w = idx % W; int t = idx / W; int h = t % H; int b = t / H;
    float nom0 = 0, den0 = 0, nom1 = 0, den1 = 0;
    #pragma unroll
    for (int ci = 0; ci < 2; ++ci) {
        const bf16* xp = xin + (long)(b * 2 + ci) * H * W;
        const bf16* cp = cin + (long)(b * 2 + ci) * H * W;
        #pragma unroll
        for (int dh = 0; dh < 5; ++dh) {
            int ih = h + dh - 2;
            if (ih < 0 || ih >= H) continue;
            #pragma unroll
            for (int dw = 0; dw < 5; ++dw) {
                int iw = w + dw - 2;
                if (iw < 0 || iw >= W) continue;
                float c = b2f(cp[ih * W + iw]);
                float x = b2f(xp[ih * W + iw]);
                float p = x * c;
                float w0 = sw[ci * 25 + dh * 5 + dw];
                float w1 = sw[50 + ci * 25 + dh * 5 + dw];
                nom0 = fmaf(w0, p, nom0); den0 = fmaf(w0, c, den0);
                nom1 = fmaf(w1, p, nom1); den1 = fmaf(w1, c, den1);
            }
        }
    }
    long o0 = (long)(b * 2) * H * W + h * W + w;
    long o1 = o0 + H * W;
    xout[o0] = f2b(nom0 / (den0 + EPSF) + sw[102]);
    xout[o1] = f2b(nom1 / (den1 + EPSF) + sw[103]);
    cout[o0] = f2b(den0 / sw[100]);
    cout[o1] = f2b(den1 / sw[101]);
}

// ---------------------------------------------------------------------------
// 2x2 max-pool on conf (first-max, row-major), gather x at argmax, conf/4.
// ---------------------------------------------------------------------------
__global__ void pool_ds2(const bf16* __restrict__ cin, const bf16* __restrict__ xin,
                         bf16* __restrict__ cout, bf16* __restrict__ xout,
                         int H, int W) {
    int Ho = H / 2, Wo = W / 2;
    int idx = blockIdx.x * blockDim.x + threadIdx.x;
    int total = B_ * 2 * Ho * Wo;
    if (idx >= total) return;
    int wo = idx % Wo; int t = idx / Wo; int ho = t % Ho; int bc = t / Ho;
    const bf16* cp = cin + (long)bc * H * W;
    const bf16* xp = xin + (long)bc * H * W;
    int base = (2 * ho) * W + 2 * wo;
    float c00 = b2f(cp[base]), c01 = b2f(cp[base + 1]);
    float c10 = b2f(cp[base + W]), c11 = b2f(cp[base + W + 1]);
    int sel = 0; float cm = c00;
    if (c01 > cm) { cm = c01; sel = 1; }
    if (c10 > cm) { cm = c10; sel = 2; }
    if (c11 > cm) { cm = c11; sel = 3; }
    bf16 xv = (sel == 0) ? xp[base] : (sel == 1) ? xp[base + 1]
            : (sel == 2) ? xp[base + W] : xp[base + W + 1];
    long o = (long)(bc * Ho + ho) * Wo + wo;
    cout[o] = f2b(cm * 0.25f);
    xout[o] = xv;
}

// ---------------------------------------------------------------------------
// Decoder nconv (mid-levels): 3x3 pad1 over concat(native [wch 0-1],
// up2(half) [wch 2-3]). bf16 I/O.
// ---------------------------------------------------------------------------
__global__ void nconv_cat(const bf16* __restrict__ nx, const bf16* __restrict__ nc,
                          const bf16* __restrict__ ux, const bf16* __restrict__ uc,
                          const float* __restrict__ wt, const float* __restrict__ sb,
                          const float* __restrict__ bias,
                          bf16* __restrict__ xout, bf16* __restrict__ cout,
                          int H, int W) {
    __shared__ float sw[76];
    for (int i = threadIdx.x; i < 72; i += blockDim.x) sw[i] = wt[i];
    if (threadIdx.x < 2) {
        sw[72 + threadIdx.x] = sb[threadIdx.x];
        sw[74 + threadIdx.x] = bias[threadIdx.x];
    }
    __syncthreads();
    int idx = blockIdx.x * blockDim.x + threadIdx.x;
    int total = B_ * H * W;
    if (idx >= total) return;
    int Hh = H / 2, Wh = W / 2;
    int w = idx % W; int t = idx / W; int h = t % H; int b = t / H;
    float nom0 = 0, den0 = 0, nom1 = 0, den1 = 0;
    #pragma unroll
    for (int dh = 0; dh < 3; ++dh) {
        int ih = h + dh - 1;
        if (ih < 0 || ih >= H) continue;
        #pragma unroll
        for (int dw = 0; dw < 3; ++dw) {
            int iw = w + dw - 1;
            if (iw < 0 || iw >= W) continue;
            int ih2 = ih >> 1, iw2 = iw >> 1;
            #pragma unroll
            for (int ci = 0; ci < 2; ++ci) {
                float c = b2f(nc[(long)(b * 2 + ci) * H * W + ih * W + iw]);
                float x = b2f(nx[(long)(b * 2 + ci) * H * W + ih * W + iw]);
                float p = x * c;
                float w0 = sw[ci * 9 + dh * 3 + dw];
                float w1 = sw[36 + ci * 9 + dh * 3 + dw];
                nom0 = fmaf(w0, p, nom0); den0 = fmaf(w0, c, den0);
                nom1 = fmaf(w1, p, nom1); den1 = fmaf(w1, c, den1);
                float c2 = b2f(uc[(long)(b * 2 + ci) * Hh * Wh + ih2 * Wh + iw2]);
                float x2 = b2f(ux[(long)(b * 2 + ci) * Hh * Wh + ih2 * Wh + iw2]);
                float p2 = x2 * c2;
                float v0 = sw[(2 + ci) * 9 + dh * 3 + dw];
                float v1 = sw[36 + (2 + ci) * 9 + dh * 3 + dw];
                nom0 = fmaf(v0, p2, nom0); den0 = fmaf(v0, c2, den0);
                nom1 = fmaf(v1, p2, nom1); den1 = fmaf(v1, c2, den1);
            }
        }
    }
    long o0 = (long)(b * 2) * H * W + h * W + w;
    long o1 = o0 + H * W;
    xout[o0] = f2b(nom0 / (den0 + EPSF) + sw[74]);
    xout[o1] = f2b(nom1 / (den1 + EPSF) + sw[75]);
    cout[o0] = f2b(den0 / sw[72]);
    cout[o1] = f2b(den1 / sw[73]);
}

// ---------------------------------------------------------------------------
// Final tiled kernel: cat(up2(x23) [wch 0-1], x1 [wch 2-3]) -> w6 3x3 nconv
// -> fused w7 1x1 nconv -> f32 d_out. 32x32 tile; A halo 1, E half-res tile
// 18x18. LDS ≈ 24 KB.
// ---------------------------------------------------------------------------
__global__ __launch_bounds__(256) void final_tiled(
    const bf16* __restrict__ Axg, const bf16* __restrict__ Acg,
    const bf16* __restrict__ Exg, const bf16* __restrict__ Ecg,
    const float* __restrict__ wb,
    const float* __restrict__ b6g, const float* __restrict__ b7g,
    float* __restrict__ oX, float* __restrict__ oC) {

    __shared__ float aX[2][34][34], aC[2][34][34];
    __shared__ float eX[2][18][18], eC[2][18][18];
    __shared__ float sw[80];
    // sw: w6@0(72) s6@72(2) b6@74(2) w7@76(2) s7@78 b7@79
    int tid = threadIdx.x;
    for (int i = tid; i < 80; i += 256) {
        float v;
        if (i < 72)       v = wb[672 + i];
        else if (i < 74)  v = wb[768 + (i - 72)];
        else if (i < 76)  v = b6g[i - 74];
        else if (i < 78)  v = wb[800 + (i - 76)];
        else if (i == 78) v = wb[804];
        else              v = b7g[0];
        sw[i] = v;
    }

    const int bh = blockIdx.y * 32, bw = blockIdx.x * 32, b = blockIdx.z;
    const int eh0 = (bh - 1) >> 1, ew0 = (bw - 1) >> 1;   // arithmetic shift: floor

    // A tile 34x34 (origin -1), zero OOB
    for (int i = tid; i < 34 * 34; i += 256) {
        int r = i / 34, c = i % 34;
        int gh = bh - 1 + r, gw = bw - 1 + c;
        bool in = (gh >= 0 && gh < H1 && gw >= 0 && gw < W1);
        #pragma unroll
        for (int ch = 0; ch < 2; ++ch) {
            long o = (long)(b * 2 + ch) * (H1 * W1) + gh * W1 + gw;
            aX[ch][r][c] = in ? b2f(Axg[o]) : 0.f;
            aC[ch][r][c] = in ? b2f(Acg[o]) : 0.f;
        }
    }
    // E tile 18x18 (origin eh0, ew0), zero OOB
    for (int i = tid; i < 18 * 18; i += 256) {
        int r = i / 18, c = i % 18;
        int gh = eh0 + r, gw = ew0 + c;
        bool in = (gh >= 0 && gh < H2 && gw >= 0 && gw < W2);
        #pragma unroll
        for (int ch = 0; ch < 2; ++ch) {
            long o = (long)(b * 2 + ch) * (H2 * W2) + gh * W2 + gw;
            eX[ch][r][c] = in ? b2f(Exg[o]) : 0.f;
            eC[ch][r][c] = in ? b2f(Ecg[o]) : 0.f;
        }
    }
    __syncthreads();

    for (int i = tid; i < 32 * 32; i += 256) {
        int r = i >> 5, c = i & 31;
        int gh = bh + r, gw = bw + c;
        float n0 = 0, d0 = 0, n1 = 0, d1 = 0;
        #pragma unroll
        for (int dh = 0; dh < 3; ++dh) {
            int ih = gh - 1 + dh;
            if (ih < 0 || ih >= H1) continue;
            int lr = r + dh, le = (ih >> 1) - eh0;
            #pragma unroll
            for (int dw = 0; dw < 3; ++dw) {
                int iw = gw - 1 + dw;
                if (iw < 0 || iw >= W1) continue;
                int lc = c + dw, lw = (iw >> 1) - ew0;
                #pragma unroll
                for (int ci = 0; ci < 2; ++ci) {
                    float cE = eC[ci][le][lw];
                    float pE = eX[ci][le][lw] * cE;
                    float u0 = sw[ci * 9 + dh * 3 + dw];
                    float u1 = sw[36 + ci * 9 + dh * 3 + dw];
                    n0 = fmaf(u0, pE, n0); d0 = fmaf(u0, cE, d0);
                    n1 = fmaf(u1, pE, n1); d1 = fmaf(u1, cE, d1);
                    float cN = aC[ci][lr][lc];
                    float pN = aX[ci][lr][lc] * cN;
                    float v0 = sw[(2 + ci) * 9 + dh * 3 + dw];
                    float v1 = sw[36 + (2 + ci) * 9 + dh * 3 + dw];
                    n0 = fmaf(v0, pN, n0); d0 = fmaf(v0, cN, d0);
                    n1 = fmaf(v1, pN, n1); d1 = fmaf(v1, cN, d1);
                }
            }
        }
        float x0v = n0 / (d0 + EPSF) + sw[74];
        float x1v = n1 / (d1 + EPSF) + sw[75];
        float c0v = d0 / sw[72];
        float c1v = d1 / sw[73];
        float w70 = sw[76], w71 = sw[77];
        float den7 = fmaf(w70, c0v, w71 * c1v);
        float nom7 = fmaf(w70, x0v * c0v, w71 * (x1v * c1v));
        long o = (long)b * (H1 * W1) + gh * W1 + gw;
        oX[o] = nom7 / (den7 + EPSF) + sw[79];
        oC[o] = den7 / sw[78];
    }
}

extern "C" void kernel_launch(void* const* d_in, const int* in_sizes, int n_in,
                              void* d_out, int out_size, void* d_ws, size_t ws_size,
                              hipStream_t stream) {
    const float* x0 = (const float*)d_in[0];
    const float* c0 = (const float*)d_in[1];
    const float* w1 = (const float*)d_in[2];
    const float* b1 = (const float*)d_in[3];
    const float* w2 = (const float*)d_in[4];
    const float* b2 = (const float*)d_in[5];
    const float* w3 = (const float*)d_in[6];
    const float* b3 = (const float*)d_in[7];
    const float* w4 = (const float*)d_in[8];
    const float* b4 = (const float*)d_in[9];
    const float* w5 = (const float*)d_in[10];
    const float* b5 = (const float*)d_in[11];
    const float* w6 = (const float*)d_in[12];
    const float* b6 = (const float*)d_in[13];
    const float* w7 = (const float*)d_in[14];
    const float* b7 = (const float*)d_in[15];

    const int N1 = B_ * H1 * W1;            // 6,848,512
    const int N2 = N1 / 4, N3 = N1 / 16, N4 = N1 / 64;

    // ws: [wb 4KB][Ax 2N1][Ac 2N1][Ex 2N2][Ec 2N2] ≈ 69 MB
    float* wb = (float*)d_ws;
    bf16* Ax = (bf16*)((char*)d_ws + 4096);
    bf16* Ac = Ax + 2 * (long)N1;
    bf16* Ex = Ac + 2 * (long)N1;
    bf16* Ec = Ex + 2 * (long)N2;

    // d_out (2N1 f32 = 16N2 bf16) as bf16 scratch. No aliasing between any
    // kernel's inputs and outputs (fused_l2 reads P1, writes D+P2 disjoint).
    bf16* R = (bf16*)d_out;
    bf16* P1x = R;                   // [0, 2N2)
    bf16* P1c = R + 2 * (long)N2;    // [2N2, 4N2)
    bf16* Dx  = R + 4 * (long)N2;    // [4N2, 6N2)
    bf16* Dc  = R + 6 * (long)N2;    // [6N2, 8N2)
    bf16* C1  = R + 8 * (long)N2;    // carve region, 8N2 bf16 available
    bf16* P2x = C1;                  bf16* P2c = C1 + 2 * (long)N3;
    bf16* Gx  = C1 + 4 * (long)N3;   bf16* Gc  = C1 + 6 * (long)N3;
    bf16* P3x = C1 + 8 * (long)N3;   bf16* P3c = P3x + 2 * (long)N4;
    bf16* Ix  = P3x + 4 * (long)N4;  bf16* Ic  = Ix + 2 * (long)N4;
    bf16* Fx  = P3x + 8 * (long)N4;  bf16* Fc  = Fx + 2 * (long)N3;
    // end = 8N2 + 12N3 + 8N4 = 11.5N2 <= 16N2. OK.

    float* oX = (float*)d_out;
    float* oC = oX + (long)N1;

    prep_weights<<<1, 256, 0, stream>>>(w1, w2, w3, w4, w5, w6, w7, wb);

    // Fused L1 encoder + pool: x0,c0 -> A (ws) + P1
    dim3 gridF(W1 / TDIM, H1 / TDIM, B_);   // 38 x 11 x 16
    fused_l1pool<<<gridF, 256, 0, stream>>>(x0, c0, wb, b1, b2, b3, Ax, Ac, P1x, P1c);

    // Fused L2: P1 -> D (x2,c2) + P2 (pooled)
    dim3 gridL2(W2 / 32, (H2 + 31) / 32, B_);   // 19 x 6 x 16
    fused_l2<<<gridL2, 256, 0, stream>>>(P1x, P1c, wb, b2, b3, Dx, Dc, P2x, P2c);

    const int g3 = (B_ * H3 * W3 + 255) / 256;
    const int g4 = (B_ * H4 * W4 + 255) / 256;

    // L3
    nconv5_c2<<<g3, 256, 0, stream>>>(P2x, P2c, wb + 96, wb + 224, b2, Gx, Gc, H3, W3);   // G = x3,c3

    // L4
    pool_ds2<<<(B_ * 2 * H4 * W4 + 255) / 256, 256, 0, stream>>>(Gc, Gx, P3c, P3x, H3, W3);
    nconv5_c2<<<g4, 256, 0, stream>>>(P3x, P3c, wb + 96, wb + 224, b2, Ix, Ic, H4, W4);   // I = x4,c4

    // Decoder
    nconv_cat<<<g3, 256, 0, stream>>>(Gx, Gc, Ix, Ic, wb + 416, wb + 512, b4, Fx, Fc, H3, W3);  // F = x34
    nconv_cat<<<(B_ * H2 * W2 + 255) / 256, 256, 0, stream>>>(Dx, Dc, Fx, Fc, wb + 544, wb + 640, b5, Ex, Ec, H2, W2);  // E = x23 (ws)

    // Final: tiled w6+w7 -> f32 d_out (reads only ws; rewrites all of d_out)
    dim3 gridL(W1 / 32, H1 / 32, B_);       // 38 x 11 x 16
    final_tiled<<<gridL, 256, 0, stream>>>(Ax, Ac, Ex, Ec, wb, b6, b7, oX, oC);
}

// Round 4
// 448.109 us; speedup vs baseline: 4.0013x; 1.5273x over previous
//
#include <hip/hip_runtime.h>
#include <hip/hip_bf16.h>

#define EPSF 1e-20f
typedef __hip_bfloat16 bf16;
typedef unsigned int u32;

__device__ __forceinline__ float rcpf_(float v) { return __builtin_amdgcn_rcpf(v); }
__device__ __forceinline__ float bits2f(u32 b) { union { u32 i; float f; } u; u.i = b; return u.f; }
__device__ __forceinline__ float lo2f(u32 v) { return bits2f(v << 16); }
__device__ __forceinline__ float hi2f(u32 v) { return bits2f(v & 0xffff0000u); }
__device__ __forceinline__ u32 f2us(float f) {
    bf16 h = __float2bfloat16(f);
    unsigned short s;
    __builtin_memcpy(&s, &h, 2);
    return (u32)s;
}
// pixel pack: (x0,c0,x1,c1) as 4x bf16 in a uint2
__device__ __forceinline__ uint2 packpx(float x0, float c0, float x1, float c1) {
    return make_uint2(f2us(x0) | (f2us(c0) << 16), f2us(x1) | (f2us(c1) << 16));
}
// unpack to (p0,c0,p1,c1) with p = x*c
__device__ __forceinline__ float4 unpk(uint2 v) {
    float x0 = lo2f(v.x), c0 = hi2f(v.x), x1 = lo2f(v.y), c1 = hi2f(v.y);
    return make_float4(x0 * c0, c0, x1 * c1, c1);
}

// ---- problem dims (fixed by setup_inputs) ----
#define B_ 16
#define H1 352
#define W1 1216
#define H2 176
#define W2 608
#define H3 88
#define W3 304
#define H4 44
#define W4 152

// ---------------------------------------------------------------------------
// Weight prep: w = softplus(10*p)/10, per-out-ch kernel sums + inverse sums.
// wb floats: wt1@0(50) s1@64 | wt2@96(100) s2@224 | wt3@256(100) s3@384 |
// wt4@416(72) s4@512 | wt5@544(72) s5@640 | wt6@672(72) s6@768 |
// wt7@800(2) s7@804 | is1@808 is2@810 is3@812 is4@814 is5@816 is6@818 is7@820
// ---------------------------------------------------------------------------
__global__ void prep_weights(const float* w1, const float* w2, const float* w3,
                             const float* w4, const float* w5, const float* w6,
                             const float* w7, float* wb) {
    const float* ptrs[7] = {w1, w2, w3, w4, w5, w6, w7};
    const int ns[7]   = {50, 100, 100, 72, 72, 72, 2};
    const int offs[7] = {0, 96, 256, 416, 544, 672, 800};
    for (int it = 0; it < 7; ++it)
        for (int i = threadIdx.x; i < ns[it]; i += blockDim.x) {
            float z = 10.f * ptrs[it][i];
            float sp = (z > 20.f) ? z : log1pf(expf(z));
            wb[offs[it] + i] = sp * 0.1f;
        }
    __syncthreads();
    if (threadIdx.x == 0) {
        const int souts[7] = {2, 2, 2, 2, 2, 2, 1};
        const int klen[7]  = {25, 50, 50, 36, 36, 36, 2};
        const int soff[7]  = {64, 224, 384, 512, 640, 768, 804};
        for (int it = 0; it < 7; ++it)
            for (int o = 0; o < souts[it]; ++o) {
                float s = 0.f;
                for (int i = 0; i < klen[it]; ++i) s += wb[offs[it] + o * klen[it] + i];
                wb[soff[it] + o] = s;
            }
        for (int o = 0; o < 2; ++o) {
            wb[808 + o] = 1.f / wb[64 + o];
            wb[810 + o] = 1.f / wb[224 + o];
            wb[812 + o] = 1.f / wb[384 + o];
            wb[814 + o] = 1.f / wb[512 + o];
            wb[816 + o] = 1.f / wb[640 + o];
            wb[818 + o] = 1.f / wb[768 + o];
        }
        wb[820] = 1.f / wb[804];
    }
}

// ---------------------------------------------------------------------------
// Fused L1 encoder + pool (proven R3 structure), packed outputs:
// Apk (full-res pixel-packed x1,c1) + P1pk (pooled).
// ---------------------------------------------------------------------------
#define TDIM 32

__global__ __launch_bounds__(256) void fused_l1pool(
    const float* __restrict__ x0g, const float* __restrict__ c0g,
    const float* __restrict__ wb,
    const float* __restrict__ b1, const float* __restrict__ b2, const float* __restrict__ b3,
    uint2* __restrict__ Apk, uint2* __restrict__ P1pk) {

    __shared__ float4 A1[40 * 41];   // stage1 out (p0,c0,p1,c1)
    __shared__ float4 U4[36 * 37];   // stage0 tile (float2 view) then stage2 out
    float2* U2 = (float2*)U4;        // 44 rows x stride 45 = 1980 float2 <= 2664

    const int tid = threadIdx.x;
    const int base_h = blockIdx.y * TDIM;
    const int base_w = blockIdx.x * TDIM;
    const int b = blockIdx.z;
    const float* xp = x0g + (long)b * (H1 * W1);
    const float* cp = c0g + (long)b * (H1 * W1);

    // stage 0: 44x44 (p,c) tile at origin (-6,-6), zero OOB.
    for (int i = tid; i < 44 * 44; i += 256) {
        int r = i / 44, c = i % 44;
        int gh = base_h - 6 + r, gw = base_w - 6 + c;
        float xv = 0.f, cv = 0.f;
        if (gh >= 0 && gh < H1 && gw >= 0 && gw < W1) {
            long o = (long)gh * W1 + gw;
            xv = xp[o]; cv = cp[o];
        }
        U2[r * 45 + c] = make_float2(xv * cv, cv);
    }
    __syncthreads();

    // stage 1: conv1 (CIN=1), 40x40 outputs (origin -4), 20x20 quads.
    {
        const float is0 = wb[808], is1 = wb[809];
        const float bb0 = b1[0], bb1 = b1[1];
        for (int i = tid; i < 400; i += 256) {
            int qr = i / 20, qc = i % 20;
            int r0 = 2 * qr, c0 = 2 * qc;
            float acc[2][2][4];
            #pragma unroll
            for (int a = 0; a < 2; ++a)
                #pragma unroll
                for (int o = 0; o < 2; ++o)
                    #pragma unroll
                    for (int k = 0; k < 4; ++k) acc[a][o][k] = 0.f;
            #pragma unroll
            for (int tr = 0; tr < 6; ++tr) {
                float2 t[6];
                #pragma unroll
                for (int j = 0; j < 6; ++j) t[j] = U2[(r0 + tr) * 45 + c0 + j];
                #pragma unroll
                for (int orr = 0; orr < 2; ++orr) {
                    const int dh = tr - orr;
                    if (dh < 0 || dh > 4) continue;
                    #pragma unroll
                    for (int dw = 0; dw < 5; ++dw) {
                        float wA = wb[dh * 5 + dw];
                        float wB = wb[25 + dh * 5 + dw];
                        #pragma unroll
                        for (int oc = 0; oc < 2; ++oc) {
                            float2 v = t[dw + oc];
                            acc[orr][oc][0] = fmaf(wA, v.x, acc[orr][oc][0]);
                            acc[orr][oc][1] = fmaf(wA, v.y, acc[orr][oc][1]);
                            acc[orr][oc][2] = fmaf(wB, v.x, acc[orr][oc][2]);
                            acc[orr][oc][3] = fmaf(wB, v.y, acc[orr][oc][3]);
                        }
                    }
                }
            }
            #pragma unroll
            for (int orr = 0; orr < 2; ++orr)
                #pragma unroll
                for (int oc = 0; oc < 2; ++oc) {
                    int r = r0 + orr, cc = c0 + oc;
                    int gh = base_h - 4 + r, gw = base_w - 4 + cc;
                    float4 out = make_float4(0.f, 0.f, 0.f, 0.f);
                    if (gh >= 0 && gh < H1 && gw >= 0 && gw < W1) {
                        float n0 = acc[orr][oc][0], d0 = acc[orr][oc][1];
                        float n1 = acc[orr][oc][2], d1 = acc[orr][oc][3];
                        float c0v = d0 * is0, x0v = n0 * rcpf_(d0 + EPSF) + bb0;
                        float c1v = d1 * is1, x1v = n1 * rcpf_(d1 + EPSF) + bb1;
                        out = make_float4(x0v * c0v, c0v, x1v * c1v, c1v);
                    }
                    A1[r * 41 + cc] = out;
                }
        }
    }
    __syncthreads();

    // stage 2: conv2 (CIN=2), 36x36 outputs (origin -2), 18x18 quads.
    {
        const float is0 = wb[810], is1 = wb[811];
        const float bb0 = b2[0], bb1 = b2[1];
        for (int i = tid; i < 324; i += 256) {
            int qr = i / 18, qc = i % 18;
            int r0 = 2 * qr, c0 = 2 * qc;
            float acc[2][2][4];
            #pragma unroll
            for (int a = 0; a < 2; ++a)
                #pragma unroll
                for (int o = 0; o < 2; ++o)
                    #pragma unroll
                    for (int k = 0; k < 4; ++k) acc[a][o][k] = 0.f;
            #pragma unroll
            for (int tr = 0; tr < 6; ++tr) {
                float4 t[6];
                #pragma unroll
                for (int j = 0; j < 6; ++j) t[j] = A1[(r0 + tr) * 41 + c0 + j];
                #pragma unroll
                for (int orr = 0; orr < 2; ++orr) {
                    const int dh = tr - orr;
                    if (dh < 0 || dh > 4) continue;
                    #pragma unroll
                    for (int dw = 0; dw < 5; ++dw) {
                        const int k = dh * 5 + dw;
                        float wa0 = wb[96 + k],  wc0 = wb[121 + k];
                        float wa1 = wb[146 + k], wc1 = wb[171 + k];
                        #pragma unroll
                        for (int oc = 0; oc < 2; ++oc) {
                            float4 v = t[dw + oc];
                            acc[orr][oc][0] = fmaf(wa0, v.x, fmaf(wc0, v.z, acc[orr][oc][0]));
                            acc[orr][oc][1] = fmaf(wa0, v.y, fmaf(wc0, v.w, acc[orr][oc][1]));
                            acc[orr][oc][2] = fmaf(wa1, v.x, fmaf(wc1, v.z, acc[orr][oc][2]));
                            acc[orr][oc][3] = fmaf(wa1, v.y, fmaf(wc1, v.w, acc[orr][oc][3]));
                        }
                    }
                }
            }
            #pragma unroll
            for (int orr = 0; orr < 2; ++orr)
                #pragma unroll
                for (int oc = 0; oc < 2; ++oc) {
                    int r = r0 + orr, cc = c0 + oc;
                    int gh = base_h - 2 + r, gw = base_w - 2 + cc;
                    float4 out = make_float4(0.f, 0.f, 0.f, 0.f);
                    if (gh >= 0 && gh < H1 && gw >= 0 && gw < W1) {
                        float n0 = acc[orr][oc][0], d0 = acc[orr][oc][1];
                        float n1 = acc[orr][oc][2], d1 = acc[orr][oc][3];
                        float c0v = d0 * is0, x0v = n0 * rcpf_(d0 + EPSF) + bb0;
                        float c1v = d1 * is1, x1v = n1 * rcpf_(d1 + EPSF) + bb1;
                        out = make_float4(x0v * c0v, c0v, x1v * c1v, c1v);
                    }
                    U4[r * 37 + cc] = out;
                }
        }
    }
    __syncthreads();

    // stage 3: conv3, one 2x2 quad per thread; write Apk + pooled P1pk.
    {
        const float is0 = wb[812], is1 = wb[813];
        const float bb0 = b3[0], bb1 = b3[1];
        const int pr = tid >> 4, pc = tid & 15;
        const int r0 = 2 * pr, c0 = 2 * pc;
        float acc[2][2][4];
        #pragma unroll
        for (int a = 0; a < 2; ++a)
            #pragma unroll
            for (int o = 0; o < 2; ++o)
                #pragma unroll
                for (int k = 0; k < 4; ++k) acc[a][o][k] = 0.f;
        #pragma unroll
        for (int tr = 0; tr < 6; ++tr) {
            float4 t[6];
            #pragma unroll
            for (int j = 0; j < 6; ++j) t[j] = U4[(r0 + tr) * 37 + c0 + j];
            #pragma unroll
            for (int orr = 0; orr < 2; ++orr) {
                const int dh = tr - orr;
                if (dh < 0 || dh > 4) continue;
                #pragma unroll
                for (int dw = 0; dw < 5; ++dw) {
                    const int k = dh * 5 + dw;
                    float wa0 = wb[256 + k], wc0 = wb[281 + k];
                    float wa1 = wb[306 + k], wc1 = wb[331 + k];
                    #pragma unroll
                    for (int oc = 0; oc < 2; ++oc) {
                        float4 v = t[dw + oc];
                        acc[orr][oc][0] = fmaf(wa0, v.x, fmaf(wc0, v.z, acc[orr][oc][0]));
                        acc[orr][oc][1] = fmaf(wa0, v.y, fmaf(wc0, v.w, acc[orr][oc][1]));
                        acc[orr][oc][2] = fmaf(wa1, v.x, fmaf(wc1, v.z, acc[orr][oc][2]));
                        acc[orr][oc][3] = fmaf(wa1, v.y, fmaf(wc1, v.w, acc[orr][oc][3]));
                    }
                }
            }
        }
        float xv[2][4], cv[2][4];
        #pragma unroll
        for (int orr = 0; orr < 2; ++orr)
            #pragma unroll
            for (int oc = 0; oc < 2; ++oc) {
                int q = orr * 2 + oc;
                float n0 = acc[orr][oc][0], d0 = acc[orr][oc][1];
                float n1 = acc[orr][oc][2], d1 = acc[orr][oc][3];
                xv[0][q] = n0 * rcpf_(d0 + EPSF) + bb0;
                xv[1][q] = n1 * rcpf_(d1 + EPSF) + bb1;
                cv[0][q] = d0 * is0;
                cv[1][q] = d1 * is1;
            }
        int fh = base_h + r0, fw = base_w + c0;
        int ph = (base_h >> 1) + pr, pw = (base_w >> 1) + pc;
        uint2 q00 = packpx(xv[0][0], cv[0][0], xv[1][0], cv[1][0]);
        uint2 q01 = packpx(xv[0][1], cv[0][1], xv[1][1], cv[1][1]);
        uint2 q10 = packpx(xv[0][2], cv[0][2], xv[1][2], cv[1][2]);
        uint2 q11 = packpx(xv[0][3], cv[0][3], xv[1][3], cv[1][3]);
        long o0 = (long)b * (H1 * W1) + (long)fh * W1 + fw;
        *reinterpret_cast<uint4*>(Apk + o0)      = make_uint4(q00.x, q00.y, q01.x, q01.y);
        *reinterpret_cast<uint4*>(Apk + o0 + W1) = make_uint4(q10.x, q10.y, q11.x, q11.y);
        // pool per channel (f32 first-max, row-major; value-tracked, no dyn index)
        float cm0 = cv[0][0], xs0 = xv[0][0];
        if (cv[0][1] > cm0) { cm0 = cv[0][1]; xs0 = xv[0][1]; }
        if (cv[0][2] > cm0) { cm0 = cv[0][2]; xs0 = xv[0][2]; }
        if (cv[0][3] > cm0) { cm0 = cv[0][3]; xs0 = xv[0][3]; }
        float cm1 = cv[1][0], xs1 = xv[1][0];
        if (cv[1][1] > cm1) { cm1 = cv[1][1]; xs1 = xv[1][1]; }
        if (cv[1][2] > cm1) { cm1 = cv[1][2]; xs1 = xv[1][2]; }
        if (cv[1][3] > cm1) { cm1 = cv[1][3]; xs1 = xv[1][3]; }
        P1pk[(long)b * (H2 * W2) + (long)ph * W2 + pw] =
            packpx(xs0, cm0 * 0.25f, xs1, cm1 * 0.25f);
    }
}

// ---------------------------------------------------------------------------
// Fused L2: P1pk -> conv w2 -> conv w3 -> Dpk (full) + pooled P2pk.
// ---------------------------------------------------------------------------
__global__ __launch_bounds__(256) void fused_l2(
    const uint2* __restrict__ P1pk, const float* __restrict__ wb,
    const float* __restrict__ b2, const float* __restrict__ b3,
    uint2* __restrict__ Dpk, uint2* __restrict__ P2pk) {

    __shared__ float4 T0[40 * 41];
    __shared__ float4 T1[36 * 37];

    const int tid = threadIdx.x;
    const int base_h = blockIdx.y * 32;
    const int base_w = blockIdx.x * 32;
    const int b = blockIdx.z;
    const long pl = (long)H2 * W2;
    const uint2* ip = P1pk + (long)b * pl;

    for (int i = tid; i < 40 * 40; i += 256) {
        int r = i / 40, c = i % 40;
        int gh = base_h - 4 + r, gw = base_w - 4 + c;
        float4 v = make_float4(0.f, 0.f, 0.f, 0.f);
        if (gh >= 0 && gh < H2 && gw >= 0 && gw < W2)
            v = unpk(ip[(long)gh * W2 + gw]);
        T0[r * 41 + c] = v;
    }
    __syncthreads();

    // conv w2 -> 36x36 (origin -2), 18x18 quads.
    {
        const float is0 = wb[810], is1 = wb[811];
        const float bb0 = b2[0], bb1 = b2[1];
        for (int i = tid; i < 324; i += 256) {
            int qr = i / 18, qc = i % 18;
            int r0 = 2 * qr, c0 = 2 * qc;
            float acc[2][2][4];
            #pragma unroll
            for (int a = 0; a < 2; ++a)
                #pragma unroll
                for (int o = 0; o < 2; ++o)
                    #pragma unroll
                    for (int k = 0; k < 4; ++k) acc[a][o][k] = 0.f;
            #pragma unroll
            for (int tr = 0; tr < 6; ++tr) {
                float4 t[6];
                #pragma unroll
                for (int j = 0; j < 6; ++j) t[j] = T0[(r0 + tr) * 41 + c0 + j];
                #pragma unroll
                for (int orr = 0; orr < 2; ++orr) {
                    const int dh = tr - orr;
                    if (dh < 0 || dh > 4) continue;
                    #pragma unroll
                    for (int dw = 0; dw < 5; ++dw) {
                        const int k = dh * 5 + dw;
                        float wa0 = wb[96 + k],  wc0 = wb[121 + k];
                        float wa1 = wb[146 + k], wc1 = wb[171 + k];
                        #pragma unroll
                        for (int oc = 0; oc < 2; ++oc) {
                            float4 v = t[dw + oc];
                            acc[orr][oc][0] = fmaf(wa0, v.x, fmaf(wc0, v.z, acc[orr][oc][0]));
                            acc[orr][oc][1] = fmaf(wa0, v.y, fmaf(wc0, v.w, acc[orr][oc][1]));
                            acc[orr][oc][2] = fmaf(wa1, v.x, fmaf(wc1, v.z, acc[orr][oc][2]));
                            acc[orr][oc][3] = fmaf(wa1, v.y, fmaf(wc1, v.w, acc[orr][oc][3]));
                        }
                    }
                }
            }
            #pragma unroll
            for (int orr = 0; orr < 2; ++orr)
                #pragma unroll
                for (int oc = 0; oc < 2; ++oc) {
                    int r = r0 + orr, cc = c0 + oc;
                    int gh = base_h - 2 + r, gw = base_w - 2 + cc;
                    float4 out = make_float4(0.f, 0.f, 0.f, 0.f);
                    if (gh >= 0 && gh < H2 && gw >= 0 && gw < W2) {
                        float n0 = acc[orr][oc][0], d0 = acc[orr][oc][1];
                        float n1 = acc[orr][oc][2], d1 = acc[orr][oc][3];
                        float c0v = d0 * is0, x0v = n0 * rcpf_(d0 + EPSF) + bb0;
                        float c1v = d1 * is1, x1v = n1 * rcpf_(d1 + EPSF) + bb1;
                        out = make_float4(x0v * c0v, c0v, x1v * c1v, c1v);
                    }
                    T1[r * 37 + cc] = out;
                }
        }
    }
    __syncthreads();

    // conv w3 per quad; write Dpk + pooled P2pk.
    {
        const float is0 = wb[812], is1 = wb[813];
        const float bb0 = b3[0], bb1 = b3[1];
        const int pr = tid >> 4, pc = tid & 15;
        const int r0 = 2 * pr, c0 = 2 * pc;
        float acc[2][2][4];
        #pragma unroll
        for (int a = 0; a < 2; ++a)
            #pragma unroll
            for (int o = 0; o < 2; ++o)
                #pragma unroll
                for (int k = 0; k < 4; ++k) acc[a][o][k] = 0.f;
        #pragma unroll
        for (int tr = 0; tr < 6; ++tr) {
            float4 t[6];
            #pragma unroll
            for (int j = 0; j < 6; ++j) t[j] = T1[(r0 + tr) * 37 + c0 + j];
            #pragma unroll
            for (int orr = 0; orr < 2; ++orr) {
                const int dh = tr - orr;
                if (dh < 0 || dh > 4) continue;
                #pragma unroll
                for (int dw = 0; dw < 5; ++dw) {
                    const int k = dh * 5 + dw;
                    float wa0 = wb[256 + k], wc0 = wb[281 + k];
                    float wa1 = wb[306 + k], wc1 = wb[331 + k];
                    #pragma unroll
                    for (int oc = 0; oc < 2; ++oc) {
                        float4 v = t[dw + oc];
                        acc[orr][oc][0] = fmaf(wa0, v.x, fmaf(wc0, v.z, acc[orr][oc][0]));
                        acc[orr][oc][1] = fmaf(wa0, v.y, fmaf(wc0, v.w, acc[orr][oc][1]));
                        acc[orr][oc][2] = fmaf(wa1, v.x, fmaf(wc1, v.z, acc[orr][oc][2]));
                        acc[orr][oc][3] = fmaf(wa1, v.y, fmaf(wc1, v.w, acc[orr][oc][3]));
                    }
                }
            }
        }
        int fh = base_h + r0, fw = base_w + c0;
        if (fh < H2) {
            float xv[2][4], cv[2][4];
            #pragma unroll
            for (int orr = 0; orr < 2; ++orr)
                #pragma unroll
                for (int oc = 0; oc < 2; ++oc) {
                    int q = orr * 2 + oc;
                    float n0 = acc[orr][oc][0], d0 = acc[orr][oc][1];
                    float n1 = acc[orr][oc][2], d1 = acc[orr][oc][3];
                    xv[0][q] = n0 * rcpf_(d0 + EPSF) + bb0;
                    xv[1][q] = n1 * rcpf_(d1 + EPSF) + bb1;
                    cv[0][q] = d0 * is0;
                    cv[1][q] = d1 * is1;
                }
            uint2 q00 = packpx(xv[0][0], cv[0][0], xv[1][0], cv[1][0]);
            uint2 q01 = packpx(xv[0][1], cv[0][1], xv[1][1], cv[1][1]);
            uint2 q10 = packpx(xv[0][2], cv[0][2], xv[1][2], cv[1][2]);
            uint2 q11 = packpx(xv[0][3], cv[0][3], xv[1][3], cv[1][3]);
            long o0 = (long)b * pl + (long)fh * W2 + fw;
            *reinterpret_cast<uint4*>(Dpk + o0)      = make_uint4(q00.x, q00.y, q01.x, q01.y);
            *reinterpret_cast<uint4*>(Dpk + o0 + W2) = make_uint4(q10.x, q10.y, q11.x, q11.y);
            float cm0 = cv[0][0], xs0 = xv[0][0];
            if (cv[0][1] > cm0) { cm0 = cv[0][1]; xs0 = xv[0][1]; }
            if (cv[0][2] > cm0) { cm0 = cv[0][2]; xs0 = xv[0][2]; }
            if (cv[0][3] > cm0) { cm0 = cv[0][3]; xs0 = xv[0][3]; }
            float cm1 = cv[1][0], xs1 = xv[1][0];
            if (cv[1][1] > cm1) { cm1 = cv[1][1]; xs1 = xv[1][1]; }
            if (cv[1][2] > cm1) { cm1 = cv[1][2]; xs1 = xv[1][2]; }
            if (cv[1][3] > cm1) { cm1 = cv[1][3]; xs1 = xv[1][3]; }
            int ph = (base_h >> 1) + pr, pw = (base_w >> 1) + pc;
            P2pk[(long)b * (H3 * W3) + (long)ph * W3 + pw] =
                packpx(xs0, cm0 * 0.25f, xs1, cm1 * 0.25f);
        }
    }
}

// ---------------------------------------------------------------------------
// Fused L3: P2pk -> conv w2 -> Gpk (full) + pooled P3pk. Tile 32x32, halo 2.
// ---------------------------------------------------------------------------
__global__ __launch_bounds__(256) void fused_l3(
    const uint2* __restrict__ P2pk, const float* __restrict__ wb,
    const float* __restrict__ b2,
    uint2* __restrict__ Gpk, uint2* __restrict__ P3pk) {

    __shared__ float4 T0[36 * 37];

    const int tid = threadIdx.x;
    const int base_h = blockIdx.y * 32;
    const int base_w = blockIdx.x * 32;
    const int b = blockIdx.z;
    const long pl = (long)H3 * W3;
    const uint2* ip = P2pk + (long)b * pl;

    for (int i = tid; i < 36 * 36; i += 256) {
        int r = i / 36, c = i % 36;
        int gh = base_h - 2 + r, gw = base_w - 2 + c;
        float4 v = make_float4(0.f, 0.f, 0.f, 0.f);
        if (gh >= 0 && gh < H3 && gw >= 0 && gw < W3)
            v = unpk(ip[(long)gh * W3 + gw]);
        T0[r * 37 + c] = v;
    }
    __syncthreads();

    {
        const float is0 = wb[810], is1 = wb[811];
        const float bb0 = b2[0], bb1 = b2[1];
        const int pr = tid >> 4, pc = tid & 15;
        const int r0 = 2 * pr, c0 = 2 * pc;
        float acc[2][2][4];
        #pragma unroll
        for (int a = 0; a < 2; ++a)
            #pragma unroll
            for (int o = 0; o < 2; ++o)
                #pragma unroll
                for (int k = 0; k < 4; ++k) acc[a][o][k] = 0.f;
        #pragma unroll
        for (int tr = 0; tr < 6; ++tr) {
            float4 t[6];
            #pragma unroll
            for (int j = 0; j < 6; ++j) t[j] = T0[(r0 + tr) * 37 + c0 + j];
            #pragma unroll
            for (int orr = 0; orr < 2; ++orr) {
                const int dh = tr - orr;
                if (dh < 0 || dh > 4) continue;
                #pragma unroll
                for (int dw = 0; dw < 5; ++dw) {
                    const int k = dh * 5 + dw;
                    float wa0 = wb[96 + k],  wc0 = wb[121 + k];
                    float wa1 = wb[146 + k], wc1 = wb[171 + k];
                    #pragma unroll
                    for (int oc = 0; oc < 2; ++oc) {
                        float4 v = t[dw + oc];
                        acc[orr][oc][0] = fmaf(wa0, v.x, fmaf(wc0, v.z, acc[orr][oc][0]));
                        acc[orr][oc][1] = fmaf(wa0, v.y, fmaf(wc0, v.w, acc[orr][oc][1]));
                        acc[orr][oc][2] = fmaf(wa1, v.x, fmaf(wc1, v.z, acc[orr][oc][2]));
                        acc[orr][oc][3] = fmaf(wa1, v.y, fmaf(wc1, v.w, acc[orr][oc][3]));
                    }
                }
            }
        }
        int fh = base_h + r0, fw = base_w + c0;
        if (fh < H3 && fw < W3) {
            float xv[2][4], cv[2][4];
            #pragma unroll
            for (int orr = 0; orr < 2; ++orr)
                #pragma unroll
                for (int oc = 0; oc < 2; ++oc) {
                    int q = orr * 2 + oc;
                    float n0 = acc[orr][oc][0], d0 = acc[orr][oc][1];
                    float n1 = acc[orr][oc][2], d1 = acc[orr][oc][3];
                    xv[0][q] = n0 * rcpf_(d0 + EPSF) + bb0;
                    xv[1][q] = n1 * rcpf_(d1 + EPSF) + bb1;
                    cv[0][q] = d0 * is0;
                    cv[1][q] = d1 * is1;
                }
            uint2 q00 = packpx(xv[0][0], cv[0][0], xv[1][0], cv[1][0]);
            uint2 q01 = packpx(xv[0][1], cv[0][1], xv[1][1], cv[1][1]);
            uint2 q10 = packpx(xv[0][2], cv[0][2], xv[1][2], cv[1][2]);
            uint2 q11 = packpx(xv[0][3], cv[0][3], xv[1][3], cv[1][3]);
            long o0 = (long)b * pl + (long)fh * W3 + fw;
            *reinterpret_cast<uint4*>(Gpk + o0)      = make_uint4(q00.x, q00.y, q01.x, q01.y);
            *reinterpret_cast<uint4*>(Gpk + o0 + W3) = make_uint4(q10.x, q10.y, q11.x, q11.y);
            float cm0 = cv[0][0], xs0 = xv[0][0];
            if (cv[0][1] > cm0) { cm0 = cv[0][1]; xs0 = xv[0][1]; }
            if (cv[0][2] > cm0) { cm0 = cv[0][2]; xs0 = xv[0][2]; }
            if (cv[0][3] > cm0) { cm0 = cv[0][3]; xs0 = xv[0][3]; }
            float cm1 = cv[1][0], xs1 = xv[1][0];
            if (cv[1][1] > cm1) { cm1 = cv[1][1]; xs1 = xv[1][1]; }
            if (cv[1][2] > cm1) { cm1 = cv[1][2]; xs1 = xv[1][2]; }
            if (cv[1][3] > cm1) { cm1 = cv[1][3]; xs1 = xv[1][3]; }
            int ph = (base_h >> 1) + pr, pw = (base_w >> 1) + pc;
            P3pk[(long)b * (H4 * W4) + (long)ph * W4 + pw] =
                packpx(xs0, cm0 * 0.25f, xs1, cm1 * 0.25f);
        }
    }
}

// ---------------------------------------------------------------------------
// L4 conv: 5x5 pad2 nconv on packed pixels (w2, b2). Per-pixel (small level).
// ---------------------------------------------------------------------------
__global__ void nconv5_pk(const uint2* __restrict__ in, const float* __restrict__ wb,
                          const float* __restrict__ bias, uint2* __restrict__ out,
                          int H, int W) {
    int idx = blockIdx.x * blockDim.x + threadIdx.x;
    int total = B_ * H * W;
    if (idx >= total) return;
    int w = idx % W; int t = idx / W; int h = t % H; int b = t / H;
    const uint2* ip = in + (long)b * H * W;
    float n0 = 0, d0 = 0, n1 = 0, d1 = 0;
    #pragma unroll
    for (int dh = 0; dh < 5; ++dh) {
        int ih = h + dh - 2;
        if (ih < 0 || ih >= H) continue;
        #pragma unroll
        for (int dw = 0; dw < 5; ++dw) {
            int iw = w + dw - 2;
            if (iw < 0 || iw >= W) continue;
            float4 v = unpk(ip[(long)ih * W + iw]);
            const int k = dh * 5 + dw;
            float wa0 = wb[96 + k],  wc0 = wb[121 + k];
            float wa1 = wb[146 + k], wc1 = wb[171 + k];
            n0 = fmaf(wa0, v.x, fmaf(wc0, v.z, n0));
            d0 = fmaf(wa0, v.y, fmaf(wc0, v.w, d0));
            n1 = fmaf(wa1, v.x, fmaf(wc1, v.z, n1));
            d1 = fmaf(wa1, v.y, fmaf(wc1, v.w, d1));
        }
    }
    out[(long)b * H * W + (long)h * W + w] =
        packpx(n0 * rcpf_(d0 + EPSF) + bias[0], d0 * wb[810],
               n1 * rcpf_(d1 + EPSF) + bias[1], d1 * wb[811]);
}

// ---------------------------------------------------------------------------
// Decoder H3: F = nconv(cat(G, up2(I)), w4, b4). Per-pixel packed.
// ---------------------------------------------------------------------------
__global__ void nconv_cat_pk(const uint2* __restrict__ nat, const uint2* __restrict__ up,
                             const float* __restrict__ wb, const float* __restrict__ bias,
                             uint2* __restrict__ out, int H, int W) {
    int idx = blockIdx.x * blockDim.x + threadIdx.x;
    int total = B_ * H * W;
    if (idx >= total) return;
    int Hh = H / 2, Wh = W / 2;
    int w = idx % W; int t = idx / W; int h = t % H; int b = t / H;
    const uint2* np = nat + (long)b * H * W;
    const uint2* upp = up + (long)b * Hh * Wh;
    float n0 = 0, d0 = 0, n1 = 0, d1 = 0;
    #pragma unroll
    for (int dh = 0; dh < 3; ++dh) {
        int ih = h + dh - 1;
        if (ih < 0 || ih >= H) continue;
        #pragma unroll
        for (int dw = 0; dw < 3; ++dw) {
            int iw = w + dw - 1;
            if (iw < 0 || iw >= W) continue;
            float4 aN = unpk(np[(long)ih * W + iw]);
            float4 eU = unpk(upp[(long)(ih >> 1) * Wh + (iw >> 1)]);
            const int k = dh * 3 + dw;
            float na0 = wb[416 + k], nb0 = wb[425 + k], ua0 = wb[434 + k], ub0 = wb[443 + k];
            float na1 = wb[452 + k], nb1 = wb[461 + k], ua1 = wb[470 + k], ub1 = wb[479 + k];
            n0 = fmaf(na0, aN.x, fmaf(nb0, aN.z, fmaf(ua0, eU.x, fmaf(ub0, eU.z, n0))));
            d0 = fmaf(na0, aN.y, fmaf(nb0, aN.w, fmaf(ua0, eU.y, fmaf(ub0, eU.w, d0))));
            n1 = fmaf(na1, aN.x, fmaf(nb1, aN.z, fmaf(ua1, eU.x, fmaf(ub1, eU.z, n1))));
            d1 = fmaf(na1, aN.y, fmaf(nb1, aN.w, fmaf(ua1, eU.y, fmaf(ub1, eU.w, d1))));
        }
    }
    out[(long)b * H * W + (long)h * W + w] =
        packpx(n0 * rcpf_(d0 + EPSF) + bias[0], d0 * wb[814],
               n1 * rcpf_(d1 + EPSF) + bias[1], d1 * wb[815]);
}

// ---------------------------------------------------------------------------
// Decoder H2 tiled: E = nconv(cat(D, up2(F)), w5, b5). 32x32 tile, quads.
// ---------------------------------------------------------------------------
__global__ __launch_bounds__(256) void nconv_cat_h2t(
    const uint2* __restrict__ Dpk, const uint2* __restrict__ Fpk,
    const float* __restrict__ wb, const float* __restrict__ b5,
    uint2* __restrict__ Epk) {

    __shared__ float4 aT[34 * 35];
    __shared__ float4 eT[18 * 19];

    const int tid = threadIdx.x;
    const int bh = blockIdx.y * 32, bw = blockIdx.x * 32, b = blockIdx.z;
    const int eh0 = (bh - 1) >> 1, ew0 = (bw - 1) >> 1;
    const uint2* dp = Dpk + (long)b * (H2 * W2);
    const uint2* fp = Fpk + (long)b * (H3 * W3);

    for (int i = tid; i < 34 * 34; i += 256) {
        int r = i / 34, c = i % 34;
        int gh = bh - 1 + r, gw = bw - 1 + c;
        float4 v = make_float4(0.f, 0.f, 0.f, 0.f);
        if (gh >= 0 && gh < H2 && gw >= 0 && gw < W2)
            v = unpk(dp[(long)gh * W2 + gw]);
        aT[r * 35 + c] = v;
    }
    for (int i = tid; i < 18 * 18; i += 256) {
        int r = i / 18, c = i % 18;
        int gh = eh0 + r, gw = ew0 + c;
        float4 v = make_float4(0.f, 0.f, 0.f, 0.f);
        if (gh >= 0 && gh < H3 && gw >= 0 && gw < W3)
            v = unpk(fp[(long)gh * W3 + gw]);
        eT[r * 19 + c] = v;
    }
    __syncthreads();

    const int pr = tid >> 4, pc = tid & 15;
    const int r0 = 2 * pr, c0 = 2 * pc;
    float4 a4[4][4], e3[3][3];
    #pragma unroll
    for (int j = 0; j < 4; ++j)
        #pragma unroll
        for (int k = 0; k < 4; ++k) a4[j][k] = aT[(r0 + j) * 35 + c0 + k];
    #pragma unroll
    for (int j = 0; j < 3; ++j)
        #pragma unroll
        for (int k = 0; k < 3; ++k) e3[j][k] = eT[(pr + j) * 19 + pc + k];

    float acc[2][2][4];
    #pragma unroll
    for (int a = 0; a < 2; ++a)
        #pragma unroll
        for (int o = 0; o < 2; ++o)
            #pragma unroll
            for (int k = 0; k < 4; ++k) acc[a][o][k] = 0.f;

    #pragma unroll
    for (int orr = 0; orr < 2; ++orr)
        #pragma unroll
        for (int dh = 0; dh < 3; ++dh)
            #pragma unroll
            for (int oc = 0; oc < 2; ++oc)
                #pragma unroll
                for (int dw = 0; dw < 3; ++dw) {
                    float4 aN = a4[orr + dh][oc + dw];
                    float4 eU = e3[(orr + dh + 1) >> 1][(oc + dw + 1) >> 1];
                    const int k = dh * 3 + dw;
                    float na0 = wb[544 + k], nb0 = wb[553 + k], ua0 = wb[562 + k], ub0 = wb[571 + k];
                    float na1 = wb[580 + k], nb1 = wb[589 + k], ua1 = wb[598 + k], ub1 = wb[607 + k];
                    acc[orr][oc][0] = fmaf(na0, aN.x, fmaf(nb0, aN.z, fmaf(ua0, eU.x, fmaf(ub0, eU.z, acc[orr][oc][0]))));
                    acc[orr][oc][1] = fmaf(na0, aN.y, fmaf(nb0, aN.w, fmaf(ua0, eU.y, fmaf(ub0, eU.w, acc[orr][oc][1]))));
                    acc[orr][oc][2] = fmaf(na1, aN.x, fmaf(nb1, aN.z, fmaf(ua1, eU.x, fmaf(ub1, eU.z, acc[orr][oc][2]))));
                    acc[orr][oc][3] = fmaf(na1, aN.y, fmaf(nb1, aN.w, fmaf(ua1, eU.y, fmaf(ub1, eU.w, acc[orr][oc][3]))));
                }

    int fh = bh + r0, fw = bw + c0;
    if (fh < H2) {
        const float is0 = wb[816], is1 = wb[817];
        const float bb0 = b5[0], bb1 = b5[1];
        float xv[2][4], cv[2][4];
        #pragma unroll
        for (int orr = 0; orr < 2; ++orr)
            #pragma unroll
            for (int oc = 0; oc < 2; ++oc) {
                int q = orr * 2 + oc;
                float n0 = acc[orr][oc][0], d0 = acc[orr][oc][1];
                float n1 = acc[orr][oc][2], d1 = acc[orr][oc][3];
                xv[0][q] = n0 * rcpf_(d0 + EPSF) + bb0;
                xv[1][q] = n1 * rcpf_(d1 + EPSF) + bb1;
                cv[0][q] = d0 * is0;
                cv[1][q] = d1 * is1;
            }
        uint2 q00 = packpx(xv[0][0], cv[0][0], xv[1][0], cv[1][0]);
        uint2 q01 = packpx(xv[0][1], cv[0][1], xv[1][1], cv[1][1]);
        uint2 q10 = packpx(xv[0][2], cv[0][2], xv[1][2], cv[1][2]);
        uint2 q11 = packpx(xv[0][3], cv[0][3], xv[1][3], cv[1][3]);
        long o0 = (long)b * (H2 * W2) + (long)fh * W2 + fw;
        *reinterpret_cast<uint4*>(Epk + o0)      = make_uint4(q00.x, q00.y, q01.x, q01.y);
        *reinterpret_cast<uint4*>(Epk + o0 + W2) = make_uint4(q10.x, q10.y, q11.x, q11.y);
    }
}

// ---------------------------------------------------------------------------
// Final: out = w7-1x1( nconv(cat(up2(E), A), w6, b6) ) -> f32. Tiled quads.
// ---------------------------------------------------------------------------
__global__ __launch_bounds__(256) void final_tiled(
    const uint2* __restrict__ Apk, const uint2* __restrict__ Epk,
    const float* __restrict__ wb,
    const float* __restrict__ b6g, const float* __restrict__ b7g,
    float* __restrict__ oX, float* __restrict__ oC) {

    __shared__ float4 aT[34 * 35];
    __shared__ float4 eT[18 * 19];

    const int tid = threadIdx.x;
    const int bh = blockIdx.y * 32, bw = blockIdx.x * 32, b = blockIdx.z;
    const int eh0 = (bh - 1) >> 1, ew0 = (bw - 1) >> 1;
    const uint2* ap = Apk + (long)b * (H1 * W1);
    const uint2* ep = Epk + (long)b * (H2 * W2);

    for (int i = tid; i < 34 * 34; i += 256) {
        int r = i / 34, c = i % 34;
        int gh = bh - 1 + r, gw = bw - 1 + c;
        float4 v = make_float4(0.f, 0.f, 0.f, 0.f);
        if (gh >= 0 && gh < H1 && gw >= 0 && gw < W1)
            v = unpk(ap[(long)gh * W1 + gw]);
        aT[r * 35 + c] = v;
    }
    for (int i = tid; i < 18 * 18; i += 256) {
        int r = i / 18, c = i % 18;
        int gh = eh0 + r, gw = ew0 + c;
        float4 v = make_float4(0.f, 0.f, 0.f, 0.f);
        if (gh >= 0 && gh < H2 && gw >= 0 && gw < W2)
            v = unpk(ep[(long)gh * W2 + gw]);
        eT[r * 19 + c] = v;
    }
    __syncthreads();

    const int pr = tid >> 4, pc = tid & 15;
    const int r0 = 2 * pr, c0 = 2 * pc;
    float4 a4[4][4], e3[3][3];
    #pragma unroll
    for (int j = 0; j < 4; ++j)
        #pragma unroll
        for (int k = 0; k < 4; ++k) a4[j][k] = aT[(r0 + j) * 35 + c0 + k];
    #pragma unroll
    for (int j = 0; j < 3; ++j)
        #pragma unroll
        for (int k = 0; k < 3; ++k) e3[j][k] = eT[(pr + j) * 19 + pc + k];

    float acc[2][2][4];
    #pragma unroll
    for (int a = 0; a < 2; ++a)
        #pragma unroll
        for (int o = 0; o < 2; ++o)
            #pragma unroll
            for (int k = 0; k < 4; ++k) acc[a][o][k] = 0.f;

    // w6 layout: up (E) = ci 0-1, native (A) = ci 2-3.
    #pragma unroll
    for (int orr = 0; orr < 2; ++orr)
        #pragma unroll
        for (int dh = 0; dh < 3; ++dh)
            #pragma unroll
            for (int oc = 0; oc < 2; ++oc)
                #pragma unroll
                for (int dw = 0; dw < 3; ++dw) {
                    float4 aN = a4[orr + dh][oc + dw];
                    float4 eU = e3[(orr + dh + 1) >> 1][(oc + dw + 1) >> 1];
                    const int k = dh * 3 + dw;
                    float ua0 = wb[672 + k], ub0 = wb[681 + k], na0 = wb[690 + k], nb0 = wb[699 + k];
                    float ua1 = wb[708 + k], ub1 = wb[717 + k], na1 = wb[726 + k], nb1 = wb[735 + k];
                    acc[orr][oc][0] = fmaf(ua0, eU.x, fmaf(ub0, eU.z, fmaf(na0, aN.x, fmaf(nb0, aN.z, acc[orr][oc][0]))));
                    acc[orr][oc][1] = fmaf(ua0, eU.y, fmaf(ub0, eU.w, fmaf(na0, aN.y, fmaf(nb0, aN.w, acc[orr][oc][1]))));
                    acc[orr][oc][2] = fmaf(ua1, eU.x, fmaf(ub1, eU.z, fmaf(na1, aN.x, fmaf(nb1, aN.z, acc[orr][oc][2]))));
                    acc[orr][oc][3] = fmaf(ua1, eU.y, fmaf(ub1, eU.w, fmaf(na1, aN.y, fmaf(nb1, aN.w, acc[orr][oc][3]))));
                }

    const float is60 = wb[818], is61 = wb[819];
    const float bb60 = b6g[0], bb61 = b6g[1];
    const float w70 = wb[800], w71 = wb[801];
    const float is7 = wb[820], bb7 = b7g[0];
    float ox[2][2], ocv[2][2];
    #pragma unroll
    for (int orr = 0; orr < 2; ++orr)
        #pragma unroll
        for (int oc = 0; oc < 2; ++oc) {
            float n0 = acc[orr][oc][0], d0 = acc[orr][oc][1];
            float n1 = acc[orr][oc][2], d1 = acc[orr][oc][3];
            float x0v = n0 * rcpf_(d0 + EPSF) + bb60;
            float x1v = n1 * rcpf_(d1 + EPSF) + bb61;
            float c0v = d0 * is60, c1v = d1 * is61;
            float den7 = fmaf(w70, c0v, w71 * c1v);
            float nom7 = fmaf(w70, x0v * c0v, w71 * (x1v * c1v));
            ox[orr][oc] = nom7 * rcpf_(den7 + EPSF) + bb7;
            ocv[orr][oc] = den7 * is7;
        }
    long o = (long)b * (H1 * W1) + (long)(bh + r0) * W1 + (bw + c0);
    *reinterpret_cast<float2*>(oX + o)      = make_float2(ox[0][0], ox[0][1]);
    *reinterpret_cast<float2*>(oX + o + W1) = make_float2(ox[1][0], ox[1][1]);
    *reinterpret_cast<float2*>(oC + o)      = make_float2(ocv[0][0], ocv[0][1]);
    *reinterpret_cast<float2*>(oC + o + W1) = make_float2(ocv[1][0], ocv[1][1]);
}

extern "C" void kernel_launch(void* const* d_in, const int* in_sizes, int n_in,
                              void* d_out, int out_size, void* d_ws, size_t ws_size,
                              hipStream_t stream) {
    const float* x0 = (const float*)d_in[0];
    const float* c0 = (const float*)d_in[1];
    const float* w1 = (const float*)d_in[2];
    const float* b1 = (const float*)d_in[3];
    const float* w2 = (const float*)d_in[4];
    const float* b2 = (const float*)d_in[5];
    const float* w3 = (const float*)d_in[6];
    const float* b3 = (const float*)d_in[7];
    const float* w4 = (const float*)d_in[8];
    const float* b4 = (const float*)d_in[9];
    const float* w5 = (const float*)d_in[10];
    const float* b5 = (const float*)d_in[11];
    const float* w6 = (const float*)d_in[12];
    const float* b6 = (const float*)d_in[13];
    const float* w7 = (const float*)d_in[14];
    const float* b7 = (const float*)d_in[15];

    const long N1 = (long)B_ * H1 * W1;     // 6,848,512 pixels (full res)
    const long N2 = N1 / 4, N3 = N1 / 16, N4 = N1 / 64;

    // ws: [wb 4KB][Apk 8*N1][Epk 8*N2] ~ 68.5 MB (under proven 96 MB)
    float* wb = (float*)d_ws;
    uint2* Apk = (uint2*)((char*)d_ws + 4096);
    uint2* Epk = Apk + N1;

    // d_out (N1 uint2 capacity) as packed scratch; final pass reads only ws.
    uint2* R = (uint2*)d_out;
    uint2* P1pk = R;                 // N2
    uint2* Dpk  = R + N2;            // N2
    uint2* P2pk = R + 2 * N2;        // N3
    uint2* Gpk  = P2pk + N3;         // N3
    uint2* P3pk = Gpk + N3;          // N4
    uint2* Ipk  = P3pk + N4;         // N4
    uint2* Fpk  = Ipk + N4;          // N3   (total 2N2+3N3+2N4 = 2.875*N2 < 4*N2)

    float* oX = (float*)d_out;
    float* oC = oX + N1;

    prep_weights<<<1, 256, 0, stream>>>(w1, w2, w3, w4, w5, w6, w7, wb);

    dim3 gridF(W1 / TDIM, H1 / TDIM, B_);           // 38 x 11 x 16
    fused_l1pool<<<gridF, 256, 0, stream>>>(x0, c0, wb, b1, b2, b3, Apk, P1pk);

    dim3 gridL2(W2 / 32, (H2 + 31) / 32, B_);       // 19 x 6 x 16
    fused_l2<<<gridL2, 256, 0, stream>>>(P1pk, wb, b2, b3, Dpk, P2pk);

    dim3 gridL3((W3 + 31) / 32, (H3 + 31) / 32, B_); // 10 x 3 x 16
    fused_l3<<<gridL3, 256, 0, stream>>>(P2pk, wb, b2, Gpk, P3pk);

    const int g4 = (B_ * H4 * W4 + 255) / 256;
    nconv5_pk<<<g4, 256, 0, stream>>>(P3pk, wb, b2, Ipk, H4, W4);   // I = x4,c4

    const int g3 = (B_ * H3 * W3 + 255) / 256;
    nconv_cat_pk<<<g3, 256, 0, stream>>>(Gpk, Ipk, wb, b4, Fpk, H3, W3);  // F = x34

    nconv_cat_h2t<<<gridL2, 256, 0, stream>>>(Dpk, Fpk, wb, b5, Epk);     // E = x23 (ws)

    dim3 gridL(W1 / 32, H1 / 32, B_);               // 38 x 11 x 16
    final_tiled<<<gridL, 256, 0, stream>>>(Apk, Epk, wb, b6, b7, oX, oC);
}

// Round 5
// 422.234 us; speedup vs baseline: 4.2465x; 1.0613x over previous
//
#include <hip/hip_runtime.h>
#include <hip/hip_bf16.h>

#define EPSF 1e-20f
typedef __hip_bfloat16 bf16;
typedef unsigned int u32;

__device__ __forceinline__ float rcpf_(float v) { return __builtin_amdgcn_rcpf(v); }
__device__ __forceinline__ float bits2f(u32 b) { union { u32 i; float f; } u; u.i = b; return u.f; }
__device__ __forceinline__ float lo2f(u32 v) { return bits2f(v << 16); }
__device__ __forceinline__ float hi2f(u32 v) { return bits2f(v & 0xffff0000u); }
__device__ __forceinline__ u32 f2us(float f) {
    bf16 h = __float2bfloat16(f);
    unsigned short s;
    __builtin_memcpy(&s, &h, 2);
    return (u32)s;
}
// pixel pack: (x0,c0,x1,c1) as 4x bf16 in a uint2
__device__ __forceinline__ uint2 packpx(float x0, float c0, float x1, float c1) {
    return make_uint2(f2us(x0) | (f2us(c0) << 16), f2us(x1) | (f2us(c1) << 16));
}
// unpack to (p0,c0,p1,c1) with p = x*c
__device__ __forceinline__ float4 unpk(uint2 v) {
    float x0 = lo2f(v.x), c0 = hi2f(v.x), x1 = lo2f(v.y), c1 = hi2f(v.y);
    return make_float4(x0 * c0, c0, x1 * c1, c1);
}

// ---- problem dims (fixed by setup_inputs) ----
#define B_ 16
#define H1 352
#define W1 1216
#define H2 176
#define W2 608
#define H3 88
#define W3 304
#define H4 44
#define W4 152

// ---------------------------------------------------------------------------
// Weight prep: w = softplus(10*p)/10, per-out-ch kernel sums + inverse sums.
// wb floats: wt1@0(50) s1@64 | wt2@96(100) s2@224 | wt3@256(100) s3@384 |
// wt4@416(72) s4@512 | wt5@544(72) s5@640 | wt6@672(72) s6@768 |
// wt7@800(2) s7@804 | is1@808 is2@810 is3@812 is4@814 is5@816 is6@818 is7@820
// ---------------------------------------------------------------------------
__global__ void prep_weights(const float* w1, const float* w2, const float* w3,
                             const float* w4, const float* w5, const float* w6,
                             const float* w7, float* wb) {
    const float* ptrs[7] = {w1, w2, w3, w4, w5, w6, w7};
    const int ns[7]   = {50, 100, 100, 72, 72, 72, 2};
    const int offs[7] = {0, 96, 256, 416, 544, 672, 800};
    for (int it = 0; it < 7; ++it)
        for (int i = threadIdx.x; i < ns[it]; i += blockDim.x) {
            float z = 10.f * ptrs[it][i];
            float sp = (z > 20.f) ? z : log1pf(expf(z));
            wb[offs[it] + i] = sp * 0.1f;
        }
    __syncthreads();
    if (threadIdx.x == 0) {
        const int souts[7] = {2, 2, 2, 2, 2, 2, 1};
        const int klen[7]  = {25, 50, 50, 36, 36, 36, 2};
        const int soff[7]  = {64, 224, 384, 512, 640, 768, 804};
        for (int it = 0; it < 7; ++it)
            for (int o = 0; o < souts[it]; ++o) {
                float s = 0.f;
                for (int i = 0; i < klen[it]; ++i) s += wb[offs[it] + o * klen[it] + i];
                wb[soff[it] + o] = s;
            }
        for (int o = 0; o < 2; ++o) {
            wb[808 + o] = 1.f / wb[64 + o];
            wb[810 + o] = 1.f / wb[224 + o];
            wb[812 + o] = 1.f / wb[384 + o];
            wb[814 + o] = 1.f / wb[512 + o];
            wb[816 + o] = 1.f / wb[640 + o];
            wb[818 + o] = 1.f / wb[768 + o];
        }
        wb[820] = 1.f / wb[804];
    }
}

// ---------------------------------------------------------------------------
// Fused L1 encoder + pool, v4: even/odd column-deinterleaved LDS.
// All compute-stage window reads become lane-stride-1 (conflict-free b64/b128);
// quad columns c0=2*qc map to E[qc..qc+2], O[qc..qc+2]. Odd row strides
// (23/21/19) stagger row-crossing phases. Stage0 loads column PAIRS (float2).
// ---------------------------------------------------------------------------
#define TDIM 32

__global__ __launch_bounds__(256) void fused_l1pool(
    const float* __restrict__ x0g, const float* __restrict__ c0g,
    const float* __restrict__ wb,
    const float* __restrict__ b1, const float* __restrict__ b2, const float* __restrict__ b3,
    uint2* __restrict__ Apk, uint2* __restrict__ P1pk) {

    __shared__ float4 A1buf[2 * 40 * 21];   // stage1 out halves (stride 21). 26880 B
    __shared__ float4 U4buf[2 * 36 * 19];   // stage0 (float2 view) / stage2 out. 21888 B
    float4* A1e = A1buf;            float4* A1o = A1buf + 40 * 21;
    float4* U4e = U4buf;            float4* U4o = U4buf + 36 * 19;
    float2* U2e = (float2*)U4buf;   float2* U2o = U2e + 44 * 23;   // 16192 B <= 21888

    const int tid = threadIdx.x;
    const int base_h = blockIdx.y * TDIM;
    const int base_w = blockIdx.x * TDIM;
    const int b = blockIdx.z;
    const float* xp = x0g + (long)b * (H1 * W1);
    const float* cpg = c0g + (long)b * (H1 * W1);

    // stage 0: 44x44 (p,c) tile at origin (-6,-6); column-pair float2 loads.
    // gw even, W1 even -> pair never straddles the boundary.
    for (int i = tid; i < 44 * 22; i += 256) {
        int r = i / 22, cp2 = i % 22;
        int gh = base_h - 6 + r, gw = base_w - 6 + 2 * cp2;
        float2 xv = make_float2(0.f, 0.f), cv = make_float2(0.f, 0.f);
        if (gh >= 0 && gh < H1 && gw >= 0 && gw < W1) {
            long o = (long)gh * W1 + gw;
            xv = *reinterpret_cast<const float2*>(xp + o);
            cv = *reinterpret_cast<const float2*>(cpg + o);
        }
        U2e[r * 23 + cp2] = make_float2(xv.x * cv.x, cv.x);
        U2o[r * 23 + cp2] = make_float2(xv.y * cv.y, cv.y);
    }
    __syncthreads();

    // stage 1: conv1 (CIN=1), 40x40 outputs (origin -4), 20x20 quads.
    {
        const float is0 = wb[808], is1 = wb[809];
        const float bb0 = b1[0], bb1 = b1[1];
        for (int i = tid; i < 400; i += 256) {
            int qr = i / 20, qc = i % 20;
            int r0 = 2 * qr;
            float acc[2][2][4];
            #pragma unroll
            for (int a = 0; a < 2; ++a)
                #pragma unroll
                for (int o = 0; o < 2; ++o)
                    #pragma unroll
                    for (int k = 0; k < 4; ++k) acc[a][o][k] = 0.f;
            #pragma unroll
            for (int tr = 0; tr < 6; ++tr) {
                const int rr = (r0 + tr) * 23;
                float2 t[6];
                t[0] = U2e[rr + qc];     t[1] = U2o[rr + qc];
                t[2] = U2e[rr + qc + 1]; t[3] = U2o[rr + qc + 1];
                t[4] = U2e[rr + qc + 2]; t[5] = U2o[rr + qc + 2];
                #pragma unroll
                for (int orr = 0; orr < 2; ++orr) {
                    const int dh = tr - orr;
                    if (dh < 0 || dh > 4) continue;
                    #pragma unroll
                    for (int dw = 0; dw < 5; ++dw) {
                        float wA = wb[dh * 5 + dw];
                        float wB = wb[25 + dh * 5 + dw];
                        #pragma unroll
                        for (int oc = 0; oc < 2; ++oc) {
                            float2 v = t[dw + oc];
                            acc[orr][oc][0] = fmaf(wA, v.x, acc[orr][oc][0]);
                            acc[orr][oc][1] = fmaf(wA, v.y, acc[orr][oc][1]);
                            acc[orr][oc][2] = fmaf(wB, v.x, acc[orr][oc][2]);
                            acc[orr][oc][3] = fmaf(wB, v.y, acc[orr][oc][3]);
                        }
                    }
                }
            }
            #pragma unroll
            for (int orr = 0; orr < 2; ++orr) {
                int r = r0 + orr;
                int gh = base_h - 4 + r;
                #pragma unroll
                for (int oc = 0; oc < 2; ++oc) {
                    int gw = base_w - 4 + 2 * qc + oc;
                    float4 out = make_float4(0.f, 0.f, 0.f, 0.f);
                    if (gh >= 0 && gh < H1 && gw >= 0 && gw < W1) {
                        float n0 = acc[orr][oc][0], d0 = acc[orr][oc][1];
                        float n1 = acc[orr][oc][2], d1 = acc[orr][oc][3];
                        float c0v = d0 * is0, x0v = n0 * rcpf_(d0 + EPSF) + bb0;
                        float c1v = d1 * is1, x1v = n1 * rcpf_(d1 + EPSF) + bb1;
                        out = make_float4(x0v * c0v, c0v, x1v * c1v, c1v);
                    }
                    if (oc == 0) A1e[r * 21 + qc] = out;
                    else         A1o[r * 21 + qc] = out;
                }
            }
        }
    }
    __syncthreads();   // A1 ready; stage0 data dead -> U4 reusable

    // stage 2: conv2 (CIN=2), 36x36 outputs (origin -2), 18x18 quads.
    {
        const float is0 = wb[810], is1 = wb[811];
        const float bb0 = b2[0], bb1 = b2[1];
        for (int i = tid; i < 324; i += 256) {
            int qr = i / 18, qc = i % 18;
            int r0 = 2 * qr;
            float acc[2][2][4];
            #pragma unroll
            for (int a = 0; a < 2; ++a)
                #pragma unroll
                for (int o = 0; o < 2; ++o)
                    #pragma unroll
                    for (int k = 0; k < 4; ++k) acc[a][o][k] = 0.f;
            #pragma unroll
            for (int tr = 0; tr < 6; ++tr) {
                const int rr = (r0 + tr) * 21;
                float4 t[6];
                t[0] = A1e[rr + qc];     t[1] = A1o[rr + qc];
                t[2] = A1e[rr + qc + 1]; t[3] = A1o[rr + qc + 1];
                t[4] = A1e[rr + qc + 2]; t[5] = A1o[rr + qc + 2];
                #pragma unroll
                for (int orr = 0; orr < 2; ++orr) {
                    const int dh = tr - orr;
                    if (dh < 0 || dh > 4) continue;
                    #pragma unroll
                    for (int dw = 0; dw < 5; ++dw) {
                        const int k = dh * 5 + dw;
                        float wa0 = wb[96 + k],  wc0 = wb[121 + k];
                        float wa1 = wb[146 + k], wc1 = wb[171 + k];
                        #pragma unroll
                        for (int oc = 0; oc < 2; ++oc) {
                            float4 v = t[dw + oc];
                            acc[orr][oc][0] = fmaf(wa0, v.x, fmaf(wc0, v.z, acc[orr][oc][0]));
                            acc[orr][oc][1] = fmaf(wa0, v.y, fmaf(wc0, v.w, acc[orr][oc][1]));
                            acc[orr][oc][2] = fmaf(wa1, v.x, fmaf(wc1, v.z, acc[orr][oc][2]));
                            acc[orr][oc][3] = fmaf(wa1, v.y, fmaf(wc1, v.w, acc[orr][oc][3]));
                        }
                    }
                }
            }
            #pragma unroll
            for (int orr = 0; orr < 2; ++orr) {
                int r = r0 + orr;
                int gh = base_h - 2 + r;
                #pragma unroll
                for (int oc = 0; oc < 2; ++oc) {
                    int gw = base_w - 2 + 2 * qc + oc;
                    float4 out = make_float4(0.f, 0.f, 0.f, 0.f);
                    if (gh >= 0 && gh < H1 && gw >= 0 && gw < W1) {
                        float n0 = acc[orr][oc][0], d0 = acc[orr][oc][1];
                        float n1 = acc[orr][oc][2], d1 = acc[orr][oc][3];
                        float c0v = d0 * is0, x0v = n0 * rcpf_(d0 + EPSF) + bb0;
                        float c1v = d1 * is1, x1v = n1 * rcpf_(d1 + EPSF) + bb1;
                        out = make_float4(x0v * c0v, c0v, x1v * c1v, c1v);
                    }
                    if (oc == 0) U4e[r * 19 + qc] = out;
                    else         U4o[r * 19 + qc] = out;
                }
            }
        }
    }
    __syncthreads();

    // stage 3: conv3, one 2x2 quad per thread; write Apk + pooled P1pk.
    {
        const float is0 = wb[812], is1 = wb[813];
        const float bb0 = b3[0], bb1 = b3[1];
        const int pr = tid >> 4, pc = tid & 15;
        const int r0 = 2 * pr;
        float acc[2][2][4];
        #pragma unroll
        for (int a = 0; a < 2; ++a)
            #pragma unroll
            for (int o = 0; o < 2; ++o)
                #pragma unroll
                for (int k = 0; k < 4; ++k) acc[a][o][k] = 0.f;
        #pragma unroll
        for (int tr = 0; tr < 6; ++tr) {
            const int rr = (r0 + tr) * 19;
            float4 t[6];
            t[0] = U4e[rr + pc];     t[1] = U4o[rr + pc];
            t[2] = U4e[rr + pc + 1]; t[3] = U4o[rr + pc + 1];
            t[4] = U4e[rr + pc + 2]; t[5] = U4o[rr + pc + 2];
            #pragma unroll
            for (int orr = 0; orr < 2; ++orr) {
                const int dh = tr - orr;
                if (dh < 0 || dh > 4) continue;
                #pragma unroll
                for (int dw = 0; dw < 5; ++dw) {
                    const int k = dh * 5 + dw;
                    float wa0 = wb[256 + k], wc0 = wb[281 + k];
                    float wa1 = wb[306 + k], wc1 = wb[331 + k];
                    #pragma unroll
                    for (int oc = 0; oc < 2; ++oc) {
                        float4 v = t[dw + oc];
                        acc[orr][oc][0] = fmaf(wa0, v.x, fmaf(wc0, v.z, acc[orr][oc][0]));
                        acc[orr][oc][1] = fmaf(wa0, v.y, fmaf(wc0, v.w, acc[orr][oc][1]));
                        acc[orr][oc][2] = fmaf(wa1, v.x, fmaf(wc1, v.z, acc[orr][oc][2]));
                        acc[orr][oc][3] = fmaf(wa1, v.y, fmaf(wc1, v.w, acc[orr][oc][3]));
                    }
                }
            }
        }
        float xv[2][4], cv[2][4];
        #pragma unroll
        for (int orr = 0; orr < 2; ++orr)
            #pragma unroll
            for (int oc = 0; oc < 2; ++oc) {
                int q = orr * 2 + oc;
                float n0 = acc[orr][oc][0], d0 = acc[orr][oc][1];
                float n1 = acc[orr][oc][2], d1 = acc[orr][oc][3];
                xv[0][q] = n0 * rcpf_(d0 + EPSF) + bb0;
                xv[1][q] = n1 * rcpf_(d1 + EPSF) + bb1;
                cv[0][q] = d0 * is0;
                cv[1][q] = d1 * is1;
            }
        int fh = base_h + r0, fw = base_w + 2 * pc;
        int ph = (base_h >> 1) + pr, pw = (base_w >> 1) + pc;
        uint2 q00 = packpx(xv[0][0], cv[0][0], xv[1][0], cv[1][0]);
        uint2 q01 = packpx(xv[0][1], cv[0][1], xv[1][1], cv[1][1]);
        uint2 q10 = packpx(xv[0][2], cv[0][2], xv[1][2], cv[1][2]);
        uint2 q11 = packpx(xv[0][3], cv[0][3], xv[1][3], cv[1][3]);
        long o0 = (long)b * (H1 * W1) + (long)fh * W1 + fw;
        *reinterpret_cast<uint4*>(Apk + o0)      = make_uint4(q00.x, q00.y, q01.x, q01.y);
        *reinterpret_cast<uint4*>(Apk + o0 + W1) = make_uint4(q10.x, q10.y, q11.x, q11.y);
        // pool per channel (f32 first-max, row-major; value-tracked)
        float cm0 = cv[0][0], xs0 = xv[0][0];
        if (cv[0][1] > cm0) { cm0 = cv[0][1]; xs0 = xv[0][1]; }
        if (cv[0][2] > cm0) { cm0 = cv[0][2]; xs0 = xv[0][2]; }
        if (cv[0][3] > cm0) { cm0 = cv[0][3]; xs0 = xv[0][3]; }
        float cm1 = cv[1][0], xs1 = xv[1][0];
        if (cv[1][1] > cm1) { cm1 = cv[1][1]; xs1 = xv[1][1]; }
        if (cv[1][2] > cm1) { cm1 = cv[1][2]; xs1 = xv[1][2]; }
        if (cv[1][3] > cm1) { cm1 = cv[1][3]; xs1 = xv[1][3]; }
        P1pk[(long)b * (H2 * W2) + (long)ph * W2 + pw] =
            packpx(xs0, cm0 * 0.25f, xs1, cm1 * 0.25f);
    }
}

// ---------------------------------------------------------------------------
// Fused L2: P1pk -> conv w2 -> conv w3 -> Dpk (full) + pooled P2pk.
// Deinterleaved LDS (same scheme as l1pool).
// ---------------------------------------------------------------------------
__global__ __launch_bounds__(256) void fused_l2(
    const uint2* __restrict__ P1pk, const float* __restrict__ wb,
    const float* __restrict__ b2, const float* __restrict__ b3,
    uint2* __restrict__ Dpk, uint2* __restrict__ P2pk) {

    __shared__ float4 T0buf[2 * 40 * 21];
    __shared__ float4 T1buf[2 * 36 * 19];
    float4* T0e = T0buf; float4* T0o = T0buf + 40 * 21;
    float4* T1e = T1buf; float4* T1o = T1buf + 36 * 19;

    const int tid = threadIdx.x;
    const int base_h = blockIdx.y * 32;
    const int base_w = blockIdx.x * 32;
    const int b = blockIdx.z;
    const long pl = (long)H2 * W2;
    const uint2* ip = P1pk + (long)b * pl;

    // stage 0: 40x40 input tile (origin -4); pixel-pair uint4 loads (gw even).
    for (int i = tid; i < 40 * 20; i += 256) {
        int r = i / 20, cp2 = i % 20;
        int gh = base_h - 4 + r, gw = base_w - 4 + 2 * cp2;
        uint4 pp = make_uint4(0, 0, 0, 0);
        if (gh >= 0 && gh < H2 && gw >= 0 && gw < W2)
            pp = *reinterpret_cast<const uint4*>(ip + (long)gh * W2 + gw);
        T0e[r * 21 + cp2] = unpk(make_uint2(pp.x, pp.y));
        T0o[r * 21 + cp2] = unpk(make_uint2(pp.z, pp.w));
    }
    __syncthreads();

    // conv w2 -> 36x36 (origin -2), 18x18 quads.
    {
        const float is0 = wb[810], is1 = wb[811];
        const float bb0 = b2[0], bb1 = b2[1];
        for (int i = tid; i < 324; i += 256) {
            int qr = i / 18, qc = i % 18;
            int r0 = 2 * qr;
            float acc[2][2][4];
            #pragma unroll
            for (int a = 0; a < 2; ++a)
                #pragma unroll
                for (int o = 0; o < 2; ++o)
                    #pragma unroll
                    for (int k = 0; k < 4; ++k) acc[a][o][k] = 0.f;
            #pragma unroll
            for (int tr = 0; tr < 6; ++tr) {
                const int rr = (r0 + tr) * 21;
                float4 t[6];
                t[0] = T0e[rr + qc];     t[1] = T0o[rr + qc];
                t[2] = T0e[rr + qc + 1]; t[3] = T0o[rr + qc + 1];
                t[4] = T0e[rr + qc + 2]; t[5] = T0o[rr + qc + 2];
                #pragma unroll
                for (int orr = 0; orr < 2; ++orr) {
                    const int dh = tr - orr;
                    if (dh < 0 || dh > 4) continue;
                    #pragma unroll
                    for (int dw = 0; dw < 5; ++dw) {
                        const int k = dh * 5 + dw;
                        float wa0 = wb[96 + k],  wc0 = wb[121 + k];
                        float wa1 = wb[146 + k], wc1 = wb[171 + k];
                        #pragma unroll
                        for (int oc = 0; oc < 2; ++oc) {
                            float4 v = t[dw + oc];
                            acc[orr][oc][0] = fmaf(wa0, v.x, fmaf(wc0, v.z, acc[orr][oc][0]));
                            acc[orr][oc][1] = fmaf(wa0, v.y, fmaf(wc0, v.w, acc[orr][oc][1]));
                            acc[orr][oc][2] = fmaf(wa1, v.x, fmaf(wc1, v.z, acc[orr][oc][2]));
                            acc[orr][oc][3] = fmaf(wa1, v.y, fmaf(wc1, v.w, acc[orr][oc][3]));
                        }
                    }
                }
            }
            #pragma unroll
            for (int orr = 0; orr < 2; ++orr) {
                int r = r0 + orr;
                int gh = base_h - 2 + r;
                #pragma unroll
                for (int oc = 0; oc < 2; ++oc) {
                    int gw = base_w - 2 + 2 * qc + oc;
                    float4 out = make_float4(0.f, 0.f, 0.f, 0.f);
                    if (gh >= 0 && gh < H2 && gw >= 0 && gw < W2) {
                        float n0 = acc[orr][oc][0], d0 = acc[orr][oc][1];
                        float n1 = acc[orr][oc][2], d1 = acc[orr][oc][3];
                        float c0v = d0 * is0, x0v = n0 * rcpf_(d0 + EPSF) + bb0;
                        float c1v = d1 * is1, x1v = n1 * rcpf_(d1 + EPSF) + bb1;
                        out = make_float4(x0v * c0v, c0v, x1v * c1v, c1v);
                    }
                    if (oc == 0) T1e[r * 19 + qc] = out;
                    else         T1o[r * 19 + qc] = out;
                }
            }
        }
    }
    __syncthreads();

    // conv w3 per quad; write Dpk + pooled P2pk.
    {
        const float is0 = wb[812], is1 = wb[813];
        const float bb0 = b3[0], bb1 = b3[1];
        const int pr = tid >> 4, pc = tid & 15;
        const int r0 = 2 * pr;
        float acc[2][2][4];
        #pragma unroll
        for (int a = 0; a < 2; ++a)
            #pragma unroll
            for (int o = 0; o < 2; ++o)
                #pragma unroll
                for (int k = 0; k < 4; ++k) acc[a][o][k] = 0.f;
        #pragma unroll
        for (int tr = 0; tr < 6; ++tr) {
            const int rr = (r0 + tr) * 19;
            float4 t[6];
            t[0] = T1e[rr + pc];     t[1] = T1o[rr + pc];
            t[2] = T1e[rr + pc + 1]; t[3] = T1o[rr + pc + 1];
            t[4] = T1e[rr + pc + 2]; t[5] = T1o[rr + pc + 2];
            #pragma unroll
            for (int orr = 0; orr < 2; ++orr) {
                const int dh = tr - orr;
                if (dh < 0 || dh > 4) continue;
                #pragma unroll
                for (int dw = 0; dw < 5; ++dw) {
                    const int k = dh * 5 + dw;
                    float wa0 = wb[256 + k], wc0 = wb[281 + k];
                    float wa1 = wb[306 + k], wc1 = wb[331 + k];
                    #pragma unroll
                    for (int oc = 0; oc < 2; ++oc) {
                        float4 v = t[dw + oc];
                        acc[orr][oc][0] = fmaf(wa0, v.x, fmaf(wc0, v.z, acc[orr][oc][0]));
                        acc[orr][oc][1] = fmaf(wa0, v.y, fmaf(wc0, v.w, acc[orr][oc][1]));
                        acc[orr][oc][2] = fmaf(wa1, v.x, fmaf(wc1, v.z, acc[orr][oc][2]));
                        acc[orr][oc][3] = fmaf(wa1, v.y, fmaf(wc1, v.w, acc[orr][oc][3]));
                    }
                }
            }
        }
        int fh = base_h + r0, fw = base_w + 2 * pc;
        if (fh < H2) {
            float xv[2][4], cv[2][4];
            #pragma unroll
            for (int orr = 0; orr < 2; ++orr)
                #pragma unroll
                for (int oc = 0; oc < 2; ++oc) {
                    int q = orr * 2 + oc;
                    float n0 = acc[orr][oc][0], d0 = acc[orr][oc][1];
                    float n1 = acc[orr][oc][2], d1 = acc[orr][oc][3];
                    xv[0][q] = n0 * rcpf_(d0 + EPSF) + bb0;
                    xv[1][q] = n1 * rcpf_(d1 + EPSF) + bb1;
                    cv[0][q] = d0 * is0;
                    cv[1][q] = d1 * is1;
                }
            uint2 q00 = packpx(xv[0][0], cv[0][0], xv[1][0], cv[1][0]);
            uint2 q01 = packpx(xv[0][1], cv[0][1], xv[1][1], cv[1][1]);
            uint2 q10 = packpx(xv[0][2], cv[0][2], xv[1][2], cv[1][2]);
            uint2 q11 = packpx(xv[0][3], cv[0][3], xv[1][3], cv[1][3]);
            long o0 = (long)b * pl + (long)fh * W2 + fw;
            *reinterpret_cast<uint4*>(Dpk + o0)      = make_uint4(q00.x, q00.y, q01.x, q01.y);
            *reinterpret_cast<uint4*>(Dpk + o0 + W2) = make_uint4(q10.x, q10.y, q11.x, q11.y);
            float cm0 = cv[0][0], xs0 = xv[0][0];
            if (cv[0][1] > cm0) { cm0 = cv[0][1]; xs0 = xv[0][1]; }
            if (cv[0][2] > cm0) { cm0 = cv[0][2]; xs0 = xv[0][2]; }
            if (cv[0][3] > cm0) { cm0 = cv[0][3]; xs0 = xv[0][3]; }
            float cm1 = cv[1][0], xs1 = xv[1][0];
            if (cv[1][1] > cm1) { cm1 = cv[1][1]; xs1 = xv[1][1]; }
            if (cv[1][2] > cm1) { cm1 = cv[1][2]; xs1 = xv[1][2]; }
            if (cv[1][3] > cm1) { cm1 = cv[1][3]; xs1 = xv[1][3]; }
            int ph = (base_h >> 1) + pr, pw = (base_w >> 1) + pc;
            P2pk[(long)b * (H3 * W3) + (long)ph * W3 + pw] =
                packpx(xs0, cm0 * 0.25f, xs1, cm1 * 0.25f);
        }
    }
}

// ---------------------------------------------------------------------------
// Fused L3: P2pk -> conv w2 -> Gpk (full) + pooled P3pk. Deinterleaved LDS.
// ---------------------------------------------------------------------------
__global__ __launch_bounds__(256) void fused_l3(
    const uint2* __restrict__ P2pk, const float* __restrict__ wb,
    const float* __restrict__ b2,
    uint2* __restrict__ Gpk, uint2* __restrict__ P3pk) {

    __shared__ float4 T0buf[2 * 36 * 19];
    float4* T0e = T0buf; float4* T0o = T0buf + 36 * 19;

    const int tid = threadIdx.x;
    const int base_h = blockIdx.y * 32;
    const int base_w = blockIdx.x * 32;
    const int b = blockIdx.z;
    const long pl = (long)H3 * W3;
    const uint2* ip = P2pk + (long)b * pl;

    for (int i = tid; i < 36 * 18; i += 256) {
        int r = i / 18, cp2 = i % 18;
        int gh = base_h - 2 + r, gw = base_w - 2 + 2 * cp2;
        uint4 pp = make_uint4(0, 0, 0, 0);
        if (gh >= 0 && gh < H3 && gw >= 0 && gw < W3)
            pp = *reinterpret_cast<const uint4*>(ip + (long)gh * W3 + gw);
        T0e[r * 19 + cp2] = unpk(make_uint2(pp.x, pp.y));
        T0o[r * 19 + cp2] = unpk(make_uint2(pp.z, pp.w));
    }
    __syncthreads();

    {
        const float is0 = wb[810], is1 = wb[811];
        const float bb0 = b2[0], bb1 = b2[1];
        const int pr = tid >> 4, pc = tid & 15;
        const int r0 = 2 * pr;
        float acc[2][2][4];
        #pragma unroll
        for (int a = 0; a < 2; ++a)
            #pragma unroll
            for (int o = 0; o < 2; ++o)
                #pragma unroll
                for (int k = 0; k < 4; ++k) acc[a][o][k] = 0.f;
        #pragma unroll
        for (int tr = 0; tr < 6; ++tr) {
            const int rr = (r0 + tr) * 19;
            float4 t[6];
            t[0] = T0e[rr + pc];     t[1] = T0o[rr + pc];
            t[2] = T0e[rr + pc + 1]; t[3] = T0o[rr + pc + 1];
            t[4] = T0e[rr + pc + 2]; t[5] = T0o[rr + pc + 2];
            #pragma unroll
            for (int orr = 0; orr < 2; ++orr) {
                const int dh = tr - orr;
                if (dh < 0 || dh > 4) continue;
                #pragma unroll
                for (int dw = 0; dw < 5; ++dw) {
                    const int k = dh * 5 + dw;
                    float wa0 = wb[96 + k],  wc0 = wb[121 + k];
                    float wa1 = wb[146 + k], wc1 = wb[171 + k];
                    #pragma unroll
                    for (int oc = 0; oc < 2; ++oc) {
                        float4 v = t[dw + oc];
                        acc[orr][oc][0] = fmaf(wa0, v.x, fmaf(wc0, v.z, acc[orr][oc][0]));
                        acc[orr][oc][1] = fmaf(wa0, v.y, fmaf(wc0, v.w, acc[orr][oc][1]));
                        acc[orr][oc][2] = fmaf(wa1, v.x, fmaf(wc1, v.z, acc[orr][oc][2]));
                        acc[orr][oc][3] = fmaf(wa1, v.y, fmaf(wc1, v.w, acc[orr][oc][3]));
                    }
                }
            }
        }
        int fh = base_h + r0, fw = base_w + 2 * pc;
        if (fh < H3 && fw < W3) {
            float xv[2][4], cv[2][4];
            #pragma unroll
            for (int orr = 0; orr < 2; ++orr)
                #pragma unroll
                for (int oc = 0; oc < 2; ++oc) {
                    int q = orr * 2 + oc;
                    float n0 = acc[orr][oc][0], d0 = acc[orr][oc][1];
                    float n1 = acc[orr][oc][2], d1 = acc[orr][oc][3];
                    xv[0][q] = n0 * rcpf_(d0 + EPSF) + bb0;
                    xv[1][q] = n1 * rcpf_(d1 + EPSF) + bb1;
                    cv[0][q] = d0 * is0;
                    cv[1][q] = d1 * is1;
                }
            uint2 q00 = packpx(xv[0][0], cv[0][0], xv[1][0], cv[1][0]);
            uint2 q01 = packpx(xv[0][1], cv[0][1], xv[1][1], cv[1][1]);
            uint2 q10 = packpx(xv[0][2], cv[0][2], xv[1][2], cv[1][2]);
            uint2 q11 = packpx(xv[0][3], cv[0][3], xv[1][3], cv[1][3]);
            long o0 = (long)b * pl + (long)fh * W3 + fw;
            *reinterpret_cast<uint4*>(Gpk + o0)      = make_uint4(q00.x, q00.y, q01.x, q01.y);
            *reinterpret_cast<uint4*>(Gpk + o0 + W3) = make_uint4(q10.x, q10.y, q11.x, q11.y);
            float cm0 = cv[0][0], xs0 = xv[0][0];
            if (cv[0][1] > cm0) { cm0 = cv[0][1]; xs0 = xv[0][1]; }
            if (cv[0][2] > cm0) { cm0 = cv[0][2]; xs0 = xv[0][2]; }
            if (cv[0][3] > cm0) { cm0 = cv[0][3]; xs0 = xv[0][3]; }
            float cm1 = cv[1][0], xs1 = xv[1][0];
            if (cv[1][1] > cm1) { cm1 = cv[1][1]; xs1 = xv[1][1]; }
            if (cv[1][2] > cm1) { cm1 = cv[1][2]; xs1 = xv[1][2]; }
            if (cv[1][3] > cm1) { cm1 = cv[1][3]; xs1 = xv[1][3]; }
            int ph = (base_h >> 1) + pr, pw = (base_w >> 1) + pc;
            P3pk[(long)b * (H4 * W4) + (long)ph * W4 + pw] =
                packpx(xs0, cm0 * 0.25f, xs1, cm1 * 0.25f);
        }
    }
}

// ---------------------------------------------------------------------------
// L4 conv: 5x5 pad2 nconv on packed pixels (w2, b2). Per-pixel (small level).
// ---------------------------------------------------------------------------
__global__ void nconv5_pk(const uint2* __restrict__ in, const float* __restrict__ wb,
                          const float* __restrict__ bias, uint2* __restrict__ out,
                          int H, int W) {
    int idx = blockIdx.x * blockDim.x + threadIdx.x;
    int total = B_ * H * W;
    if (idx >= total) return;
    int w = idx % W; int t = idx / W; int h = t % H; int b = t / H;
    const uint2* ip = in + (long)b * H * W;
    float n0 = 0, d0 = 0, n1 = 0, d1 = 0;
    #pragma unroll
    for (int dh = 0; dh < 5; ++dh) {
        int ih = h + dh - 2;
        if (ih < 0 || ih >= H) continue;
        #pragma unroll
        for (int dw = 0; dw < 5; ++dw) {
            int iw = w + dw - 2;
            if (iw < 0 || iw >= W) continue;
            float4 v = unpk(ip[(long)ih * W + iw]);
            const int k = dh * 5 + dw;
            float wa0 = wb[96 + k],  wc0 = wb[121 + k];
            float wa1 = wb[146 + k], wc1 = wb[171 + k];
            n0 = fmaf(wa0, v.x, fmaf(wc0, v.z, n0));
            d0 = fmaf(wa0, v.y, fmaf(wc0, v.w, d0));
            n1 = fmaf(wa1, v.x, fmaf(wc1, v.z, n1));
            d1 = fmaf(wa1, v.y, fmaf(wc1, v.w, d1));
        }
    }
    out[(long)b * H * W + (long)h * W + w] =
        packpx(n0 * rcpf_(d0 + EPSF) + bias[0], d0 * wb[810],
               n1 * rcpf_(d1 + EPSF) + bias[1], d1 * wb[811]);
}

// ---------------------------------------------------------------------------
// Decoder H3: F = nconv(cat(G, up2(I)), w4, b4). Per-pixel packed.
// ---------------------------------------------------------------------------
__global__ void nconv_cat_pk(const uint2* __restrict__ nat, const uint2* __restrict__ up,
                             const float* __restrict__ wb, const float* __restrict__ bias,
                             uint2* __restrict__ out, int H, int W) {
    int idx = blockIdx.x * blockDim.x + threadIdx.x;
    int total = B_ * H * W;
    if (idx >= total) return;
    int Hh = H / 2, Wh = W / 2;
    int w = idx % W; int t = idx / W; int h = t % H; int b = t / H;
    const uint2* np = nat + (long)b * H * W;
    const uint2* upp = up + (long)b * Hh * Wh;
    float n0 = 0, d0 = 0, n1 = 0, d1 = 0;
    #pragma unroll
    for (int dh = 0; dh < 3; ++dh) {
        int ih = h + dh - 1;
        if (ih < 0 || ih >= H) continue;
        #pragma unroll
        for (int dw = 0; dw < 3; ++dw) {
            int iw = w + dw - 1;
            if (iw < 0 || iw >= W) continue;
            float4 aN = unpk(np[(long)ih * W + iw]);
            float4 eU = unpk(upp[(long)(ih >> 1) * Wh + (iw >> 1)]);
            const int k = dh * 3 + dw;
            float na0 = wb[416 + k], nb0 = wb[425 + k], ua0 = wb[434 + k], ub0 = wb[443 + k];
            float na1 = wb[452 + k], nb1 = wb[461 + k], ua1 = wb[470 + k], ub1 = wb[479 + k];
            n0 = fmaf(na0, aN.x, fmaf(nb0, aN.z, fmaf(ua0, eU.x, fmaf(ub0, eU.z, n0))));
            d0 = fmaf(na0, aN.y, fmaf(nb0, aN.w, fmaf(ua0, eU.y, fmaf(ub0, eU.w, d0))));
            n1 = fmaf(na1, aN.x, fmaf(nb1, aN.z, fmaf(ua1, eU.x, fmaf(ub1, eU.z, n1))));
            d1 = fmaf(na1, aN.y, fmaf(nb1, aN.w, fmaf(ua1, eU.y, fmaf(ub1, eU.w, d1))));
        }
    }
    out[(long)b * H * W + (long)h * W + w] =
        packpx(n0 * rcpf_(d0 + EPSF) + bias[0], d0 * wb[814],
               n1 * rcpf_(d1 + EPSF) + bias[1], d1 * wb[815]);
}

// ---------------------------------------------------------------------------
// Decoder H2 tiled: E = nconv(cat(D, up2(F)), w5, b5). Deinterleaved aT.
// ---------------------------------------------------------------------------
__global__ __launch_bounds__(256) void nconv_cat_h2t(
    const uint2* __restrict__ Dpk, const uint2* __restrict__ Fpk,
    const float* __restrict__ wb, const float* __restrict__ b5,
    uint2* __restrict__ Epk) {

    __shared__ float4 aTbuf[2 * 34 * 17];
    __shared__ float4 eT[18 * 19];
    float4* aTe = aTbuf; float4* aTo = aTbuf + 34 * 17;

    const int tid = threadIdx.x;
    const int bh = blockIdx.y * 32, bw = blockIdx.x * 32, b = blockIdx.z;
    const int eh0 = (bh - 1) >> 1, ew0 = (bw - 1) >> 1;
    const uint2* dp = Dpk + (long)b * (H2 * W2);
    const uint2* fp = Fpk + (long)b * (H3 * W3);

    // aT: tile cols 0..33 (origin -1, odd global start) -> 2 guarded uint2 loads.
    for (int i = tid; i < 34 * 17; i += 256) {
        int r = i / 17, cp2 = i % 17;
        int gh = bh - 1 + r;
        int gw0 = bw - 1 + 2 * cp2, gw1 = gw0 + 1;
        uint2 p0 = make_uint2(0, 0), p1 = make_uint2(0, 0);
        if (gh >= 0 && gh < H2) {
            if (gw0 >= 0 && gw0 < W2) p0 = dp[(long)gh * W2 + gw0];
            if (gw1 < W2)             p1 = dp[(long)gh * W2 + gw1];
        }
        aTe[r * 17 + cp2] = unpk(p0);
        aTo[r * 17 + cp2] = unpk(p1);
    }
    for (int i = tid; i < 18 * 18; i += 256) {
        int r = i / 18, c = i % 18;
        int gh = eh0 + r, gw = ew0 + c;
        float4 v = make_float4(0.f, 0.f, 0.f, 0.f);
        if (gh >= 0 && gh < H3 && gw >= 0 && gw < W3)
            v = unpk(fp[(long)gh * W3 + gw]);
        eT[r * 19 + c] = v;
    }
    __syncthreads();

    const int pr = tid >> 4, pc = tid & 15;
    const int r0 = 2 * pr;
    float4 a4[4][4], e3[3][3];
    #pragma unroll
    for (int j = 0; j < 4; ++j) {
        const int rr = (r0 + j) * 17;
        a4[j][0] = aTe[rr + pc];     a4[j][1] = aTo[rr + pc];
        a4[j][2] = aTe[rr + pc + 1]; a4[j][3] = aTo[rr + pc + 1];
    }
    #pragma unroll
    for (int j = 0; j < 3; ++j)
        #pragma unroll
        for (int k = 0; k < 3; ++k) e3[j][k] = eT[(pr + j) * 19 + pc + k];

    float acc[2][2][4];
    #pragma unroll
    for (int a = 0; a < 2; ++a)
        #pragma unroll
        for (int o = 0; o < 2; ++o)
            #pragma unroll
            for (int k = 0; k < 4; ++k) acc[a][o][k] = 0.f;

    #pragma unroll
    for (int orr = 0; orr < 2; ++orr)
        #pragma unroll
        for (int dh = 0; dh < 3; ++dh)
            #pragma unroll
            for (int oc = 0; oc < 2; ++oc)
                #pragma unroll
                for (int dw = 0; dw < 3; ++dw) {
                    float4 aN = a4[orr + dh][oc + dw];
                    float4 eU = e3[(orr + dh + 1) >> 1][(oc + dw + 1) >> 1];
                    const int k = dh * 3 + dw;
                    float na0 = wb[544 + k], nb0 = wb[553 + k], ua0 = wb[562 + k], ub0 = wb[571 + k];
                    float na1 = wb[580 + k], nb1 = wb[589 + k], ua1 = wb[598 + k], ub1 = wb[607 + k];
                    acc[orr][oc][0] = fmaf(na0, aN.x, fmaf(nb0, aN.z, fmaf(ua0, eU.x, fmaf(ub0, eU.z, acc[orr][oc][0]))));
                    acc[orr][oc][1] = fmaf(na0, aN.y, fmaf(nb0, aN.w, fmaf(ua0, eU.y, fmaf(ub0, eU.w, acc[orr][oc][1]))));
                    acc[orr][oc][2] = fmaf(na1, aN.x, fmaf(nb1, aN.z, fmaf(ua1, eU.x, fmaf(ub1, eU.z, acc[orr][oc][2]))));
                    acc[orr][oc][3] = fmaf(na1, aN.y, fmaf(nb1, aN.w, fmaf(ua1, eU.y, fmaf(ub1, eU.w, acc[orr][oc][3]))));
                }

    int fh = bh + r0, fw = bw + 2 * pc;
    if (fh < H2) {
        const float is0 = wb[816], is1 = wb[817];
        const float bb0 = b5[0], bb1 = b5[1];
        float xv[2][4], cv[2][4];
        #pragma unroll
        for (int orr = 0; orr < 2; ++orr)
            #pragma unroll
            for (int oc = 0; oc < 2; ++oc) {
                int q = orr * 2 + oc;
                float n0 = acc[orr][oc][0], d0 = acc[orr][oc][1];
                float n1 = acc[orr][oc][2], d1 = acc[orr][oc][3];
                xv[0][q] = n0 * rcpf_(d0 + EPSF) + bb0;
                xv[1][q] = n1 * rcpf_(d1 + EPSF) + bb1;
                cv[0][q] = d0 * is0;
                cv[1][q] = d1 * is1;
            }
        uint2 q00 = packpx(xv[0][0], cv[0][0], xv[1][0], cv[1][0]);
        uint2 q01 = packpx(xv[0][1], cv[0][1], xv[1][1], cv[1][1]);
        uint2 q10 = packpx(xv[0][2], cv[0][2], xv[1][2], cv[1][2]);
        uint2 q11 = packpx(xv[0][3], cv[0][3], xv[1][3], cv[1][3]);
        long o0 = (long)b * (H2 * W2) + (long)fh * W2 + fw;
        *reinterpret_cast<uint4*>(Epk + o0)      = make_uint4(q00.x, q00.y, q01.x, q01.y);
        *reinterpret_cast<uint4*>(Epk + o0 + W2) = make_uint4(q10.x, q10.y, q11.x, q11.y);
    }
}

// ---------------------------------------------------------------------------
// Final: out = w7-1x1( nconv(cat(up2(E), A), w6, b6) ) -> f32. Deinterleaved aT.
// ---------------------------------------------------------------------------
__global__ __launch_bounds__(256) void final_tiled(
    const uint2* __restrict__ Apk, const uint2* __restrict__ Epk,
    const float* __restrict__ wb,
    const float* __restrict__ b6g, const float* __restrict__ b7g,
    float* __restrict__ oX, float* __restrict__ oC) {

    __shared__ float4 aTbuf[2 * 34 * 17];
    __shared__ float4 eT[18 * 19];
    float4* aTe = aTbuf; float4* aTo = aTbuf + 34 * 17;

    const int tid = threadIdx.x;
    const int bh = blockIdx.y * 32, bw = blockIdx.x * 32, b = blockIdx.z;
    const int eh0 = (bh - 1) >> 1, ew0 = (bw - 1) >> 1;
    const uint2* ap = Apk + (long)b * (H1 * W1);
    const uint2* ep = Epk + (long)b * (H2 * W2);

    for (int i = tid; i < 34 * 17; i += 256) {
        int r = i / 17, cp2 = i % 17;
        int gh = bh - 1 + r;
        int gw0 = bw - 1 + 2 * cp2, gw1 = gw0 + 1;
        uint2 p0 = make_uint2(0, 0), p1 = make_uint2(0, 0);
        if (gh >= 0 && gh < H1) {
            if (gw0 >= 0 && gw0 < W1) p0 = ap[(long)gh * W1 + gw0];
            if (gw1 < W1)             p1 = ap[(long)gh * W1 + gw1];
        }
        aTe[r * 17 + cp2] = unpk(p0);
        aTo[r * 17 + cp2] = unpk(p1);
    }
    for (int i = tid; i < 18 * 18; i += 256) {
        int r = i / 18, c = i % 18;
        int gh = eh0 + r, gw = ew0 + c;
        float4 v = make_float4(0.f, 0.f, 0.f, 0.f);
        if (gh >= 0 && gh < H2 && gw >= 0 && gw < W2)
            v = unpk(ep[(long)gh * W2 + gw]);
        eT[r * 19 + c] = v;
    }
    __syncthreads();

    const int pr = tid >> 4, pc = tid & 15;
    const int r0 = 2 * pr;
    float4 a4[4][4], e3[3][3];
    #pragma unroll
    for (int j = 0; j < 4; ++j) {
        const int rr = (r0 + j) * 17;
        a4[j][0] = aTe[rr + pc];     a4[j][1] = aTo[rr + pc];
        a4[j][2] = aTe[rr + pc + 1]; a4[j][3] = aTo[rr + pc + 1];
    }
    #pragma unroll
    for (int j = 0; j < 3; ++j)
        #pragma unroll
        for (int k = 0; k < 3; ++k) e3[j][k] = eT[(pr + j) * 19 + pc + k];

    float acc[2][2][4];
    #pragma unroll
    for (int a = 0; a < 2; ++a)
        #pragma unroll
        for (int o = 0; o < 2; ++o)
            #pragma unroll
            for (int k = 0; k < 4; ++k) acc[a][o][k] = 0.f;

    // w6 layout: up (E) = ci 0-1, native (A) = ci 2-3.
    #pragma unroll
    for (int orr = 0; orr < 2; ++orr)
        #pragma unroll
        for (int dh = 0; dh < 3; ++dh)
            #pragma unroll
            for (int oc = 0; oc < 2; ++oc)
                #pragma unroll
                for (int dw = 0; dw < 3; ++dw) {
                    float4 aN = a4[orr + dh][oc + dw];
                    float4 eU = e3[(orr + dh + 1) >> 1][(oc + dw + 1) >> 1];
                    const int k = dh * 3 + dw;
                    float ua0 = wb[672 + k], ub0 = wb[681 + k], na0 = wb[690 + k], nb0 = wb[699 + k];
                    float ua1 = wb[708 + k], ub1 = wb[717 + k], na1 = wb[726 + k], nb1 = wb[735 + k];
                    acc[orr][oc][0] = fmaf(ua0, eU.x, fmaf(ub0, eU.z, fmaf(na0, aN.x, fmaf(nb0, aN.z, acc[orr][oc][0]))));
                    acc[orr][oc][1] = fmaf(ua0, eU.y, fmaf(ub0, eU.w, fmaf(na0, aN.y, fmaf(nb0, aN.w, acc[orr][oc][1]))));
                    acc[orr][oc][2] = fmaf(ua1, eU.x, fmaf(ub1, eU.z, fmaf(na1, aN.x, fmaf(nb1, aN.z, acc[orr][oc][2]))));
                    acc[orr][oc][3] = fmaf(ua1, eU.y, fmaf(ub1, eU.w, fmaf(na1, aN.y, fmaf(nb1, aN.w, acc[orr][oc][3]))));
                }

    const float is60 = wb[818], is61 = wb[819];
    const float bb60 = b6g[0], bb61 = b6g[1];
    const float w70 = wb[800], w71 = wb[801];
    const float is7 = wb[820], bb7 = b7g[0];
    float ox[2][2], ocv[2][2];
    #pragma unroll
    for (int orr = 0; orr < 2; ++orr)
        #pragma unroll
        for (int oc = 0; oc < 2; ++oc) {
            float n0 = acc[orr][oc][0], d0 = acc[orr][oc][1];
            float n1 = acc[orr][oc][2], d1 = acc[orr][oc][3];
            float x0v = n0 * rcpf_(d0 + EPSF) + bb60;
            float x1v = n1 * rcpf_(d1 + EPSF) + bb61;
            float c0v = d0 * is60, c1v = d1 * is61;
            float den7 = fmaf(w70, c0v, w71 * c1v);
            float nom7 = fmaf(w70, x0v * c0v, w71 * (x1v * c1v));
            ox[orr][oc] = nom7 * rcpf_(den7 + EPSF) + bb7;
            ocv[orr][oc] = den7 * is7;
        }
    long o = (long)b * (H1 * W1) + (long)(bh + r0) * W1 + (bw + 2 * pc);
    *reinterpret_cast<float2*>(oX + o)      = make_float2(ox[0][0], ox[0][1]);
    *reinterpret_cast<float2*>(oX + o + W1) = make_float2(ox[1][0], ox[1][1]);
    *reinterpret_cast<float2*>(oC + o)      = make_float2(ocv[0][0], ocv[0][1]);
    *reinterpret_cast<float2*>(oC + o + W1) = make_float2(ocv[1][0], ocv[1][1]);
}

extern "C" void kernel_launch(void* const* d_in, const int* in_sizes, int n_in,
                              void* d_out, int out_size, void* d_ws, size_t ws_size,
                              hipStream_t stream) {
    const float* x0 = (const float*)d_in[0];
    const float* c0 = (const float*)d_in[1];
    const float* w1 = (const float*)d_in[2];
    const float* b1 = (const float*)d_in[3];
    const float* w2 = (const float*)d_in[4];
    const float* b2 = (const float*)d_in[5];
    const float* w3 = (const float*)d_in[6];
    const float* b3 = (const float*)d_in[7];
    const float* w4 = (const float*)d_in[8];
    const float* b4 = (const float*)d_in[9];
    const float* w5 = (const float*)d_in[10];
    const float* b5 = (const float*)d_in[11];
    const float* w6 = (const float*)d_in[12];
    const float* b6 = (const float*)d_in[13];
    const float* w7 = (const float*)d_in[14];
    const float* b7 = (const float*)d_in[15];

    const long N1 = (long)B_ * H1 * W1;     // 6,848,512 pixels (full res)
    const long N2 = N1 / 4, N3 = N1 / 16, N4 = N1 / 64;

    // ws: [wb 4KB][Apk 8*N1][Epk 8*N2] ~ 68.5 MB
    float* wb = (float*)d_ws;
    uint2* Apk = (uint2*)((char*)d_ws + 4096);
    uint2* Epk = Apk + N1;

    // d_out (N1 uint2 capacity) as packed scratch; final pass reads only ws.
    uint2* R = (uint2*)d_out;
    uint2* P1pk = R;                 // N2
    uint2* Dpk  = R + N2;            // N2
    uint2* P2pk = R + 2 * N2;        // N3
    uint2* Gpk  = P2pk + N3;         // N3
    uint2* P3pk = Gpk + N3;          // N4
    uint2* Ipk  = P3pk + N4;         // N4
    uint2* Fpk  = Ipk + N4;          // N3

    float* oX = (float*)d_out;
    float* oC = oX + N1;

    prep_weights<<<1, 256, 0, stream>>>(w1, w2, w3, w4, w5, w6, w7, wb);

    dim3 gridF(W1 / TDIM, H1 / TDIM, B_);           // 38 x 11 x 16
    fused_l1pool<<<gridF, 256, 0, stream>>>(x0, c0, wb, b1, b2, b3, Apk, P1pk);

    dim3 gridL2(W2 / 32, (H2 + 31) / 32, B_);       // 19 x 6 x 16
    fused_l2<<<gridL2, 256, 0, stream>>>(P1pk, wb, b2, b3, Dpk, P2pk);

    dim3 gridL3((W3 + 31) / 32, (H3 + 31) / 32, B_); // 10 x 3 x 16
    fused_l3<<<gridL3, 256, 0, stream>>>(P2pk, wb, b2, Gpk, P3pk);

    const int g4 = (B_ * H4 * W4 + 255) / 256;
    nconv5_pk<<<g4, 256, 0, stream>>>(P3pk, wb, b2, Ipk, H4, W4);   // I = x4,c4

    const int g3 = (B_ * H3 * W3 + 255) / 256;
    nconv_cat_pk<<<g3, 256, 0, stream>>>(Gpk, Ipk, wb, b4, Fpk, H3, W3);  // F = x34

    nconv_cat_h2t<<<gridL2, 256, 0, stream>>>(Dpk, Fpk, wb, b5, Epk);     // E = x23 (ws)

    dim3 gridL(W1 / 32, H1 / 32, B_);               // 38 x 11 x 16
    final_tiled<<<gridL, 256, 0, stream>>>(Apk, Epk, wb, b6, b7, oX, oC);
}